// Round 12
// baseline (1215.767 us; speedup 1.0000x reference)
//
#include <hip/hip_runtime.h>
#include <hip/hip_bf16.h>
#include <math.h>

// Problem constants (B=1)
#define S_LEN  2048
#define DIMN   2048
#define NHEAD  16
#define NKV    8
#define HEADD  128
#define WSTART 1536      // S - WIN
#define RSQD   0.08838834764831845f   // 1/sqrt(128)
#define NEGINF (-INFINITY)

typedef __hip_bfloat16 bf16;
typedef __attribute__((ext_vector_type(8))) __bf16 bf16x8;
typedef __attribute__((ext_vector_type(8))) unsigned short u16x8;
typedef __attribute__((ext_vector_type(4))) unsigned short us4;
typedef __attribute__((ext_vector_type(4))) float  f32x4;

__device__ __forceinline__ float bfl(unsigned u){ u <<= 16; float f; __builtin_memcpy(&f, &u, 4); return f; }
// fp32 -> bf16 bits, RTNE
__device__ __forceinline__ unsigned short f2b(float f){
  unsigned u; __builtin_memcpy(&u, &f, 4);
  u += 0x7fff + ((u >> 16) & 1);
  return (unsigned short)(u >> 16);
}
// broadcast lane j's float via v_readlane
__device__ __forceinline__ float lane_bcast(float v, int lane){
  int i; __builtin_memcpy(&i, &v, 4);
  i = __builtin_amdgcn_readlane(i, lane);
  float f; __builtin_memcpy(&f, &i, 4);
  return f;
}

__device__ __forceinline__ float wave_max(float v){
#pragma unroll
  for (int o = 32; o; o >>= 1) v = fmaxf(v, __shfl_xor(v, o));
  return v;
}
__device__ __forceinline__ float wave_sum(float v){
#pragma unroll
  for (int o = 32; o; o >>= 1) v += __shfl_xor(v, o);
  return v;
}

// ---- DPP 16-lane butterfly reduce (row = 16 lanes on CDNA) ----
template<int CTRL>
__device__ __forceinline__ float dpp_f(float v){
  int i; __builtin_memcpy(&i, &v, 4);
  i = __builtin_amdgcn_update_dpp(i, i, CTRL, 0xf, 0xf, false);
  float f; __builtin_memcpy(&f, &i, 4);
  return f;
}
__device__ __forceinline__ float gmax16(float v){
  v = fmaxf(v, dpp_f<0xB1>(v));    // quad_perm(1,0,3,2)  xor1
  v = fmaxf(v, dpp_f<0x4E>(v));    // quad_perm(2,3,0,1)  xor2
  v = fmaxf(v, dpp_f<0x141>(v));   // row_half_mirror     (quad exchange)
  v = fmaxf(v, dpp_f<0x140>(v));   // row_mirror          (half exchange)
  return v;
}
__device__ __forceinline__ float gsum16(float v){
  v += dpp_f<0xB1>(v);
  v += dpp_f<0x4E>(v);
  v += dpp_f<0x141>(v);
  v += dpp_f<0x140>(v);
  return v;
}

__device__ __forceinline__ float dot128_bf16(const float* __restrict__ qv, const bf16* __restrict__ krow){
  const uint4* kp = (const uint4*)krow;
  float s = 0.f;
#pragma unroll
  for (int t = 0; t < 16; ++t){
    uint4 u = kp[t];
    const float* q8 = qv + t*8;
    s += q8[0]*bfl(u.x & 0xffffu) + q8[1]*bfl(u.x >> 16)
       + q8[2]*bfl(u.y & 0xffffu) + q8[3]*bfl(u.y >> 16)
       + q8[4]*bfl(u.z & 0xffffu) + q8[5]*bfl(u.z >> 16)
       + q8[6]*bfl(u.w & 0xffffu) + q8[7]*bfl(u.w >> 16);
  }
  return s;
}

// exact summation order kept (selection top-k tie behavior must match the proven kernel)
__device__ __forceinline__ float dot128_f32(const float* __restrict__ qv, const float* __restrict__ row){
  const float4* rp = (const float4*)row;
  float s = 0.f;
#pragma unroll
  for (int t = 0; t < 32; ++t){
    float4 r = rp[t];
    const float* q4 = qv + t*4;
    s += q4[0]*r.x + q4[1]*r.y + q4[2]*r.z + q4[3]*r.w;
  }
  return s;
}

// u16x8 (bf16 bits) MFMA wrapper
__device__ __forceinline__ f32x4 MFMA(u16x8 a, u16x8 b, f32x4 c){
  bf16x8 ab, bb;
  __builtin_memcpy(&ab, &a, 16);
  __builtin_memcpy(&bb, &b, 16);
  return __builtin_amdgcn_mfma_f32_16x16x32_bf16(ab, bb, c, 0, 0, 0);
}

// L2-locality supertile remap (R10, bit-identical; kept — neutral)
__device__ __forceinline__ void remap_bc_br(int& bc, int& br){
  const int GN = gridDim.x, GM = gridDim.y;
  const int lin = blockIdx.y * GN + blockIdx.x;
  const int per = GM * 8;
  const int sc = lin / per, rem = lin % per;
  br = rem % GM;
  bc = sc * 8 + rem / GM;
}

// ---------------- GEMM: C[M][N] = A[M][K] * B[N][K]^T  (bf16 in, fp32 acc) ----------------
template<bool OUT_BF16>
__global__ __launch_bounds__(256) void gemm_bt(const bf16* __restrict__ A, const bf16* __restrict__ B,
                                               void* __restrict__ Cp, int M, int N, int K)
{
  __shared__ __align__(16) bf16 As[128*32];
  __shared__ __align__(16) bf16 Bs[128*32];
  const int t = threadIdx.x;
  const int w = t >> 6, l = t & 63;
  int bc, br; remap_bc_br(bc, br);
  const int wr = w >> 1, wc = w & 1;
  f32x4 acc[4][4];
  {
    f32x4 z = {0.f, 0.f, 0.f, 0.f};
#pragma unroll
    for (int m = 0; m < 4; ++m)
#pragma unroll
      for (int n = 0; n < 4; ++n) acc[m][n] = z;
  }
  const int srow = l >> 2, scol = (l & 3) * 8;
  const int lrow = l & 15, lko = (l >> 4) * 8;

  for (int kt = 0; kt < K; kt += 32){
#pragma unroll
    for (int cc = 0; cc < 2; ++cc){
      const int c = w + cc*4;
      const bf16* gA = A + (size_t)(br*128 + c*16 + srow)*K + kt + scol;
      const bf16* gB = B + (size_t)(bc*128 + c*16 + srow)*K + kt + scol;
      __builtin_amdgcn_global_load_lds((const __attribute__((address_space(1))) void*)gA,
                                       (__attribute__((address_space(3))) void*)&As[c*512], 16, 0, 0);
      __builtin_amdgcn_global_load_lds((const __attribute__((address_space(1))) void*)gB,
                                       (__attribute__((address_space(3))) void*)&Bs[c*512], 16, 0, 0);
    }
    __syncthreads();
    bf16x8 af[4], bfr[4];
#pragma unroll
    for (int m = 0; m < 4; ++m) af[m]  = *(const bf16x8*)&As[(wr*64 + m*16 + lrow)*32 + lko];
#pragma unroll
    for (int n = 0; n < 4; ++n) bfr[n] = *(const bf16x8*)&Bs[(wc*64 + n*16 + lrow)*32 + lko];
#pragma unroll
    for (int m = 0; m < 4; ++m)
#pragma unroll
      for (int n = 0; n < 4; ++n)
        acc[m][n] = __builtin_amdgcn_mfma_f32_16x16x32_bf16(af[m], bfr[n], acc[m][n], 0, 0, 0);
    __syncthreads();
  }
  const int crow0 = br*128 + wr*64 + (l >> 4)*4;
  const int ccol  = bc*128 + wc*64 + lrow;
#pragma unroll
  for (int m = 0; m < 4; ++m)
#pragma unroll
    for (int n = 0; n < 4; ++n)
#pragma unroll
      for (int r = 0; r < 4; ++r){
        const size_t idx = (size_t)(crow0 + m*16 + r)*N + (ccol + n*16);
        if constexpr (OUT_BF16) ((bf16*)Cp)[idx] = __float2bfloat16(acc[m][n][r]);
        else                    ((float*)Cp)[idx] = acc[m][n][r];
      }
}

// ---------------- pre-split 3-pass GEMM: C = A*B^T with A,B given as hi/lo bf16 ----------------
__global__ __launch_bounds__(256) void gemm_bt3(const bf16* __restrict__ Ahg, const bf16* __restrict__ Alg,
                                                const bf16* __restrict__ Bhg, const bf16* __restrict__ Blg,
                                                float* __restrict__ C, int M, int N, int K)
{
  __shared__ __align__(16) bf16 AhS[128*32], AlS[128*32], BhS[128*32], BlS[128*32];
  const int t = threadIdx.x;
  const int w = t >> 6, l = t & 63;
  int bc, br; remap_bc_br(bc, br);
  const int wr = w >> 1, wc = w & 1;
  f32x4 acc[4][4];
  {
    f32x4 z = {0.f, 0.f, 0.f, 0.f};
#pragma unroll
    for (int m = 0; m < 4; ++m)
#pragma unroll
      for (int n = 0; n < 4; ++n) acc[m][n] = z;
  }
  const int srow = l >> 2, scol = (l & 3) * 8;
  const int lrow = l & 15, lko = (l >> 4) * 8;

  for (int kt = 0; kt < K; kt += 32){
#pragma unroll
    for (int cc = 0; cc < 2; ++cc){
      const int c = w + cc*4;
      const size_t aoff = (size_t)(br*128 + c*16 + srow)*K + kt + scol;
      const size_t boff = (size_t)(bc*128 + c*16 + srow)*K + kt + scol;
      __builtin_amdgcn_global_load_lds((const __attribute__((address_space(1))) void*)(Ahg + aoff),
                                       (__attribute__((address_space(3))) void*)&AhS[c*512], 16, 0, 0);
      __builtin_amdgcn_global_load_lds((const __attribute__((address_space(1))) void*)(Alg + aoff),
                                       (__attribute__((address_space(3))) void*)&AlS[c*512], 16, 0, 0);
      __builtin_amdgcn_global_load_lds((const __attribute__((address_space(1))) void*)(Bhg + boff),
                                       (__attribute__((address_space(3))) void*)&BhS[c*512], 16, 0, 0);
      __builtin_amdgcn_global_load_lds((const __attribute__((address_space(1))) void*)(Blg + boff),
                                       (__attribute__((address_space(3))) void*)&BlS[c*512], 16, 0, 0);
    }
    __syncthreads();
    bf16x8 ahf[4], alf[4], bhf[4], blf[4];
#pragma unroll
    for (int m = 0; m < 4; ++m){
      ahf[m] = *(const bf16x8*)&AhS[(wr*64 + m*16 + lrow)*32 + lko];
      alf[m] = *(const bf16x8*)&AlS[(wr*64 + m*16 + lrow)*32 + lko];
    }
#pragma unroll
    for (int n = 0; n < 4; ++n){
      bhf[n] = *(const bf16x8*)&BhS[(wc*64 + n*16 + lrow)*32 + lko];
      blf[n] = *(const bf16x8*)&BlS[(wc*64 + n*16 + lrow)*32 + lko];
    }
#pragma unroll
    for (int m = 0; m < 4; ++m)
#pragma unroll
      for (int n = 0; n < 4; ++n){
        acc[m][n] = __builtin_amdgcn_mfma_f32_16x16x32_bf16(ahf[m], bhf[n], acc[m][n], 0, 0, 0);
        acc[m][n] = __builtin_amdgcn_mfma_f32_16x16x32_bf16(ahf[m], blf[n], acc[m][n], 0, 0, 0);
        acc[m][n] = __builtin_amdgcn_mfma_f32_16x16x32_bf16(alf[m], bhf[n], acc[m][n], 0, 0, 0);
      }
    __syncthreads();
  }
  const int crow0 = br*128 + wr*64 + (l >> 4)*4;
  const int ccol  = bc*128 + wc*64 + lrow;
#pragma unroll
  for (int m = 0; m < 4; ++m)
#pragma unroll
    for (int n = 0; n < 4; ++n)
#pragma unroll
      for (int r = 0; r < 4; ++r)
        C[(size_t)(crow0 + m*16 + r)*N + (ccol + n*16)] = acc[m][n][r];
}

// ---------------- split-bf16 emulated-fp32 GEMM (kept for the small ck32 GEMM) ----------------
__global__ __launch_bounds__(256) void gemm_bt_split(const float* __restrict__ A, const float* __restrict__ B,
                                                     float* __restrict__ C, int M, int N, int K)
{
  __shared__ __align__(16) unsigned short Ah[128*32], Al[128*32], Bh[128*32], Bl[128*32];
  const int t = threadIdx.x;
  const int w = t >> 6, l = t & 63;
  const int bc = blockIdx.x, br = blockIdx.y;
  const int wr = w >> 1, wc = w & 1;
  f32x4 acc[4][4];
  {
    f32x4 z = {0.f, 0.f, 0.f, 0.f};
#pragma unroll
    for (int m = 0; m < 4; ++m)
#pragma unroll
      for (int n = 0; n < 4; ++n) acc[m][n] = z;
  }
  const int lrow = l & 15, lko = (l >> 4) * 8;

  for (int kt = 0; kt < K; kt += 32){
#pragma unroll
    for (int i = 0; i < 4; ++i){
      const int lin = t + i*256;
      const int row = lin >> 3;
      const int cq  = (lin & 7) * 4;
      const float4 va = *(const float4*)&A[(size_t)(br*128 + row)*K + kt + cq];
      const float4 vb = *(const float4*)&B[(size_t)(bc*128 + row)*K + kt + cq];
      const float fa[4] = {va.x, va.y, va.z, va.w};
      const float fb[4] = {vb.x, vb.y, vb.z, vb.w};
      us4 ah, al2, bh, bl2;
#pragma unroll
      for (int j = 0; j < 4; ++j){
        const unsigned short h = f2b(fa[j]); ah[j] = h; al2[j] = f2b(fa[j] - bfl(h));
        const unsigned short g = f2b(fb[j]); bh[j] = g; bl2[j] = f2b(fb[j] - bfl(g));
      }
      *(us4*)&Ah[row*32 + cq] = ah;  *(us4*)&Al[row*32 + cq] = al2;
      *(us4*)&Bh[row*32 + cq] = bh;  *(us4*)&Bl[row*32 + cq] = bl2;
    }
    __syncthreads();
    bf16x8 ahf[4], alf[4], bhf[4], blf[4];
#pragma unroll
    for (int m = 0; m < 4; ++m){
      ahf[m] = *(const bf16x8*)&Ah[(wr*64 + m*16 + lrow)*32 + lko];
      alf[m] = *(const bf16x8*)&Al[(wr*64 + m*16 + lrow)*32 + lko];
    }
#pragma unroll
    for (int n = 0; n < 4; ++n){
      bhf[n] = *(const bf16x8*)&Bh[(wc*64 + n*16 + lrow)*32 + lko];
      blf[n] = *(const bf16x8*)&Bl[(wc*64 + n*16 + lrow)*32 + lko];
    }
#pragma unroll
    for (int m = 0; m < 4; ++m)
#pragma unroll
      for (int n = 0; n < 4; ++n){
        acc[m][n] = __builtin_amdgcn_mfma_f32_16x16x32_bf16(ahf[m], bhf[n], acc[m][n], 0, 0, 0);
        acc[m][n] = __builtin_amdgcn_mfma_f32_16x16x32_bf16(ahf[m], blf[n], acc[m][n], 0, 0, 0);
        acc[m][n] = __builtin_amdgcn_mfma_f32_16x16x32_bf16(alf[m], bhf[n], acc[m][n], 0, 0, 0);
      }
    __syncthreads();
  }
  const int crow0 = br*128 + wr*64 + (l >> 4)*4;
  const int ccol  = bc*128 + wc*64 + lrow;
#pragma unroll
  for (int m = 0; m < 4; ++m)
#pragma unroll
    for (int n = 0; n < 4; ++n)
#pragma unroll
      for (int r = 0; r < 4; ++r)
        C[(size_t)(crow0 + m*16 + r)*N + (ccol + n*16)] = acc[m][n][r];
}

// ---------------- small utility kernels ----------------
__global__ void build_tables_kernel(float* __restrict__ cosT, float* __restrict__ sinT){
  const int idx = blockIdx.x*blockDim.x + threadIdx.x;
  if (idx >= S_LEN*64) return;
  const int s = idx >> 6, i = idx & 63;
  const float inv = powf(10000.f, -(float)(2*i) / 128.f);
  const float ang = (float)s * inv;
  cosT[idx] = cosf(ang);
  sinT[idx] = sinf(ang);
}

__global__ void cvt_f32_bf16(const float* __restrict__ src, bf16* __restrict__ dst, int n){
  const int stride = gridDim.x * blockDim.x;
  for (int i = blockIdx.x*blockDim.x + threadIdx.x; i < n; i += stride)
    dst[i] = __float2bfloat16(src[i]);
}

// fp32 -> hi/lo bf16 pair (same f2b formulas as gemm_bt_split staging; done ONCE)
__global__ void split_f32_kernel(const float* __restrict__ src, bf16* __restrict__ hi,
                                 bf16* __restrict__ lo, int n4){
  const int stride = gridDim.x * blockDim.x;
  for (int i = blockIdx.x*blockDim.x + threadIdx.x; i < n4; i += stride){
    const float4 v = ((const float4*)src)[i];
    const float f[4] = {v.x, v.y, v.z, v.w};
    us4 h, l2;
#pragma unroll
    for (int j = 0; j < 4; ++j){
      const unsigned short hh = f2b(f[j]);
      h[j] = hh;
      l2[j] = f2b(f[j] - bfl(hh));
    }
    ((us4*)hi)[i] = h;
    ((us4*)lo)[i] = l2;
  }
}

// in-place fp32 RoPE on a [S][C] buffer (C = heads*128)
__global__ void rope32_kernel(float* __restrict__ T, const float* __restrict__ cosT,
                              const float* __restrict__ sinT, int C){
  const int s = blockIdx.x;
  float* row = T + (size_t)s*C;
  for (int p = threadIdx.x; p < (C >> 1); p += blockDim.x){
    const int i = p & 63;
    const int col = (p >> 6)*128 + 2*i;
    const float a = row[col], b = row[col+1];
    const float c = cosT[s*64 + i], sn = sinT[s*64 + i];
    row[col]   = a*c - b*sn;
    row[col+1] = a*sn + b*c;
  }
}

// [s][kv*128+d] -> [kv][s][d] fp32
__global__ void khm_kernel(const float* __restrict__ src, float* __restrict__ dst){
  const int idx = blockIdx.x*blockDim.x + threadIdx.x;
  if (idx >= S_LEN*1024) return;
  const int s = idx >> 10, c = idx & 1023;
  const int kv = c >> 7, d = c & 127;
  dst[((size_t)kv*S_LEN + s)*HEADD + d] = src[idx];
}

// Y[s][12288] -> 9 head-major bf16 tensors with RoPE on q/k
__global__ void rope_scatter_kernel(const bf16* __restrict__ Y, const float* __restrict__ cosT,
    const float* __restrict__ sinT,
    bf16* __restrict__ Qw, bf16* __restrict__ Kw, bf16* __restrict__ Vw,
    bf16* __restrict__ Qs, bf16* __restrict__ Ks, bf16* __restrict__ Vs,
    bf16* __restrict__ Qc, bf16* __restrict__ Kc, bf16* __restrict__ Vc)
{
  const int s = blockIdx.x;
  const unsigned* Yrow = (const unsigned*)(Y + (size_t)s*12288);
  for (int p = threadIdx.x; p < 6144; p += blockDim.x){
    const int col = p*2;
    bf16* dst; int base; bool isv = false;
    if (col < 4096){
      if      (col < 2048){ dst = Qw; base = 0; }
      else if (col < 3072){ dst = Kw; base = 2048; }
      else                { dst = Vw; base = 3072; isv = true; }
    } else if (col < 8192){
      if      (col < 6144){ dst = Qs; base = 4096; }
      else if (col < 7168){ dst = Ks; base = 6144; }
      else                { dst = Vs; base = 7168; isv = true; }
    } else {
      if      (col < 10240){ dst = Qc; base = 8192; }
      else if (col < 11264){ dst = Kc; base = 10240; }
      else                 { dst = Vc; base = 11264; isv = true; }
    }
    const int lc = col - base;
    const int head = lc >> 7, d = lc & 127, i = d >> 1;
    const unsigned yy = Yrow[p];
    float a = bfl(yy & 0xffffu), b = bfl(yy >> 16);
    if (!isv){
      const float c = cosT[s*64 + i], sn = sinT[s*64 + i];
      const float na = a*c - b*sn;
      b = a*sn + b*c;
      a = na;
    }
    const size_t off = ((size_t)head*S_LEN + s)*HEADD + d;
    dst[off]   = __float2bfloat16(a);
    dst[off+1] = __float2bfloat16(b);
  }
}

// [NKV][S_LEN][HEADD] bf16 -> [NKV][HEADD][S_LEN] bf16 (64x64 LDS tiles)
__global__ __launch_bounds__(256) void vtrans_kernel(const bf16* __restrict__ src, bf16* __restrict__ dst){
  __shared__ unsigned short tile[64][72];   // 72: keeps 16B-aligned rows (144B)
  const int kv = blockIdx.z;
  const int r0 = blockIdx.x*64;   // S dim
  const int c0 = blockIdx.y*64;   // D dim
  const int t = threadIdx.x;
  const int lr = t >> 2, lc = (t & 3)*16;
  const unsigned short* sp = (const unsigned short*)src + ((size_t)kv*S_LEN + r0 + lr)*HEADD + c0 + lc;
  *(u16x8*)&tile[lr][lc]     = *(const u16x8*)sp;
  *(u16x8*)&tile[lr][lc + 8] = *(const u16x8*)(sp + 8);
  __syncthreads();
  unsigned short* dp = (unsigned short*)dst + ((size_t)kv*HEADD + c0 + lr)*S_LEN + r0 + lc;
  u16x8 v0, v1;
#pragma unroll
  for (int j = 0; j < 8; ++j){ v0[j] = tile[lc + j][lr]; v1[j] = tile[lc + 8 + j][lr]; }
  *(u16x8*)dp       = v0;
  *(u16x8*)(dp + 8) = v1;
}

// ck32/cv [NKV][64][HEADD] fp32 -> hi/lo bf16 (ck as-is, cv transposed to [NKV][HEADD][64])
__global__ void comp_prep_kernel(const float* __restrict__ ck32, const float* __restrict__ cv,
    bf16* __restrict__ ckh, bf16* __restrict__ ckl, bf16* __restrict__ cvTh, bf16* __restrict__ cvTl)
{
  const int i = blockIdx.x*256 + threadIdx.x;
  if (i >= NKV*64*HEADD) return;
  const int kv = i >> 13, rem = i & 8191, key = rem >> 7, d = rem & 127;
  const float a = ck32[i];
  const unsigned short ah = f2b(a);
  ((unsigned short*)ckh)[i] = ah;
  ((unsigned short*)ckl)[i] = f2b(a - bfl(ah));
  const float b = cv[i];
  const unsigned short bh = f2b(b);
  const size_t j = ((size_t)kv*HEADD + d)*64 + key;
  ((unsigned short*)cvTh)[j] = bh;
  ((unsigned short*)cvTl)[j] = f2b(b - bfl(bh));
}

__global__ __launch_bounds__(64) void gates_kernel(const float* __restrict__ x,
    const float* __restrict__ wg, float* __restrict__ gates)
{
  const int r = blockIdx.x, l = threadIdx.x;
  const float* xr = x + (size_t)r*DIMN;
  float p0 = 0.f, p1 = 0.f, p2 = 0.f;
  for (int i = l; i < DIMN; i += 64){
    const float xv = xr[i];
    p0 += xv * wg[i];
    p1 += xv * wg[DIMN + i];
    p2 += xv * wg[2*DIMN + i];
  }
  p0 = wave_sum(p0); p1 = wave_sum(p1); p2 = wave_sum(p2);
  if (l == 0){
    const float mx = fmaxf(p0, fmaxf(p1, p2));
    const float e0 = expf(p0-mx), e1 = expf(p1-mx), e2 = expf(p2-mx);
    const float inv = 1.f/(e0+e1+e2);
    gates[r*3+0] = e0*inv; gates[r*3+1] = e1*inv; gates[r*3+2] = e2*inv;
  }
}

// block per kv; thread (d, half) reduces 256 window rows each
__global__ __launch_bounds__(256) void meanv_kernel(const bf16* __restrict__ Vw, float* __restrict__ mean_vw){
  const int kv = blockIdx.x, t = threadIdx.x;
  const int d = t & 127, half = t >> 7;
  const bf16* base = Vw + ((size_t)kv*S_LEN + WSTART + half*256)*HEADD + d;
  float acc = 0.f;
  for (int r = 0; r < 256; ++r) acc += __bfloat162float(base[(size_t)r*HEADD]);
  __shared__ float red[256];
  red[t] = acc;
  __syncthreads();
  if (!half) mean_vw[kv*HEADD + d] = (red[d] + red[128 + d]) * (1.f/512.f);
}

// suffix-sum of Vs over s, two-phase
__global__ __launch_bounds__(256) void suffv_a_kernel(const bf16* __restrict__ Vs, float* __restrict__ chunkSums){
  const int kv = blockIdx.x, ch = blockIdx.y, t = threadIdx.x;
  const int d = t & 127, half = t >> 7;
  const bf16* base = Vs + ((size_t)kv*S_LEN + ch*128 + half*64)*HEADD + d;
  float acc = 0.f;
  for (int r = 0; r < 64; ++r) acc += __bfloat162float(base[(size_t)r*HEADD]);
  __shared__ float red[256];
  red[t] = acc;
  __syncthreads();
  if (!half) chunkSums[((size_t)kv*16 + ch)*HEADD + d] = red[d] + red[128 + d];
}
__global__ __launch_bounds__(128) void suffv_b_kernel(const bf16* __restrict__ Vs,
    const float* __restrict__ chunkSums, float* __restrict__ suffV){
  const int kv = blockIdx.x, ch = blockIdx.y, d = threadIdx.x;
  float acc = 0.f;
  for (int c = ch + 1; c < 16; ++c) acc += chunkSums[((size_t)kv*16 + c)*HEADD + d];
  const int s0 = ch*128;
  for (int r = 127; r >= 0; --r){
    acc += __bfloat162float(Vs[((size_t)kv*S_LEN + s0 + r)*HEADD + d]);
    suffV[((size_t)kv*2049 + s0 + r)*HEADD + d] = acc;
  }
  if (ch == 15) suffV[((size_t)kv*2049 + 2048)*HEADD + d] = 0.f;
}

__global__ void win_mean_kernel(const float* __restrict__ mean_vw, const float* __restrict__ gates,
                                float* __restrict__ comb)
{
  const int q = blockIdx.x;
  const float g0 = gates[q*3];
  for (int c = threadIdx.x; c < DIMN; c += blockDim.x){
    const int kv = c >> 8;
    const int d  = c & 127;
    comb[(size_t)q*DIMN + c] = g0 * mean_vw[kv*HEADD + d];
  }
}

// ---------------- selection kernel: exact dot order + rank-based top-16 ----------------
__global__ __launch_bounds__(64) void sel_select_kernel(
    const float* __restrict__ Qs32, const float* __restrict__ ck32,
    unsigned long long* __restrict__ selm, unsigned long long* __restrict__ selU,
    unsigned* __restrict__ selvis)
{
  const int tile = blockIdx.x, h = blockIdx.y, kv = h >> 1, l = threadIdx.x;
  const int q0 = tile*16, bq = tile >> 1;
  __shared__ float impS[16][64];
  __shared__ unsigned short pmaskS[16][4];
  __shared__ unsigned long long vmS[16];
  const float* ckrow = ck32 + (size_t)(kv*64 + l)*HEADD;
#pragma unroll
  for (int qq = 0; qq < 16; ++qq){
    const float* qr = Qs32 + (size_t)(q0+qq)*DIMN + h*HEADD;
    impS[qq][l] = dot128_f32(qr, ckrow);
  }
  __syncthreads();
  const int row = l >> 2, part = l & 3;
  float mine[16];
#pragma unroll
  for (int j = 0; j < 16; ++j) mine[j] = impS[row][part*16 + j];
  int rk[16];
#pragma unroll
  for (int j = 0; j < 16; ++j) rk[j] = 0;
  for (int b = 0; b < 64; ++b){
    const float vb = impS[row][b];
#pragma unroll
    for (int j = 0; j < 16; ++j){
      const int idxj = part*16 + j;
      rk[j] += ((vb > mine[j]) || (vb == mine[j] && b < idxj)) ? 1 : 0;
    }
  }
  unsigned pm = 0;
#pragma unroll
  for (int j = 0; j < 16; ++j) if (rk[j] < 16) pm |= (1u << j);
  pmaskS[row][part] = (unsigned short)pm;
  __syncthreads();
  if (l < 16){
    const unsigned long long sm =
        (unsigned long long)pmaskS[l][0]
      | ((unsigned long long)pmaskS[l][1] << 16)
      | ((unsigned long long)pmaskS[l][2] << 32)
      | ((unsigned long long)pmaskS[l][3] << 48);
    selm[((size_t)h*128 + tile)*16 + l] = sm;
    vmS[l] = (bq >= 63) ? sm : (sm & ((1ull << (bq+1)) - 1ull));
  }
  __syncthreads();
  if (l == 0){
    unsigned long long U = 0ull; unsigned vis = 0u;
#pragma unroll
    for (int i = 0; i < 16; ++i){ U |= vmS[i]; vis |= (vmS[i] ? 1u : 0u) << i; }
    selU[(size_t)h*128 + tile] = U;
    selvis[(size_t)h*128 + tile] = vis;
  }
}

// ---------------- MFMA fused attention, 4-way key-split flash ----------------
// Block = 256 threads = 4 waves, one (branch, tile, head) per block.
// R6: LPT grid. R7: V-prefetch. R8: __expf. R12: 64-KEY ITERATIONS — the per-chunk fixed
// cost (sm_step DPP/exp chains + LDS P round-trip + lgkmcnt drain) dominated (~7k cy/chunk
// vs ~1k compute, R9-R11 accounting); pairing two 32-key chunks per iteration halves the
// number of sm_step invocations, LDS round-trips, and waitcnt drains per key. comp routes
// through sm_step4 with s2=s3=-inf (bit-identical: p2=p3=0 add exactly zero).

// online-softmax step over 4 score registers (64 keys); row-group reduces are DPP.
// P stored hi/lo bf16 at row stride 72 shorts (2-way bank pattern, free).
__device__ __forceinline__ void sm_step4(float s0, float s1, float s2, float s3,
                                         int row, int c16,
                                         float& m, float& sum, f32x4* out, int r,
                                         unsigned short* Plh, unsigned short* Pll)
{
  const float mx = gmax16(fmaxf(fmaxf(s0, s1), fmaxf(s2, s3)));
  const float mn = fmaxf(m, mx);
  float p0, p1, p2, p3, scale;
  if (mn == NEGINF){ p0 = p1 = p2 = p3 = 0.f; scale = 1.f; }   // fully-masked-so-far row
  else {
    scale = __expf(m - mn);
    p0 = __expf(s0 - mn); p1 = __expf(s1 - mn);
    p2 = __expf(s2 - mn); p3 = __expf(s3 - mn);
  }
  const bool needscale = (mn != m);
  m = mn;
  sum = sum*scale + gsum16((p0 + p1) + (p2 + p3));
  if (needscale){
#pragma unroll
    for (int t = 0; t < 8; ++t) out[t][r] *= scale;
  }
  const unsigned short h0 = f2b(p0), h1 = f2b(p1), h2 = f2b(p2), h3 = f2b(p3);
  Plh[row*72 + c16]      = h0;
  Plh[row*72 + 16 + c16] = h1;
  Plh[row*72 + 32 + c16] = h2;
  Plh[row*72 + 48 + c16] = h3;
  Pll[row*72 + c16]      = f2b(p0 - bfl(h0));
  Pll[row*72 + 16 + c16] = f2b(p1 - bfl(h1));
  Pll[row*72 + 32 + c16] = f2b(p2 - bfl(h2));
  Pll[row*72 + 48 + c16] = f2b(p3 - bfl(h3));
}

__global__ __launch_bounds__(256) void attn_mfma_kernel(
    const bf16* __restrict__ Qw, const bf16* __restrict__ Kw, const bf16* __restrict__ VwT,
    const bf16* __restrict__ Qc, const bf16* __restrict__ ckh, const bf16* __restrict__ ckl,
    const bf16* __restrict__ cvTh, const bf16* __restrict__ cvTl,
    const float* __restrict__ Qs32, const bf16* __restrict__ Ks, const bf16* __restrict__ VsT,
    const bf16* __restrict__ Vs,
    const float* __restrict__ suffV, const float* __restrict__ gates,
    const unsigned long long* __restrict__ selm, const unsigned long long* __restrict__ selU,
    const unsigned* __restrict__ selvis,
    float* __restrict__ comb, float* __restrict__ combC, float* __restrict__ combS)
{
  const int h = blockIdx.x, kv = h >> 1;     // heads on X (dispatch-fastest axis)
  const int tid = threadIdx.x, wv = tid >> 6, l = tid & 63;
  const int g16 = l >> 4, c16 = l & 15;
  const int bx = blockIdx.y;                 // branch/tile on Y

  __shared__ unsigned short PlhS[4][1152], PllS[4][1152];   // 16 rows x 72 shorts
  __shared__ float outS[16][132];               // +4 pad: spreads rows across banks
  __shared__ float mS[4][16], sumS[4][16];
  __shared__ float qv[128];
  unsigned short* Plh = PlhS[wv];
  unsigned short* Pll = PllS[wv];

  f32x4 out[8];
  float m[4], sum[4];
#pragma unroll
  for (int t = 0; t < 8; ++t) out[t] = (f32x4){0.f,0.f,0.f,0.f};
#pragma unroll
  for (int r = 0; r < 4; ++r){ m[r] = NEGINF; sum[r] = 0.f; }

  int branch, tile, q0;                         // branch: 0=win 1=comp 2=sel (gate index)
  if (bx < 128)      { branch = 2; tile = 127 - bx;  q0 = tile*16; }
  else if (bx < 160) { branch = 0; tile = 159 - bx;  q0 = WSTART + tile*16; }
  else               { branch = 1; tile = bx - 160;  q0 = tile*16; }

  if (branch == 0){
    // ================= window: keys [1536, qi]; 64-key paired iterations =================
    u16x8 qf[4];
    {
      const unsigned short* qrow = (const unsigned short*)Qw + ((size_t)h*S_LEN + q0 + c16)*HEADD + g16*8;
#pragma unroll
      for (int ks = 0; ks < 4; ++ks) qf[ks] = *(const u16x8*)(qrow + ks*32);
    }
    const unsigned short* Kb  = (const unsigned short*)Kw  + (size_t)kv*S_LEN*HEADD;
    const unsigned short* Vtb = (const unsigned short*)VwT + (size_t)kv*HEADD*S_LEN;
    const int cmax = tile >> 1;
    for (int c = wv; c <= cmax; c += 8){
      const int c1 = c + 4;
      const bool has1 = (c1 <= cmax);
      const int ko0 = WSTART + c*32;
      const int ko1 = WSTART + (has1 ? c1 : c)*32;
      u16x8 k00[4], k01[4], k10[4], k11[4];
#pragma unroll
      for (int ks = 0; ks < 4; ++ks){
        k00[ks] = *(const u16x8*)(Kb + (size_t)(ko0 + c16)*HEADD      + g16*8 + ks*32);
        k01[ks] = *(const u16x8*)(Kb + (size_t)(ko0 + 16 + c16)*HEADD + g16*8 + ks*32);
        k10[ks] = *(const u16x8*)(Kb + (size_t)(ko1 + c16)*HEADD      + g16*8 + ks*32);
        k11[ks] = *(const u16x8*)(Kb + (size_t)(ko1 + 16 + c16)*HEADD + g16*8 + ks*32);
      }
      f32x4 sa0 = {0.f,0.f,0.f,0.f}, sa1 = sa0, sa2 = sa0, sa3 = sa0;
#pragma unroll
      for (int ks = 0; ks < 4; ++ks){
        sa0 = MFMA(qf[ks], k00[ks], sa0);
        sa1 = MFMA(qf[ks], k01[ks], sa1);
        sa2 = MFMA(qf[ks], k10[ks], sa2);
        sa3 = MFMA(qf[ks], k11[ks], sa3);
      }
      // V prefetch (both sub-chunks): latency hides under the softmax chain
      u16x8 bv0[8], bv1[8];
#pragma unroll
      for (int t = 0; t < 8; ++t){
        bv0[t] = *(const u16x8*)(Vtb + (size_t)(t*16 + c16)*S_LEN + ko0 + g16*8);
        bv1[t] = *(const u16x8*)(Vtb + (size_t)(t*16 + c16)*S_LEN + ko1 + g16*8);
      }
#pragma unroll
      for (int r = 0; r < 4; ++r){
        const int row = g16*4 + r;
        const int qi = q0 + row;
        const float s0 = (ko0 + c16      <= qi) ? sa0[r]*RSQD : NEGINF;
        const float s1 = (ko0 + 16 + c16 <= qi) ? sa1[r]*RSQD : NEGINF;
        const float s2 = (has1 && ko1 + c16      <= qi) ? sa2[r]*RSQD : NEGINF;
        const float s3 = (has1 && ko1 + 16 + c16 <= qi) ? sa3[r]*RSQD : NEGINF;
        sm_step4(s0, s1, s2, s3, row, c16, m[r], sum[r], out, r, Plh, Pll);
      }
      asm volatile("s_waitcnt lgkmcnt(0)" ::: "memory");
      const u16x8 pah0 = *(const u16x8*)&Plh[c16*72 + g16*8];
      const u16x8 pal0 = *(const u16x8*)&Pll[c16*72 + g16*8];
#pragma unroll
      for (int t = 0; t < 8; ++t){
        out[t] = MFMA(pah0, bv0[t], out[t]);
        out[t] = MFMA(pal0, bv0[t], out[t]);
      }
      if (has1){
        const u16x8 pah1 = *(const u16x8*)&Plh[c16*72 + 32 + g16*8];
        const u16x8 pal1 = *(const u16x8*)&Pll[c16*72 + 32 + g16*8];
#pragma unroll
        for (int t = 0; t < 8; ++t){
          out[t] = MFMA(pah1, bv1[t], out[t]);
          out[t] = MFMA(pal1, bv1[t], out[t]);
        }
      }
    }
  } else if (branch == 1){
    // ================= compressed: 64 keys, non-causal, waves 0/1 take one chunk each ====
    // (cross-wave combine below is REQUIRED: each wave sees only half the keys — R5 bug)
    u16x8 qf[4];
    {
      const unsigned short* qrow = (const unsigned short*)Qc + ((size_t)h*S_LEN + q0 + c16)*HEADD + g16*8;
#pragma unroll
      for (int ks = 0; ks < 4; ++ks) qf[ks] = *(const u16x8*)(qrow + ks*32);
    }
    const unsigned short* ckhp = (const unsigned short*)ckh  + (size_t)kv*64*HEADD;
    const unsigned short* cklp = (const unsigned short*)ckl  + (size_t)kv*64*HEADD;
    const unsigned short* cvhp = (const unsigned short*)cvTh + (size_t)kv*HEADD*64;
    const unsigned short* cvlp = (const unsigned short*)cvTl + (size_t)kv*HEADD*64;
    for (int ch = wv; ch < 2; ch += 4){
      const int kb = ch*32;
      u16x8 bh0[4], bh1[4], bl0[4], bl1[4];
#pragma unroll
      for (int ks = 0; ks < 4; ++ks){
        bh0[ks] = *(const u16x8*)(ckhp + (size_t)(kb + c16)*HEADD      + g16*8 + ks*32);
        bh1[ks] = *(const u16x8*)(ckhp + (size_t)(kb + 16 + c16)*HEADD + g16*8 + ks*32);
        bl0[ks] = *(const u16x8*)(cklp + (size_t)(kb + c16)*HEADD      + g16*8 + ks*32);
        bl1[ks] = *(const u16x8*)(cklp + (size_t)(kb + 16 + c16)*HEADD + g16*8 + ks*32);
      }
      f32x4 sa0 = {0.f,0.f,0.f,0.f}, sa1 = {0.f,0.f,0.f,0.f};
#pragma unroll
      for (int ks = 0; ks < 4; ++ks){
        sa0 = MFMA(qf[ks], bh0[ks], sa0);
        sa0 = MFMA(qf[ks], bl0[ks], sa0);
        sa1 = MFMA(qf[ks], bh1[ks], sa1);
        sa1 = MFMA(qf[ks], bl1[ks], sa1);
      }
      // V prefetch (hi+lo) before the softmax chain
      u16x8 bvh[8], bvl[8];
#pragma unroll
      for (int t = 0; t < 8; ++t){
        bvh[t] = *(const u16x8*)(cvhp + (size_t)(t*16 + c16)*64 + kb + g16*8);
        bvl[t] = *(const u16x8*)(cvlp + (size_t)(t*16 + c16)*64 + kb + g16*8);
      }
#pragma unroll
      for (int r = 0; r < 4; ++r){
        const int row = g16*4 + r;
        sm_step4(sa0[r]*RSQD, sa1[r]*RSQD, NEGINF, NEGINF, row, c16, m[r], sum[r], out, r, Plh, Pll);
      }
      asm volatile("s_waitcnt lgkmcnt(0)" ::: "memory");
      const u16x8 pah = *(const u16x8*)&Plh[c16*72 + g16*8];
      const u16x8 pal = *(const u16x8*)&Pll[c16*72 + g16*8];
#pragma unroll
      for (int t = 0; t < 8; ++t){
        out[t] = MFMA(pah, bvh[t], out[t]);
        out[t] = MFMA(pah, bvl[t], out[t]);
        out[t] = MFMA(pal, bvh[t], out[t]);
      }
    }
  } else {
    // ================= selected: precomputed masks; 64-key paired iterations =============
    const size_t tb = (size_t)h*128 + tile;
    unsigned long long smr[4];
#pragma unroll
    for (int r = 0; r < 4; ++r) smr[r] = selm[tb*16 + g16*4 + r];
    const unsigned long long U = selU[tb];
    const int bq = tile >> 1;
    // split-fp32 Q fragments from Qs32 (hi/lo bf16 -> matches fp32-q scores)
    u16x8 qh[4], ql[4];
    {
      const float* qrow = Qs32 + (size_t)(q0 + c16)*DIMN + h*HEADD + g16*8;
#pragma unroll
      for (int ks = 0; ks < 4; ++ks){
        const float4 f0 = *(const float4*)(qrow + ks*32);
        const float4 f1 = *(const float4*)(qrow + ks*32 + 4);
        const float ff[8] = {f0.x,f0.y,f0.z,f0.w,f1.x,f1.y,f1.z,f1.w};
#pragma unroll
        for (int j = 0; j < 8; ++j){
          const unsigned short hh = f2b(ff[j]);
          qh[ks][j] = hh;
          ql[ks][j] = f2b(ff[j] - bfl(hh));
        }
      }
    }
    const unsigned short* Kb  = (const unsigned short*)Ks  + (size_t)kv*S_LEN*HEADD;
    const unsigned short* Vtb = (const unsigned short*)VsT + (size_t)kv*HEADD*S_LEN;
    // this wave's block subsequence (same ascending every-4th-selected order as before)
    unsigned long long myU = 0ull;
    {
      int cnt = 0;
      for (int b = 0; b <= bq; ++b){
        if ((U >> b) & 1ull){
          if ((cnt & 3) == wv) myU |= (1ull << b);
          ++cnt;
        }
      }
    }
    int b0 = myU ? (__ffsll((long long)myU) - 1) : -1;
    myU &= myU - 1;
    while (b0 >= 0){
      const int b1 = myU ? (__ffsll((long long)myU) - 1) : -1;
      myU &= myU - 1;
      const bool has1 = (b1 >= 0);
      const int ko0 = b0*32;
      const int ko1 = (has1 ? b1 : b0)*32;
      u16x8 k00[4], k01[4], k10[4], k11[4];
#pragma unroll
      for (int ks = 0; ks < 4; ++ks){
        k00[ks] = *(const u16x8*)(Kb + (size_t)(ko0 + c16)*HEADD      + g16*8 + ks*32);
        k01[ks] = *(const u16x8*)(Kb + (size_t)(ko0 + 16 + c16)*HEADD + g16*8 + ks*32);
        k10[ks] = *(const u16x8*)(Kb + (size_t)(ko1 + c16)*HEADD      + g16*8 + ks*32);
        k11[ks] = *(const u16x8*)(Kb + (size_t)(ko1 + 16 + c16)*HEADD + g16*8 + ks*32);
      }
      f32x4 sa0 = {0.f,0.f,0.f,0.f}, sa1 = sa0, sa2 = sa0, sa3 = sa0;
#pragma unroll
      for (int ks = 0; ks < 4; ++ks){
        sa0 = MFMA(qh[ks], k00[ks], sa0);
        sa0 = MFMA(ql[ks], k00[ks], sa0);
        sa1 = MFMA(qh[ks], k01[ks], sa1);
        sa1 = MFMA(ql[ks], k01[ks], sa1);
        sa2 = MFMA(qh[ks], k10[ks], sa2);
        sa2 = MFMA(ql[ks], k10[ks], sa2);
        sa3 = MFMA(qh[ks], k11[ks], sa3);
        sa3 = MFMA(ql[ks], k11[ks], sa3);
      }
      // V prefetch (both sub-chunks)
      u16x8 bv0[8], bv1[8];
#pragma unroll
      for (int t = 0; t < 8; ++t){
        bv0[t] = *(const u16x8*)(Vtb + (size_t)(t*16 + c16)*S_LEN + ko0 + g16*8);
        bv1[t] = *(const u16x8*)(Vtb + (size_t)(t*16 + c16)*S_LEN + ko1 + g16*8);
      }
#pragma unroll
      for (int r = 0; r < 4; ++r){
        const int row = g16*4 + r;
        const int qi = q0 + row;
        const bool sel0 = (smr[r] >> b0) & 1ull;
        const bool sel1 = has1 && ((smr[r] >> b1) & 1ull);
        const float s0 = (sel0 && (ko0 + c16      <= qi)) ? sa0[r]*RSQD : NEGINF;
        const float s1 = (sel0 && (ko0 + 16 + c16 <= qi)) ? sa1[r]*RSQD : NEGINF;
        const float s2 = (sel1 && (ko1 + c16      <= qi)) ? sa2[r]*RSQD : NEGINF;
        const float s3 = (sel1 && (ko1 + 16 + c16 <= qi)) ? sa3[r]*RSQD : NEGINF;
        sm_step4(s0, s1, s2, s3, row, c16, m[r], sum[r], out, r, Plh, Pll);
      }
      asm volatile("s_waitcnt lgkmcnt(0)" ::: "memory");
      const u16x8 pah0 = *(const u16x8*)&Plh[c16*72 + g16*8];
      const u16x8 pal0 = *(const u16x8*)&Pll[c16*72 + g16*8];
#pragma unroll
      for (int t = 0; t < 8; ++t){
        out[t] = MFMA(pah0, bv0[t], out[t]);
        out[t] = MFMA(pal0, bv0[t], out[t]);
      }
      if (has1){
        const u16x8 pah1 = *(const u16x8*)&Plh[c16*72 + 32 + g16*8];
        const u16x8 pal1 = *(const u16x8*)&Pll[c16*72 + 32 + g16*8];
#pragma unroll
        for (int t = 0; t < 8; ++t){
          out[t] = MFMA(pah1, bv1[t], out[t]);
          out[t] = MFMA(pal1, bv1[t], out[t]);
        }
      }
      b0 = myU ? (__ffsll((long long)myU) - 1) : -1;
      myU &= myU - 1;
    }
  }

  // ---- export per-wave m/sum ----
  if (c16 == 0){
#pragma unroll
    for (int r = 0; r < 4; ++r){ mS[wv][g16*4 + r] = m[r]; sumS[wv][g16*4 + r] = sum[r]; }
  }
  __syncthreads();

  // ---- per-row global max + this wave's factor; serialized fp32 accumulation ----
  float fw[4];
#pragma unroll
  for (int r = 0; r < 4; ++r){
    const int row = g16*4 + r;
    const float M = fmaxf(fmaxf(mS[0][row], mS[1][row]), fmaxf(mS[2][row], mS[3][row]));
    fw[r] = (m[r] == NEGINF) ? 0.f : __expf(m[r] - M);
  }
#pragma unroll
  for (int w = 0; w < 4; ++w){
    if (wv == w){
#pragma unroll
      for (int r = 0; r < 4; ++r){
        const int row = g16*4 + r;
#pragma unroll
        for (int t = 0; t < 8; ++t){
          const float v = fw[r] * out[t][r];
          if (w == 0) outS[row][t*16 + c16] = v;
          else        outS[row][t*16 + c16] += v;
        }
      }
    }
    __syncthreads();
  }

  // ---- final write: thread -> (row, 8 cols) ----
  {
    const int row = tid >> 4, cc0 = (tid & 15) * 8;
    bool doit = true;
    if (branch == 2) doit = (selvis[(size_t)h*128 + tile] >> row) & 1u;
    if (doit){
      const float m0 = mS[0][row], m1 = mS[1][row], m2 = mS[2][row], m3 = mS[3][row];
      const float M = fmaxf(fmaxf(m0, m1), fmaxf(m2, m3));
      const float f0 = (m0 == NEGINF) ? 0.f : __expf(m0 - M);
      const float f1 = (m1 == NEGINF) ? 0.f : __expf(m1 - M);
      const float f2 = (m2 == NEGINF) ? 0.f : __expf(m2 - M);
      const float f3 = (m3 == NEGINF) ? 0.f : __expf(m3 - M);
      const float S = f0*sumS[0][row] + f1*sumS[1][row] + f2*sumS[2][row] + f3*sumS[3][row];
      const float gate = gates[(q0+row)*3 + branch];
      const float inv = gate / S;
      float* dst = (branch == 0) ? comb : (branch == 1) ? combC : combS;
      const size_t ob = (size_t)(q0+row)*DIMN + h*HEADD + cc0;
#pragma unroll
      for (int j = 0; j < 8; ++j)
        dst[ob + j] = outS[row][cc0 + j] * inv;
    }
  }

  // ---- degenerate sel rows: exact scalar path (wave 0 only, after last barrier) ----
  if (branch == 2 && wv == 0){
    unsigned degbits = (~selvis[(size_t)h*128 + tile]) & 0xffffu;
    if (degbits){
      const bf16* Kbase = Ks + (size_t)kv*S_LEN*HEADD;
      const bf16* Vbase = Vs + (size_t)kv*S_LEN*HEADD;
      while (degbits){
        const int qq = __ffs(degbits) - 1; degbits &= degbits - 1;
        const int qi = q0 + qq;
        {
          const float* qr = Qs32 + (size_t)qi*DIMN + h*HEADD;
          qv[l] = qr[l]; qv[l+64] = qr[l+64];
        }
        asm volatile("s_waitcnt lgkmcnt(0)" ::: "memory");
        float md = NEGINF, sumd = 0.f, a0 = 0.f, a1 = 0.f;
        for (int k0 = 0; k0 <= qi; k0 += 64){
          const int key = k0 + l;
          const bool valid = key <= qi;
          const int keyc = min(key, S_LEN-1);
          float s = dot128_bf16(qv, Kbase + (size_t)keyc*HEADD) * RSQD;
          s = valid ? s : NEGINF;
          const float tmax = wave_max(s);
          const float mn = fmaxf(md, tmax);
          const float p = valid ? __expf(s - mn) : 0.f;
          const float scale = __expf(md - mn);
          sumd = sumd*scale + wave_sum(p);
          a0 *= scale; a1 *= scale;
          const unsigned* Vt = (const unsigned*)(Vbase + (size_t)k0*HEADD) + l;
#pragma unroll 8
          for (int j = 0; j < 64; ++j){
            const float pj = lane_bcast(p, j);
            const int kj = min(k0 + j, S_LEN-1) - k0;
            const unsigned u = Vt[(size_t)kj*64];
            a0 += pj * bfl(u & 0xffffu);
            a1 += pj * bfl(u >> 16);
          }
          md = mn;
        }
        const float mn = fmaxf(md, 0.f);
        const float scale = __expf(md - mn);
        sumd *= scale; a0 *= scale; a1 *= scale;
        const float ef = __expf(-mn);
        sumd += (float)(2047 - qi) * ef;
        const float2 s2 = ((const float2*)(suffV + ((size_t)kv*2049 + (qi+1))*HEADD))[l];
        a0 += ef * s2.x; a1 += ef * s2.y;
        const float g2 = gates[qi*3 + 2];
        const float inv = g2 / sumd;
        const size_t ob = (size_t)qi*DIMN + h*HEADD + 2*l;
        combS[ob]   = a0 * inv;
        combS[ob+1] = a1 * inv;
        asm volatile("s_waitcnt lgkmcnt(0)" ::: "memory");
      }
    }
  }
}

// sum three fp32 partials -> bf16
__global__ __launch_bounds__(256) void combine_kernel(const float* __restrict__ a, const float* __restrict__ b,
    const float* __restrict__ c, bf16* __restrict__ outb)
{
  const int i = blockIdx.x*blockDim.x + threadIdx.x;   // float4 index
  const float4 va = ((const float4*)a)[i];
  const float4 vb = ((const float4*)b)[i];
  const float4 vc = ((const float4*)c)[i];
  us4 r;
  r[0] = f2b(va.x + vb.x + vc.x);
  r[1] = f2b(va.y + vb.y + vc.y);
  r[2] = f2b(va.z + vb.z + vc.z);
  r[3] = f2b(va.w + vb.w + vc.w);
  ((us4*)outb)[i] = r;
}

// ---------------- host ----------------
extern "C" void kernel_launch(void* const* d_in, const int* in_sizes, int n_in,
                              void* d_out, int out_size, void* d_ws, size_t ws_size,
                              hipStream_t stream)
{
  (void)in_sizes; (void)n_in; (void)out_size;
  const float* x          = (const float*)d_in[0];
  const float* wq_win     = (const float*)d_in[1];
  const float* wk_win     = (const float*)d_in[2];
  const float* wv_win     = (const float*)d_in[3];
  const float* wq_sel     = (const float*)d_in[4];
  const float* wk_sel     = (const float*)d_in[5];
  const float* wv_sel     = (const float*)d_in[6];
  const float* wq_comp    = (const float*)d_in[7];
  const float* wk_comp    = (const float*)d_in[8];
  const float* wv_comp    = (const float*)d_in[9];
  const float* w_comp_mlp = (const float*)d_in[10];
  const float* w_gate     = (const float*)d_in[11];
  const float* w_o        = (const float*)d_in[12];
  float* outp = (float*)d_out;

  char* ws = (char*)d_ws;
  size_t o = 0;
  auto alloc = [&](size_t b)->char*{ char* p = ws + o; o += (b + 255) & ~(size_t)255; return p; };
  float* cosT = (float*)alloc((size_t)S_LEN*64*4);
  float* sinT = (float*)alloc((size_t)S_LEN*64*4);
  char*  xb_base = alloc((size_t)S_LEN*DIMN*2);
  bf16*  Xb   = (bf16*)xb_base;                       // dead after proj GEMM -> combb
  char*  wall_base = alloc((size_t)12288*DIMN*2);     // 50.33 MB
  bf16*  Wall = (bf16*)wall_base;
  char*  y_base = alloc((size_t)S_LEN*12288*2);       // 50.33 MB
  bf16*  Y    = (bf16*)y_base;
  bf16*  Qw = (bf16*)alloc((size_t)NHEAD*S_LEN*HEADD*2);
  bf16*  Qs = (bf16*)alloc((size_t)NHEAD*S_LEN*HEADD*2);
  bf16*  Qc = (bf16*)alloc((size_t)NHEAD*S_LEN*HEADD*2);
  bf16*  Kw = (bf16*)alloc((size_t)NKV*S_LEN*HEADD*2);
  bf16*  Ks = (bf16*)alloc((size_t)NKV*S_LEN*HEADD*2);
  bf16*  Kc = (bf16*)alloc((size_t)NKV*S_LEN*HEADD*2);
  bf16*  Vw = (bf16*)alloc((size_t)NKV*S_LEN*HEADD*2);
  bf16*  Vs = (bf16*)alloc((size_t)NKV*S_LEN*HEADD*2);
  bf16*  Vc = (bf16*)alloc((size_t)NKV*S_LEN*HEADD*2);
  // Qs bf16 is dead in the MFMA design (sel uses split Qs32) -> reuse for transposed V tensors
  bf16*  VwT = Qs;                                         // [NKV][HEADD][S_LEN], 4 MB
  bf16*  VsT = Qs + (size_t)NKV*S_LEN*HEADD;               // [NKV][HEADD][S_LEN], 4 MB
  // Wall dead after projection GEMM: three fp32 branch partials (exactly 50.33 MB)
  size_t e = 0;
  auto alloc2 = [&](size_t b)->char*{ char* p = wall_base + e; e += (b + 255) & ~(size_t)255; return p; };
  float* comb   = (float*)alloc2((size_t)S_LEN*DIMN*4);
  float* combC  = (float*)alloc2((size_t)S_LEN*DIMN*4);
  float* combS  = (float*)alloc2((size_t)S_LEN*DIMN*4);
  // Pre-split hi/lo bf16 buffers overlay comb/combC/combS (dead until win_mean/attn;
  // consumed by the gemm_bt3 launches which complete before step 6; stream-ordered)
  bf16* x_hi   = (bf16*)comb;                                   // 8 MB
  bf16* x_lo   = (bf16*)comb  + (size_t)S_LEN*DIMN;             // 8 MB
  bf16* wqs_hi = (bf16*)combC;                                  // 8 MB
  bf16* wqs_lo = (bf16*)combC + (size_t)S_LEN*DIMN;             // 8 MB
  bf16* wkc_hi = (bf16*)combS;                                  // 4 MB
  bf16* wkc_lo = (bf16*)combS + (size_t)1024*DIMN;              // 4 MB
  // Y dead after rope_scatter: fp32 selection chain + small late-phase buffers
  size_t y = 0;
  auto alloc3 = [&](size_t b)->char*{ char* p = y_base + y; y += (b + 255) & ~(size_t)255; return p; };
  float* Qs32   = (float*)alloc3((size_t)S_LEN*DIMN*4);
  float* Kc32   = (float*)alloc3((size_t)S_LEN*1024*4);
  char*  kc32hm_base = alloc3((size_t)NKV*S_LEN*HEADD*4);
  float* Kc32hm = (float*)kc32hm_base;                 // dead after ck32 GEMM -> wob
  float* ck32   = (float*)alloc3((size_t)512*128*4);
  bf16*  Wm     = (bf16*) alloc3((size_t)128*4096*2);
  float* cv     = (float*)alloc3((size_t)512*128*4);
  float* gates  = (float*)alloc3((size_t)S_LEN*3*4);
  float* meanvw = (float*)alloc3((size_t)NKV*HEADD*4);
  float* chunkS = (float*)alloc3((size_t)NKV*16*HEADD*4);
  float* suffV  = (float*)alloc3((size_t)NKV*2049*HEADD*4);
  bf16*  ckh    = (bf16*)alloc3((size_t)NKV*64*HEADD*2);   // split ck hi/lo (B-frag layout)
  bf16*  ckl    = (bf16*)alloc3((size_t)NKV*64*HEADD*2);
  bf16*  cvTh   = (bf16*)alloc3((size_t)NKV*HEADD*64*2);   // split cv^T hi/lo
  bf16*  cvTl   = (bf16*)alloc3((size_t)NKV*HEADD*64*2);
  unsigned long long* selm = (unsigned long long*)alloc3((size_t)NHEAD*128*16*8);  // 256 KB
  unsigned long long* selU = (unsigned long long*)alloc3((size_t)NHEAD*128*8);
  unsigned*           selvis = (unsigned*)alloc3((size_t)NHEAD*128*4);
  bf16*  wob    = (bf16*)kc32hm_base;                  // reuse: 8.4 MB bf16 in 8.4 MB fp32 region
  bf16*  combb  = (bf16*)xb_base;                      // reuse Xb
  if (o > ws_size) return;

  // 1) tables + bf16 conversions
  build_tables_kernel<<<dim3((S_LEN*64 + 255)/256), dim3(256), 0, stream>>>(cosT, sinT);
  cvt_f32_bf16<<<dim3(1024), dim3(256), 0, stream>>>(x, Xb, S_LEN*DIMN);
  {
    const float* srcs[9] = {wq_win, wk_win, wv_win, wq_sel, wk_sel, wv_sel, wq_comp, wk_comp, wv_comp};
    const int rows[9]    = {2048, 1024, 1024, 2048, 1024, 1024, 2048, 1024, 1024};
    size_t ro = 0;
    for (int i = 0; i < 9; ++i){
      cvt_f32_bf16<<<dim3(1024), dim3(256), 0, stream>>>(srcs[i], Wall + ro*DIMN, rows[i]*DIMN);
      ro += rows[i];
    }
  }
  // 2) fused QKV projection (bf16): Y[2048][12288] = Xb @ Wall^T
  gemm_bt<true><<<dim3(96, 16), dim3(256), 0, stream>>>(Xb, Wall, Y, 2048, 12288, 2048);
  // 3) RoPE + scatter into head-major bf16 q/k/v
  rope_scatter_kernel<<<dim3(S_LEN), dim3(256), 0, stream>>>(Y, cosT, sinT, Qw, Kw, Vw, Qs, Ks, Vs, Qc, Kc, Vc);
  // 3a) transposed V copies for MFMA B-fragments (overwrite dead Qs region)
  vtrans_kernel<<<dim3(32, 2, 8), dim3(256), 0, stream>>>(Vw, VwT);
  vtrans_kernel<<<dim3(32, 2, 8), dim3(256), 0, stream>>>(Vs, VsT);
  // 3b) fp32-accurate selection chain: PRE-SPLIT hi/lo once, then 3-pass bf16 GEMMs
  split_f32_kernel<<<dim3(1024), dim3(256), 0, stream>>>(x,       x_hi,   x_lo,   S_LEN*DIMN/4);
  split_f32_kernel<<<dim3(1024), dim3(256), 0, stream>>>(wq_sel,  wqs_hi, wqs_lo, S_LEN*DIMN/4);
  split_f32_kernel<<<dim3(1024), dim3(256), 0, stream>>>(wk_comp, wkc_hi, wkc_lo, 1024*DIMN/4);
  gemm_bt3<<<dim3(16, 16), dim3(256), 0, stream>>>(x_hi, x_lo, wqs_hi, wqs_lo, Qs32, 2048, 2048, 2048);
  gemm_bt3<<<dim3(8, 16),  dim3(256), 0, stream>>>(x_hi, x_lo, wkc_hi, wkc_lo, Kc32, 2048, 1024, 2048);
  rope32_kernel<<<dim3(S_LEN), dim3(256), 0, stream>>>(Qs32, cosT, sinT, 2048);
  rope32_kernel<<<dim3(S_LEN), dim3(256), 0, stream>>>(Kc32, cosT, sinT, 1024);
  khm_kernel<<<dim3(S_LEN*1024/256), dim3(256), 0, stream>>>(Kc32, Kc32hm);
  gemm_bt_split<<<dim3(1, 4), dim3(256), 0, stream>>>(Kc32hm, w_comp_mlp, ck32, 512, 128, 4096);
  // 3c) selection masks (exact scores, rank-based top-16)
  sel_select_kernel<<<dim3(128, 16), dim3(64), 0, stream>>>(Qs32, ck32, selm, selU, selvis);
  // 4) compress MLP value path (bf16 ok — smooth); wob into dead Kc32hm region
  cvt_f32_bf16<<<dim3(1024), dim3(256), 0, stream>>>(w_comp_mlp, Wm, 128*4096);
  gemm_bt<false><<<dim3(1, 4), dim3(256), 0, stream>>>(Vc, Wm, cv, 512, 128, 4096);
  cvt_f32_bf16<<<dim3(1024), dim3(256), 0, stream>>>(w_o, wob, DIMN*DIMN);
  // 4b) split-bf16 ck + transposed split-bf16 cv for the compressed MFMA branch
  comp_prep_kernel<<<dim3(256), dim3(256), 0, stream>>>(ck32, cv, ckh, ckl, cvTh, cvTl);
  // 5) gates, window mean, V suffix sums
  gates_kernel<<<dim3(S_LEN), dim3(64), 0, stream>>>(x, w_gate, gates);
  meanv_kernel<<<dim3(NKV), dim3(256), 0, stream>>>(Vw, meanvw);
  suffv_a_kernel<<<dim3(NKV, 16), dim3(256), 0, stream>>>(Vs, chunkS);
  suffv_b_kernel<<<dim3(NKV, 16), dim3(128), 0, stream>>>(Vs, chunkS, suffV);
  // 6) window-mean rows (q<1536) + fused 3-branch MFMA attention (64-key iterations)
  win_mean_kernel<<<dim3(WSTART), dim3(256), 0, stream>>>(meanvw, gates, comb);
  attn_mfma_kernel<<<dim3(16, 288), dim3(256), 0, stream>>>(Qw, Kw, VwT, Qc, ckh, ckl, cvTh, cvTl,
                                                            Qs32, Ks, VsT, Vs, suffV, gates,
                                                            selm, selU, selvis,
                                                            comb, combC, combS);
  // 7) combine partials -> bf16, then output projection
  combine_kernel<<<dim3(S_LEN*DIMN/4/256), dim3(256), 0, stream>>>(comb, combC, combS, combb);
  gemm_bt<false><<<dim3(16, 16), dim3(256), 0, stream>>>(combb, wob, outp, 2048, 2048, 2048);
}

// Round 13
// 1164.988 us; speedup vs baseline: 1.0436x; 1.0436x over previous
//
#include <hip/hip_runtime.h>
#include <hip/hip_bf16.h>
#include <math.h>

// Problem constants (B=1)
#define S_LEN  2048
#define DIMN   2048
#define NHEAD  16
#define NKV    8
#define HEADD  128
#define WSTART 1536      // S - WIN
#define RSQD   0.08838834764831845f   // 1/sqrt(128)
#define NEGINF (-INFINITY)

typedef __hip_bfloat16 bf16;
typedef __attribute__((ext_vector_type(8))) __bf16 bf16x8;
typedef __attribute__((ext_vector_type(8))) unsigned short u16x8;
typedef __attribute__((ext_vector_type(4))) unsigned short us4;
typedef __attribute__((ext_vector_type(4))) float  f32x4;

__device__ __forceinline__ float bfl(unsigned u){ u <<= 16; float f; __builtin_memcpy(&f, &u, 4); return f; }
// fp32 -> bf16 bits, RTNE
__device__ __forceinline__ unsigned short f2b(float f){
  unsigned u; __builtin_memcpy(&u, &f, 4);
  u += 0x7fff + ((u >> 16) & 1);
  return (unsigned short)(u >> 16);
}
// broadcast lane j's float via v_readlane
__device__ __forceinline__ float lane_bcast(float v, int lane){
  int i; __builtin_memcpy(&i, &v, 4);
  i = __builtin_amdgcn_readlane(i, lane);
  float f; __builtin_memcpy(&f, &i, 4);
  return f;
}

__device__ __forceinline__ float wave_max(float v){
#pragma unroll
  for (int o = 32; o; o >>= 1) v = fmaxf(v, __shfl_xor(v, o));
  return v;
}
__device__ __forceinline__ float wave_sum(float v){
#pragma unroll
  for (int o = 32; o; o >>= 1) v += __shfl_xor(v, o);
  return v;
}

// ---- DPP 16-lane butterfly reduce (row = 16 lanes on CDNA) ----
template<int CTRL>
__device__ __forceinline__ float dpp_f(float v){
  int i; __builtin_memcpy(&i, &v, 4);
  i = __builtin_amdgcn_update_dpp(i, i, CTRL, 0xf, 0xf, false);
  float f; __builtin_memcpy(&f, &i, 4);
  return f;
}
__device__ __forceinline__ float gmax16(float v){
  v = fmaxf(v, dpp_f<0xB1>(v));    // quad_perm(1,0,3,2)  xor1
  v = fmaxf(v, dpp_f<0x4E>(v));    // quad_perm(2,3,0,1)  xor2
  v = fmaxf(v, dpp_f<0x141>(v));   // row_half_mirror     (quad exchange)
  v = fmaxf(v, dpp_f<0x140>(v));   // row_mirror          (half exchange)
  return v;
}
__device__ __forceinline__ float gsum16(float v){
  v += dpp_f<0xB1>(v);
  v += dpp_f<0x4E>(v);
  v += dpp_f<0x141>(v);
  v += dpp_f<0x140>(v);
  return v;
}

__device__ __forceinline__ float dot128_bf16(const float* __restrict__ qv, const bf16* __restrict__ krow){
  const uint4* kp = (const uint4*)krow;
  float s = 0.f;
#pragma unroll
  for (int t = 0; t < 16; ++t){
    uint4 u = kp[t];
    const float* q8 = qv + t*8;
    s += q8[0]*bfl(u.x & 0xffffu) + q8[1]*bfl(u.x >> 16)
       + q8[2]*bfl(u.y & 0xffffu) + q8[3]*bfl(u.y >> 16)
       + q8[4]*bfl(u.z & 0xffffu) + q8[5]*bfl(u.z >> 16)
       + q8[6]*bfl(u.w & 0xffffu) + q8[7]*bfl(u.w >> 16);
  }
  return s;
}

// exact summation order kept (selection top-k tie behavior must match the proven kernel)
__device__ __forceinline__ float dot128_f32(const float* __restrict__ qv, const float* __restrict__ row){
  const float4* rp = (const float4*)row;
  float s = 0.f;
#pragma unroll
  for (int t = 0; t < 32; ++t){
    float4 r = rp[t];
    const float* q4 = qv + t*4;
    s += q4[0]*r.x + q4[1]*r.y + q4[2]*r.z + q4[3]*r.w;
  }
  return s;
}

// u16x8 (bf16 bits) MFMA wrapper
__device__ __forceinline__ f32x4 MFMA(u16x8 a, u16x8 b, f32x4 c){
  bf16x8 ab, bb;
  __builtin_memcpy(&ab, &a, 16);
  __builtin_memcpy(&bb, &b, 16);
  return __builtin_amdgcn_mfma_f32_16x16x32_bf16(ab, bb, c, 0, 0, 0);
}

// L2-locality supertile remap (R10, bit-identical; kept — neutral)
__device__ __forceinline__ void remap_bc_br(int& bc, int& br){
  const int GN = gridDim.x, GM = gridDim.y;
  const int lin = blockIdx.y * GN + blockIdx.x;
  const int per = GM * 8;
  const int sc = lin / per, rem = lin % per;
  br = rem % GM;
  bc = sc * 8 + rem / GM;
}

// ---------------- GEMM: C[M][N] = A[M][K] * B[N][K]^T  (bf16 in, fp32 acc) ----------------
template<bool OUT_BF16>
__global__ __launch_bounds__(256) void gemm_bt(const bf16* __restrict__ A, const bf16* __restrict__ B,
                                               void* __restrict__ Cp, int M, int N, int K)
{
  __shared__ __align__(16) bf16 As[128*32];
  __shared__ __align__(16) bf16 Bs[128*32];
  const int t = threadIdx.x;
  const int w = t >> 6, l = t & 63;
  int bc, br; remap_bc_br(bc, br);
  const int wr = w >> 1, wc = w & 1;
  f32x4 acc[4][4];
  {
    f32x4 z = {0.f, 0.f, 0.f, 0.f};
#pragma unroll
    for (int m = 0; m < 4; ++m)
#pragma unroll
      for (int n = 0; n < 4; ++n) acc[m][n] = z;
  }
  const int srow = l >> 2, scol = (l & 3) * 8;
  const int lrow = l & 15, lko = (l >> 4) * 8;

  for (int kt = 0; kt < K; kt += 32){
#pragma unroll
    for (int cc = 0; cc < 2; ++cc){
      const int c = w + cc*4;
      const bf16* gA = A + (size_t)(br*128 + c*16 + srow)*K + kt + scol;
      const bf16* gB = B + (size_t)(bc*128 + c*16 + srow)*K + kt + scol;
      __builtin_amdgcn_global_load_lds((const __attribute__((address_space(1))) void*)gA,
                                       (__attribute__((address_space(3))) void*)&As[c*512], 16, 0, 0);
      __builtin_amdgcn_global_load_lds((const __attribute__((address_space(1))) void*)gB,
                                       (__attribute__((address_space(3))) void*)&Bs[c*512], 16, 0, 0);
    }
    __syncthreads();
    bf16x8 af[4], bfr[4];
#pragma unroll
    for (int m = 0; m < 4; ++m) af[m]  = *(const bf16x8*)&As[(wr*64 + m*16 + lrow)*32 + lko];
#pragma unroll
    for (int n = 0; n < 4; ++n) bfr[n] = *(const bf16x8*)&Bs[(wc*64 + n*16 + lrow)*32 + lko];
#pragma unroll
    for (int m = 0; m < 4; ++m)
#pragma unroll
      for (int n = 0; n < 4; ++n)
        acc[m][n] = __builtin_amdgcn_mfma_f32_16x16x32_bf16(af[m], bfr[n], acc[m][n], 0, 0, 0);
    __syncthreads();
  }
  const int crow0 = br*128 + wr*64 + (l >> 4)*4;
  const int ccol  = bc*128 + wc*64 + lrow;
#pragma unroll
  for (int m = 0; m < 4; ++m)
#pragma unroll
    for (int n = 0; n < 4; ++n)
#pragma unroll
      for (int r = 0; r < 4; ++r){
        const size_t idx = (size_t)(crow0 + m*16 + r)*N + (ccol + n*16);
        if constexpr (OUT_BF16) ((bf16*)Cp)[idx] = __float2bfloat16(acc[m][n][r]);
        else                    ((float*)Cp)[idx] = acc[m][n][r];
      }
}

// ---------------- pre-split 3-pass GEMM: C = A*B^T with A,B given as hi/lo bf16 ----------------
__global__ __launch_bounds__(256) void gemm_bt3(const bf16* __restrict__ Ahg, const bf16* __restrict__ Alg,
                                                const bf16* __restrict__ Bhg, const bf16* __restrict__ Blg,
                                                float* __restrict__ C, int M, int N, int K)
{
  __shared__ __align__(16) bf16 AhS[128*32], AlS[128*32], BhS[128*32], BlS[128*32];
  const int t = threadIdx.x;
  const int w = t >> 6, l = t & 63;
  int bc, br; remap_bc_br(bc, br);
  const int wr = w >> 1, wc = w & 1;
  f32x4 acc[4][4];
  {
    f32x4 z = {0.f, 0.f, 0.f, 0.f};
#pragma unroll
    for (int m = 0; m < 4; ++m)
#pragma unroll
      for (int n = 0; n < 4; ++n) acc[m][n] = z;
  }
  const int srow = l >> 2, scol = (l & 3) * 8;
  const int lrow = l & 15, lko = (l >> 4) * 8;

  for (int kt = 0; kt < K; kt += 32){
#pragma unroll
    for (int cc = 0; cc < 2; ++cc){
      const int c = w + cc*4;
      const size_t aoff = (size_t)(br*128 + c*16 + srow)*K + kt + scol;
      const size_t boff = (size_t)(bc*128 + c*16 + srow)*K + kt + scol;
      __builtin_amdgcn_global_load_lds((const __attribute__((address_space(1))) void*)(Ahg + aoff),
                                       (__attribute__((address_space(3))) void*)&AhS[c*512], 16, 0, 0);
      __builtin_amdgcn_global_load_lds((const __attribute__((address_space(1))) void*)(Alg + aoff),
                                       (__attribute__((address_space(3))) void*)&AlS[c*512], 16, 0, 0);
      __builtin_amdgcn_global_load_lds((const __attribute__((address_space(1))) void*)(Bhg + boff),
                                       (__attribute__((address_space(3))) void*)&BhS[c*512], 16, 0, 0);
      __builtin_amdgcn_global_load_lds((const __attribute__((address_space(1))) void*)(Blg + boff),
                                       (__attribute__((address_space(3))) void*)&BlS[c*512], 16, 0, 0);
    }
    __syncthreads();
    bf16x8 ahf[4], alf[4], bhf[4], blf[4];
#pragma unroll
    for (int m = 0; m < 4; ++m){
      ahf[m] = *(const bf16x8*)&AhS[(wr*64 + m*16 + lrow)*32 + lko];
      alf[m] = *(const bf16x8*)&AlS[(wr*64 + m*16 + lrow)*32 + lko];
    }
#pragma unroll
    for (int n = 0; n < 4; ++n){
      bhf[n] = *(const bf16x8*)&BhS[(wc*64 + n*16 + lrow)*32 + lko];
      blf[n] = *(const bf16x8*)&BlS[(wc*64 + n*16 + lrow)*32 + lko];
    }
#pragma unroll
    for (int m = 0; m < 4; ++m)
#pragma unroll
      for (int n = 0; n < 4; ++n){
        acc[m][n] = __builtin_amdgcn_mfma_f32_16x16x32_bf16(ahf[m], bhf[n], acc[m][n], 0, 0, 0);
        acc[m][n] = __builtin_amdgcn_mfma_f32_16x16x32_bf16(ahf[m], blf[n], acc[m][n], 0, 0, 0);
        acc[m][n] = __builtin_amdgcn_mfma_f32_16x16x32_bf16(alf[m], bhf[n], acc[m][n], 0, 0, 0);
      }
    __syncthreads();
  }
  const int crow0 = br*128 + wr*64 + (l >> 4)*4;
  const int ccol  = bc*128 + wc*64 + lrow;
#pragma unroll
  for (int m = 0; m < 4; ++m)
#pragma unroll
    for (int n = 0; n < 4; ++n)
#pragma unroll
      for (int r = 0; r < 4; ++r)
        C[(size_t)(crow0 + m*16 + r)*N + (ccol + n*16)] = acc[m][n][r];
}

// ---------------- split-bf16 emulated-fp32 GEMM (kept for the small ck32 GEMM) ----------------
__global__ __launch_bounds__(256) void gemm_bt_split(const float* __restrict__ A, const float* __restrict__ B,
                                                     float* __restrict__ C, int M, int N, int K)
{
  __shared__ __align__(16) unsigned short Ah[128*32], Al[128*32], Bh[128*32], Bl[128*32];
  const int t = threadIdx.x;
  const int w = t >> 6, l = t & 63;
  const int bc = blockIdx.x, br = blockIdx.y;
  const int wr = w >> 1, wc = w & 1;
  f32x4 acc[4][4];
  {
    f32x4 z = {0.f, 0.f, 0.f, 0.f};
#pragma unroll
    for (int m = 0; m < 4; ++m)
#pragma unroll
      for (int n = 0; n < 4; ++n) acc[m][n] = z;
  }
  const int lrow = l & 15, lko = (l >> 4) * 8;

  for (int kt = 0; kt < K; kt += 32){
#pragma unroll
    for (int i = 0; i < 4; ++i){
      const int lin = t + i*256;
      const int row = lin >> 3;
      const int cq  = (lin & 7) * 4;
      const float4 va = *(const float4*)&A[(size_t)(br*128 + row)*K + kt + cq];
      const float4 vb = *(const float4*)&B[(size_t)(bc*128 + row)*K + kt + cq];
      const float fa[4] = {va.x, va.y, va.z, va.w};
      const float fb[4] = {vb.x, vb.y, vb.z, vb.w};
      us4 ah, al2, bh, bl2;
#pragma unroll
      for (int j = 0; j < 4; ++j){
        const unsigned short h = f2b(fa[j]); ah[j] = h; al2[j] = f2b(fa[j] - bfl(h));
        const unsigned short g = f2b(fb[j]); bh[j] = g; bl2[j] = f2b(fb[j] - bfl(g));
      }
      *(us4*)&Ah[row*32 + cq] = ah;  *(us4*)&Al[row*32 + cq] = al2;
      *(us4*)&Bh[row*32 + cq] = bh;  *(us4*)&Bl[row*32 + cq] = bl2;
    }
    __syncthreads();
    bf16x8 ahf[4], alf[4], bhf[4], blf[4];
#pragma unroll
    for (int m = 0; m < 4; ++m){
      ahf[m] = *(const bf16x8*)&Ah[(wr*64 + m*16 + lrow)*32 + lko];
      alf[m] = *(const bf16x8*)&Al[(wr*64 + m*16 + lrow)*32 + lko];
    }
#pragma unroll
    for (int n = 0; n < 4; ++n){
      bhf[n] = *(const bf16x8*)&Bh[(wc*64 + n*16 + lrow)*32 + lko];
      blf[n] = *(const bf16x8*)&Bl[(wc*64 + n*16 + lrow)*32 + lko];
    }
#pragma unroll
    for (int m = 0; m < 4; ++m)
#pragma unroll
      for (int n = 0; n < 4; ++n){
        acc[m][n] = __builtin_amdgcn_mfma_f32_16x16x32_bf16(ahf[m], bhf[n], acc[m][n], 0, 0, 0);
        acc[m][n] = __builtin_amdgcn_mfma_f32_16x16x32_bf16(ahf[m], blf[n], acc[m][n], 0, 0, 0);
        acc[m][n] = __builtin_amdgcn_mfma_f32_16x16x32_bf16(alf[m], bhf[n], acc[m][n], 0, 0, 0);
      }
    __syncthreads();
  }
  const int crow0 = br*128 + wr*64 + (l >> 4)*4;
  const int ccol  = bc*128 + wc*64 + lrow;
#pragma unroll
  for (int m = 0; m < 4; ++m)
#pragma unroll
    for (int n = 0; n < 4; ++n)
#pragma unroll
      for (int r = 0; r < 4; ++r)
        C[(size_t)(crow0 + m*16 + r)*N + (ccol + n*16)] = acc[m][n][r];
}

// ---------------- small utility kernels ----------------
__global__ void build_tables_kernel(float* __restrict__ cosT, float* __restrict__ sinT){
  const int idx = blockIdx.x*blockDim.x + threadIdx.x;
  if (idx >= S_LEN*64) return;
  const int s = idx >> 6, i = idx & 63;
  const float inv = powf(10000.f, -(float)(2*i) / 128.f);
  const float ang = (float)s * inv;
  cosT[idx] = cosf(ang);
  sinT[idx] = sinf(ang);
}

__global__ void cvt_f32_bf16(const float* __restrict__ src, bf16* __restrict__ dst, int n){
  const int stride = gridDim.x * blockDim.x;
  for (int i = blockIdx.x*blockDim.x + threadIdx.x; i < n; i += stride)
    dst[i] = __float2bfloat16(src[i]);
}

// R13: ONE launch, float4-vectorized, converts x + all 9 weights (10 compile-time ranges).
// Same __float2bfloat16 per element as the 10 scalar launches it replaces -> bit-identical.
__global__ __launch_bounds__(256) void cvt_fuse_kernel(
    const float* __restrict__ x,
    const float* __restrict__ w0, const float* __restrict__ w1, const float* __restrict__ w2,
    const float* __restrict__ w3, const float* __restrict__ w4, const float* __restrict__ w5,
    const float* __restrict__ w6, const float* __restrict__ w7, const float* __restrict__ w8,
    bf16* __restrict__ Xb, bf16* __restrict__ Wall)
{
  const int stride = gridDim.x * blockDim.x;
  for (int i = blockIdx.x*blockDim.x + threadIdx.x; i < 7340032; i += stride){
    const float* src; us4* dst; int li;
    if      (i < 1048576){ src = x;  dst = (us4*)Xb;                li = i; }
    else if (i < 2097152){ src = w0; dst = (us4*)Wall;              li = i - 1048576; }
    else if (i < 2621440){ src = w1; dst = (us4*)(Wall +  4194304); li = i - 2097152; }
    else if (i < 3145728){ src = w2; dst = (us4*)(Wall +  6291456); li = i - 2621440; }
    else if (i < 4194304){ src = w3; dst = (us4*)(Wall +  8388608); li = i - 3145728; }
    else if (i < 4718592){ src = w4; dst = (us4*)(Wall + 12582912); li = i - 4194304; }
    else if (i < 5242880){ src = w5; dst = (us4*)(Wall + 14680064); li = i - 4718592; }
    else if (i < 6291456){ src = w6; dst = (us4*)(Wall + 16777216); li = i - 5242880; }
    else if (i < 6815744){ src = w7; dst = (us4*)(Wall + 20971520); li = i - 6291456; }
    else                 { src = w8; dst = (us4*)(Wall + 23068672); li = i - 6815744; }
    const float4 v = ((const float4*)src)[li];
    us4 r;
    r[0] = __bfloat16_as_ushort(__float2bfloat16(v.x));
    r[1] = __bfloat16_as_ushort(__float2bfloat16(v.y));
    r[2] = __bfloat16_as_ushort(__float2bfloat16(v.z));
    r[3] = __bfloat16_as_ushort(__float2bfloat16(v.w));
    dst[li] = r;
  }
}

// R13: ONE launch for all three hi/lo splits (x, wq_sel, wk_comp). Same f2b formulas
// as the split_f32_kernel launches it replaces -> bit-identical.
__global__ __launch_bounds__(256) void split3_kernel(
    const float* __restrict__ xx, const float* __restrict__ wqs, const float* __restrict__ wkc,
    bf16* __restrict__ x_hi, bf16* __restrict__ x_lo,
    bf16* __restrict__ wqs_hi, bf16* __restrict__ wqs_lo,
    bf16* __restrict__ wkc_hi, bf16* __restrict__ wkc_lo)
{
  const int stride = gridDim.x * blockDim.x;
  for (int i = blockIdx.x*blockDim.x + threadIdx.x; i < 2621440; i += stride){
    const float* src; us4* dh; us4* dl; int li;
    if      (i < 1048576){ src = xx;  dh = (us4*)x_hi;   dl = (us4*)x_lo;   li = i; }
    else if (i < 2097152){ src = wqs; dh = (us4*)wqs_hi; dl = (us4*)wqs_lo; li = i - 1048576; }
    else                 { src = wkc; dh = (us4*)wkc_hi; dl = (us4*)wkc_lo; li = i - 2097152; }
    const float4 v = ((const float4*)src)[li];
    const float f[4] = {v.x, v.y, v.z, v.w};
    us4 h, l2;
#pragma unroll
    for (int j = 0; j < 4; ++j){
      const unsigned short hh = f2b(f[j]);
      h[j] = hh;
      l2[j] = f2b(f[j] - bfl(hh));
    }
    dh[li] = h;
    dl[li] = l2;
  }
}

// in-place fp32 RoPE on a [S][C] buffer (C = heads*128)
__global__ void rope32_kernel(float* __restrict__ T, const float* __restrict__ cosT,
                              const float* __restrict__ sinT, int C){
  const int s = blockIdx.x;
  float* row = T + (size_t)s*C;
  for (int p = threadIdx.x; p < (C >> 1); p += blockDim.x){
    const int i = p & 63;
    const int col = (p >> 6)*128 + 2*i;
    const float a = row[col], b = row[col+1];
    const float c = cosT[s*64 + i], sn = sinT[s*64 + i];
    row[col]   = a*c - b*sn;
    row[col+1] = a*sn + b*c;
  }
}

// [s][kv*128+d] -> [kv][s][d] fp32
__global__ void khm_kernel(const float* __restrict__ src, float* __restrict__ dst){
  const int idx = blockIdx.x*blockDim.x + threadIdx.x;
  if (idx >= S_LEN*1024) return;
  const int s = idx >> 10, c = idx & 1023;
  const int kv = c >> 7, d = c & 127;
  dst[((size_t)kv*S_LEN + s)*HEADD + d] = src[idx];
}

// Y[s][12288] -> 9 head-major bf16 tensors with RoPE on q/k
__global__ void rope_scatter_kernel(const bf16* __restrict__ Y, const float* __restrict__ cosT,
    const float* __restrict__ sinT,
    bf16* __restrict__ Qw, bf16* __restrict__ Kw, bf16* __restrict__ Vw,
    bf16* __restrict__ Qs, bf16* __restrict__ Ks, bf16* __restrict__ Vs,
    bf16* __restrict__ Qc, bf16* __restrict__ Kc, bf16* __restrict__ Vc)
{
  const int s = blockIdx.x;
  const unsigned* Yrow = (const unsigned*)(Y + (size_t)s*12288);
  for (int p = threadIdx.x; p < 6144; p += blockDim.x){
    const int col = p*2;
    bf16* dst; int base; bool isv = false;
    if (col < 4096){
      if      (col < 2048){ dst = Qw; base = 0; }
      else if (col < 3072){ dst = Kw; base = 2048; }
      else                { dst = Vw; base = 3072; isv = true; }
    } else if (col < 8192){
      if      (col < 6144){ dst = Qs; base = 4096; }
      else if (col < 7168){ dst = Ks; base = 6144; }
      else                { dst = Vs; base = 7168; isv = true; }
    } else {
      if      (col < 10240){ dst = Qc; base = 8192; }
      else if (col < 11264){ dst = Kc; base = 10240; }
      else                 { dst = Vc; base = 11264; isv = true; }
    }
    const int lc = col - base;
    const int head = lc >> 7, d = lc & 127, i = d >> 1;
    const unsigned yy = Yrow[p];
    float a = bfl(yy & 0xffffu), b = bfl(yy >> 16);
    if (!isv){
      const float c = cosT[s*64 + i], sn = sinT[s*64 + i];
      const float na = a*c - b*sn;
      b = a*sn + b*c;
      a = na;
    }
    const size_t off = ((size_t)head*S_LEN + s)*HEADD + d;
    dst[off]   = __float2bfloat16(a);
    dst[off+1] = __float2bfloat16(b);
  }
}

// [NKV][S_LEN][HEADD] bf16 -> [NKV][HEADD][S_LEN] bf16 (64x64 LDS tiles)
__global__ __launch_bounds__(256) void vtrans_kernel(const bf16* __restrict__ src, bf16* __restrict__ dst){
  __shared__ unsigned short tile[64][72];   // 72: keeps 16B-aligned rows (144B)
  const int kv = blockIdx.z;
  const int r0 = blockIdx.x*64;   // S dim
  const int c0 = blockIdx.y*64;   // D dim
  const int t = threadIdx.x;
  const int lr = t >> 2, lc = (t & 3)*16;
  const unsigned short* sp = (const unsigned short*)src + ((size_t)kv*S_LEN + r0 + lr)*HEADD + c0 + lc;
  *(u16x8*)&tile[lr][lc]     = *(const u16x8*)sp;
  *(u16x8*)&tile[lr][lc + 8] = *(const u16x8*)(sp + 8);
  __syncthreads();
  unsigned short* dp = (unsigned short*)dst + ((size_t)kv*HEADD + c0 + lr)*S_LEN + r0 + lc;
  u16x8 v0, v1;
#pragma unroll
  for (int j = 0; j < 8; ++j){ v0[j] = tile[lc + j][lr]; v1[j] = tile[lc + 8 + j][lr]; }
  *(u16x8*)dp       = v0;
  *(u16x8*)(dp + 8) = v1;
}

// ck32/cv [NKV][64][HEADD] fp32 -> hi/lo bf16 (ck as-is, cv transposed to [NKV][HEADD][64])
__global__ void comp_prep_kernel(const float* __restrict__ ck32, const float* __restrict__ cv,
    bf16* __restrict__ ckh, bf16* __restrict__ ckl, bf16* __restrict__ cvTh, bf16* __restrict__ cvTl)
{
  const int i = blockIdx.x*256 + threadIdx.x;
  if (i >= NKV*64*HEADD) return;
  const int kv = i >> 13, rem = i & 8191, key = rem >> 7, d = rem & 127;
  const float a = ck32[i];
  const unsigned short ah = f2b(a);
  ((unsigned short*)ckh)[i] = ah;
  ((unsigned short*)ckl)[i] = f2b(a - bfl(ah));
  const float b = cv[i];
  const unsigned short bh = f2b(b);
  const size_t j = ((size_t)kv*HEADD + d)*64 + key;
  ((unsigned short*)cvTh)[j] = bh;
  ((unsigned short*)cvTl)[j] = f2b(b - bfl(bh));
}

__global__ __launch_bounds__(64) void gates_kernel(const float* __restrict__ x,
    const float* __restrict__ wg, float* __restrict__ gates)
{
  const int r = blockIdx.x, l = threadIdx.x;
  const float* xr = x + (size_t)r*DIMN;
  float p0 = 0.f, p1 = 0.f, p2 = 0.f;
  for (int i = l; i < DIMN; i += 64){
    const float xv = xr[i];
    p0 += xv * wg[i];
    p1 += xv * wg[DIMN + i];
    p2 += xv * wg[2*DIMN + i];
  }
  p0 = wave_sum(p0); p1 = wave_sum(p1); p2 = wave_sum(p2);
  if (l == 0){
    const float mx = fmaxf(p0, fmaxf(p1, p2));
    const float e0 = expf(p0-mx), e1 = expf(p1-mx), e2 = expf(p2-mx);
    const float inv = 1.f/(e0+e1+e2);
    gates[r*3+0] = e0*inv; gates[r*3+1] = e1*inv; gates[r*3+2] = e2*inv;
  }
}

// block per kv; thread (d, half) reduces 256 window rows each
__global__ __launch_bounds__(256) void meanv_kernel(const bf16* __restrict__ Vw, float* __restrict__ mean_vw){
  const int kv = blockIdx.x, t = threadIdx.x;
  const int d = t & 127, half = t >> 7;
  const bf16* base = Vw + ((size_t)kv*S_LEN + WSTART + half*256)*HEADD + d;
  float acc = 0.f;
  for (int r = 0; r < 256; ++r) acc += __bfloat162float(base[(size_t)r*HEADD]);
  __shared__ float red[256];
  red[t] = acc;
  __syncthreads();
  if (!half) mean_vw[kv*HEADD + d] = (red[d] + red[128 + d]) * (1.f/512.f);
}

// suffix-sum of Vs over s, two-phase
__global__ __launch_bounds__(256) void suffv_a_kernel(const bf16* __restrict__ Vs, float* __restrict__ chunkSums){
  const int kv = blockIdx.x, ch = blockIdx.y, t = threadIdx.x;
  const int d = t & 127, half = t >> 7;
  const bf16* base = Vs + ((size_t)kv*S_LEN + ch*128 + half*64)*HEADD + d;
  float acc = 0.f;
  for (int r = 0; r < 64; ++r) acc += __bfloat162float(base[(size_t)r*HEADD]);
  __shared__ float red[256];
  red[t] = acc;
  __syncthreads();
  if (!half) chunkSums[((size_t)kv*16 + ch)*HEADD + d] = red[d] + red[128 + d];
}
__global__ __launch_bounds__(128) void suffv_b_kernel(const bf16* __restrict__ Vs,
    const float* __restrict__ chunkSums, float* __restrict__ suffV){
  const int kv = blockIdx.x, ch = blockIdx.y, d = threadIdx.x;
  float acc = 0.f;
  for (int c = ch + 1; c < 16; ++c) acc += chunkSums[((size_t)kv*16 + c)*HEADD + d];
  const int s0 = ch*128;
  for (int r = 127; r >= 0; --r){
    acc += __bfloat162float(Vs[((size_t)kv*S_LEN + s0 + r)*HEADD + d]);
    suffV[((size_t)kv*2049 + s0 + r)*HEADD + d] = acc;
  }
  if (ch == 15) suffV[((size_t)kv*2049 + 2048)*HEADD + d] = 0.f;
}

__global__ void win_mean_kernel(const float* __restrict__ mean_vw, const float* __restrict__ gates,
                                float* __restrict__ comb)
{
  const int q = blockIdx.x;
  const float g0 = gates[q*3];
  for (int c = threadIdx.x; c < DIMN; c += blockDim.x){
    const int kv = c >> 8;
    const int d  = c & 127;
    comb[(size_t)q*DIMN + c] = g0 * mean_vw[kv*HEADD + d];
  }
}

// ---------------- selection kernel: exact dot order + rank-based top-16 ----------------
__global__ __launch_bounds__(64) void sel_select_kernel(
    const float* __restrict__ Qs32, const float* __restrict__ ck32,
    unsigned long long* __restrict__ selm, unsigned long long* __restrict__ selU,
    unsigned* __restrict__ selvis)
{
  const int tile = blockIdx.x, h = blockIdx.y, kv = h >> 1, l = threadIdx.x;
  const int q0 = tile*16, bq = tile >> 1;
  __shared__ float impS[16][64];
  __shared__ unsigned short pmaskS[16][4];
  __shared__ unsigned long long vmS[16];
  const float* ckrow = ck32 + (size_t)(kv*64 + l)*HEADD;
#pragma unroll
  for (int qq = 0; qq < 16; ++qq){
    const float* qr = Qs32 + (size_t)(q0+qq)*DIMN + h*HEADD;
    impS[qq][l] = dot128_f32(qr, ckrow);
  }
  __syncthreads();
  const int row = l >> 2, part = l & 3;
  float mine[16];
#pragma unroll
  for (int j = 0; j < 16; ++j) mine[j] = impS[row][part*16 + j];
  int rk[16];
#pragma unroll
  for (int j = 0; j < 16; ++j) rk[j] = 0;
  for (int b = 0; b < 64; ++b){
    const float vb = impS[row][b];
#pragma unroll
    for (int j = 0; j < 16; ++j){
      const int idxj = part*16 + j;
      rk[j] += ((vb > mine[j]) || (vb == mine[j] && b < idxj)) ? 1 : 0;
    }
  }
  unsigned pm = 0;
#pragma unroll
  for (int j = 0; j < 16; ++j) if (rk[j] < 16) pm |= (1u << j);
  pmaskS[row][part] = (unsigned short)pm;
  __syncthreads();
  if (l < 16){
    const unsigned long long sm =
        (unsigned long long)pmaskS[l][0]
      | ((unsigned long long)pmaskS[l][1] << 16)
      | ((unsigned long long)pmaskS[l][2] << 32)
      | ((unsigned long long)pmaskS[l][3] << 48);
    selm[((size_t)h*128 + tile)*16 + l] = sm;
    vmS[l] = (bq >= 63) ? sm : (sm & ((1ull << (bq+1)) - 1ull));
  }
  __syncthreads();
  if (l == 0){
    unsigned long long U = 0ull; unsigned vis = 0u;
#pragma unroll
    for (int i = 0; i < 16; ++i){ U |= vmS[i]; vis |= (vmS[i] ? 1u : 0u) << i; }
    selU[(size_t)h*128 + tile] = U;
    selvis[(size_t)h*128 + tile] = vis;
  }
}

// ---------------- MFMA fused attention, 4-way key-split flash (R11 state) ----------------
// R6: LPT grid. R7: V-prefetch. R8: __expf. R11: K-load software pipeline.
// R12 (64-key iterations) REGRESSED (289->312us; removed VALU was fill, not critical path;
// +16 VGPR/+8KB LDS added pressure) -> reverted to this proven R11 structure.

// online-softmax step; row-group reduces are DPP (no LDS shuffles)
__device__ __forceinline__ void sm_step(float s0, float s1, int row, int c16,
                                        float& m, float& sum, f32x4* out, int r,
                                        unsigned short* Plh, unsigned short* Pll)
{
  const float mx = gmax16(fmaxf(s0, s1));
  const float mn = fmaxf(m, mx);
  float p0, p1, scale;
  if (mn == NEGINF){ p0 = 0.f; p1 = 0.f; scale = 1.f; }        // fully-masked-so-far row
  else { scale = __expf(m - mn); p0 = __expf(s0 - mn); p1 = __expf(s1 - mn); }
  const bool needscale = (mn != m);
  m = mn;
  sum = sum*scale + gsum16(p0 + p1);
  if (needscale){
#pragma unroll
    for (int t = 0; t < 8; ++t) out[t][r] *= scale;
  }
  const unsigned short h0 = f2b(p0), h1 = f2b(p1);
  Plh[row*40 + c16]      = h0;
  Plh[row*40 + 16 + c16] = h1;
  Pll[row*40 + c16]      = f2b(p0 - bfl(h0));
  Pll[row*40 + 16 + c16] = f2b(p1 - bfl(h1));
}

__global__ __launch_bounds__(256) void attn_mfma_kernel(
    const bf16* __restrict__ Qw, const bf16* __restrict__ Kw, const bf16* __restrict__ VwT,
    const bf16* __restrict__ Qc, const bf16* __restrict__ ckh, const bf16* __restrict__ ckl,
    const bf16* __restrict__ cvTh, const bf16* __restrict__ cvTl,
    const float* __restrict__ Qs32, const bf16* __restrict__ Ks, const bf16* __restrict__ VsT,
    const bf16* __restrict__ Vs,
    const float* __restrict__ suffV, const float* __restrict__ gates,
    const unsigned long long* __restrict__ selm, const unsigned long long* __restrict__ selU,
    const unsigned* __restrict__ selvis,
    float* __restrict__ comb, float* __restrict__ combC, float* __restrict__ combS)
{
  const int h = blockIdx.x, kv = h >> 1;     // heads on X (dispatch-fastest axis)
  const int tid = threadIdx.x, wv = tid >> 6, l = tid & 63;
  const int g16 = l >> 4, c16 = l & 15;
  const int bx = blockIdx.y;                 // branch/tile on Y

  __shared__ unsigned short PlhS[4][640], PllS[4][640];
  __shared__ float outS[16][132];               // +4 pad: spreads rows across banks
  __shared__ float mS[4][16], sumS[4][16];
  __shared__ float qv[128];
  unsigned short* Plh = PlhS[wv];
  unsigned short* Pll = PllS[wv];

  f32x4 out[8];
  float m[4], sum[4];
#pragma unroll
  for (int t = 0; t < 8; ++t) out[t] = (f32x4){0.f,0.f,0.f,0.f};
#pragma unroll
  for (int r = 0; r < 4; ++r){ m[r] = NEGINF; sum[r] = 0.f; }

  int branch, tile, q0;                         // branch: 0=win 1=comp 2=sel (gate index)
  if (bx < 128)      { branch = 2; tile = 127 - bx;  q0 = tile*16; }
  else if (bx < 160) { branch = 0; tile = 159 - bx;  q0 = WSTART + tile*16; }
  else               { branch = 1; tile = bx - 160;  q0 = tile*16; }

  if (branch == 0){
    // ================= window: keys [1536, qi], chunks round-robin; K pipelined =========
    u16x8 qf[4];
    {
      const unsigned short* qrow = (const unsigned short*)Qw + ((size_t)h*S_LEN + q0 + c16)*HEADD + g16*8;
#pragma unroll
      for (int ks = 0; ks < 4; ++ks) qf[ks] = *(const u16x8*)(qrow + ks*32);
    }
    const unsigned short* Kb  = (const unsigned short*)Kw  + (size_t)kv*S_LEN*HEADD;
    const unsigned short* Vtb = (const unsigned short*)VwT + (size_t)kv*HEADD*S_LEN;
    const int cmax = tile >> 1;
    u16x8 kc0[4], kc1[4], kn0[4], kn1[4];
    int c = wv;
    if (c <= cmax){
      const int kb = WSTART + c*32;
#pragma unroll
      for (int ks = 0; ks < 4; ++ks){
        kc0[ks] = *(const u16x8*)(Kb + (size_t)(kb + c16)*HEADD      + g16*8 + ks*32);
        kc1[ks] = *(const u16x8*)(Kb + (size_t)(kb + 16 + c16)*HEADD + g16*8 + ks*32);
      }
    }
    for (; c <= cmax; c += 4){
      const int kb = WSTART + c*32;
      // V prefetch: issue early so HBM/L2 latency hides under the softmax chain
      u16x8 bv[8];
#pragma unroll
      for (int t = 0; t < 8; ++t)
        bv[t] = *(const u16x8*)(Vtb + (size_t)(t*16 + c16)*S_LEN + kb + g16*8);
      f32x4 sa0 = {0.f,0.f,0.f,0.f}, sa1 = {0.f,0.f,0.f,0.f};
#pragma unroll
      for (int ks = 0; ks < 4; ++ks){
        sa0 = MFMA(qf[ks], kc0[ks], sa0);
        sa1 = MFMA(qf[ks], kc1[ks], sa1);
      }
      // K pipeline: issue next chunk's K now — softmax+PV covers its latency
      const int cn = c + 4;
      const int kbn = WSTART + min(cn, cmax)*32;
      if (cn <= cmax){
#pragma unroll
        for (int ks = 0; ks < 4; ++ks){
          kn0[ks] = *(const u16x8*)(Kb + (size_t)(kbn + c16)*HEADD      + g16*8 + ks*32);
          kn1[ks] = *(const u16x8*)(Kb + (size_t)(kbn + 16 + c16)*HEADD + g16*8 + ks*32);
        }
      }
#pragma unroll
      for (int r = 0; r < 4; ++r){
        const int row = g16*4 + r;
        const int qi = q0 + row;
        const float s0 = (kb + c16      <= qi) ? sa0[r]*RSQD : NEGINF;
        const float s1 = (kb + 16 + c16 <= qi) ? sa1[r]*RSQD : NEGINF;
        sm_step(s0, s1, row, c16, m[r], sum[r], out, r, Plh, Pll);
      }
      asm volatile("s_waitcnt lgkmcnt(0)" ::: "memory");
      const u16x8 pah = *(const u16x8*)&Plh[c16*40 + g16*8];
      const u16x8 pal = *(const u16x8*)&Pll[c16*40 + g16*8];
#pragma unroll
      for (int t = 0; t < 8; ++t){
        out[t] = MFMA(pah, bv[t], out[t]);
        out[t] = MFMA(pal, bv[t], out[t]);
      }
#pragma unroll
      for (int ks = 0; ks < 4; ++ks){ kc0[ks] = kn0[ks]; kc1[ks] = kn1[ks]; }
    }
  } else if (branch == 1){
    // ================= compressed: 64 keys, non-causal, waves 0/1 take one chunk each ====
    // (cross-wave combine below is REQUIRED: each wave sees only half the keys — R5 bug)
    u16x8 qf[4];
    {
      const unsigned short* qrow = (const unsigned short*)Qc + ((size_t)h*S_LEN + q0 + c16)*HEADD + g16*8;
#pragma unroll
      for (int ks = 0; ks < 4; ++ks) qf[ks] = *(const u16x8*)(qrow + ks*32);
    }
    const unsigned short* ckhp = (const unsigned short*)ckh  + (size_t)kv*64*HEADD;
    const unsigned short* cklp = (const unsigned short*)ckl  + (size_t)kv*64*HEADD;
    const unsigned short* cvhp = (const unsigned short*)cvTh + (size_t)kv*HEADD*64;
    const unsigned short* cvlp = (const unsigned short*)cvTl + (size_t)kv*HEADD*64;
    for (int ch = wv; ch < 2; ch += 4){
      const int kb = ch*32;
      u16x8 bh0[4], bh1[4], bl0[4], bl1[4];
#pragma unroll
      for (int ks = 0; ks < 4; ++ks){
        bh0[ks] = *(const u16x8*)(ckhp + (size_t)(kb + c16)*HEADD      + g16*8 + ks*32);
        bh1[ks] = *(const u16x8*)(ckhp + (size_t)(kb + 16 + c16)*HEADD + g16*8 + ks*32);
        bl0[ks] = *(const u16x8*)(cklp + (size_t)(kb + c16)*HEADD      + g16*8 + ks*32);
        bl1[ks] = *(const u16x8*)(cklp + (size_t)(kb + 16 + c16)*HEADD + g16*8 + ks*32);
      }
      f32x4 sa0 = {0.f,0.f,0.f,0.f}, sa1 = {0.f,0.f,0.f,0.f};
#pragma unroll
      for (int ks = 0; ks < 4; ++ks){
        sa0 = MFMA(qf[ks], bh0[ks], sa0);
        sa0 = MFMA(qf[ks], bl0[ks], sa0);
        sa1 = MFMA(qf[ks], bh1[ks], sa1);
        sa1 = MFMA(qf[ks], bl1[ks], sa1);
      }
      // V prefetch (hi+lo) before the softmax chain
      u16x8 bvh[8], bvl[8];
#pragma unroll
      for (int t = 0; t < 8; ++t){
        bvh[t] = *(const u16x8*)(cvhp + (size_t)(t*16 + c16)*64 + kb + g16*8);
        bvl[t] = *(const u16x8*)(cvlp + (size_t)(t*16 + c16)*64 + kb + g16*8);
      }
#pragma unroll
      for (int r = 0; r < 4; ++r){
        const int row = g16*4 + r;
        sm_step(sa0[r]*RSQD, sa1[r]*RSQD, row, c16, m[r], sum[r], out, r, Plh, Pll);
      }
      asm volatile("s_waitcnt lgkmcnt(0)" ::: "memory");
      const u16x8 pah = *(const u16x8*)&Plh[c16*40 + g16*8];
      const u16x8 pal = *(const u16x8*)&Pll[c16*40 + g16*8];
#pragma unroll
      for (int t = 0; t < 8; ++t){
        out[t] = MFMA(pah, bvh[t], out[t]);
        out[t] = MFMA(pah, bvl[t], out[t]);
        out[t] = MFMA(pal, bvh[t], out[t]);
      }
    }
  } else {
    // ================= selected: precomputed masks, K pipelined over my-block list =======
    const size_t tb = (size_t)h*128 + tile;
    unsigned long long smr[4];
#pragma unroll
    for (int r = 0; r < 4; ++r) smr[r] = selm[tb*16 + g16*4 + r];
    const unsigned long long U = selU[tb];
    const int bq = tile >> 1;
    // split-fp32 Q fragments from Qs32 (hi/lo bf16 -> matches fp32-q scores)
    u16x8 qh[4], ql[4];
    {
      const float* qrow = Qs32 + (size_t)(q0 + c16)*DIMN + h*HEADD + g16*8;
#pragma unroll
      for (int ks = 0; ks < 4; ++ks){
        const float4 f0 = *(const float4*)(qrow + ks*32);
        const float4 f1 = *(const float4*)(qrow + ks*32 + 4);
        const float ff[8] = {f0.x,f0.y,f0.z,f0.w,f1.x,f1.y,f1.z,f1.w};
#pragma unroll
        for (int j = 0; j < 8; ++j){
          const unsigned short hh = f2b(ff[j]);
          qh[ks][j] = hh;
          ql[ks][j] = f2b(ff[j] - bfl(hh));
        }
      }
    }
    const unsigned short* Kb  = (const unsigned short*)Ks  + (size_t)kv*S_LEN*HEADD;
    const unsigned short* Vtb = (const unsigned short*)VsT + (size_t)kv*HEADD*S_LEN;
    // this wave's block subsequence (same ascending every-4th-selected order as before)
    unsigned long long myU = 0ull;
    {
      int cnt = 0;
      for (int b = 0; b <= bq; ++b){
        if ((U >> b) & 1ull){
          if ((cnt & 3) == wv) myU |= (1ull << b);
          ++cnt;
        }
      }
    }
    u16x8 kc0[4], kc1[4], kn0[4], kn1[4];
    int b = myU ? (__ffsll((long long)myU) - 1) : -1;
    myU &= myU - 1;
    if (b >= 0){
      const int kb = b*32;
#pragma unroll
      for (int ks = 0; ks < 4; ++ks){
        kc0[ks] = *(const u16x8*)(Kb + (size_t)(kb + c16)*HEADD      + g16*8 + ks*32);
        kc1[ks] = *(const u16x8*)(Kb + (size_t)(kb + 16 + c16)*HEADD + g16*8 + ks*32);
      }
    }
    while (b >= 0){
      const int kb = b*32;
      // V prefetch
      u16x8 bv[8];
#pragma unroll
      for (int t = 0; t < 8; ++t)
        bv[t] = *(const u16x8*)(Vtb + (size_t)(t*16 + c16)*S_LEN + kb + g16*8);
      f32x4 sa0 = {0.f,0.f,0.f,0.f}, sa1 = {0.f,0.f,0.f,0.f};
#pragma unroll
      for (int ks = 0; ks < 4; ++ks){
        sa0 = MFMA(qh[ks], kc0[ks], sa0);
        sa0 = MFMA(ql[ks], kc0[ks], sa0);
        sa1 = MFMA(qh[ks], kc1[ks], sa1);
        sa1 = MFMA(ql[ks], kc1[ks], sa1);
      }
      // K pipeline: issue next block's K now
      const int bn = myU ? (__ffsll((long long)myU) - 1) : -1;
      myU &= myU - 1;
      if (bn >= 0){
        const int kbn = bn*32;
#pragma unroll
        for (int ks = 0; ks < 4; ++ks){
          kn0[ks] = *(const u16x8*)(Kb + (size_t)(kbn + c16)*HEADD      + g16*8 + ks*32);
          kn1[ks] = *(const u16x8*)(Kb + (size_t)(kbn + 16 + c16)*HEADD + g16*8 + ks*32);
        }
      }
#pragma unroll
      for (int r = 0; r < 4; ++r){
        const int row = g16*4 + r;
        const int qi = q0 + row;
        const bool selr = (smr[r] >> b) & 1ull;
        const float s0 = (selr && (kb + c16      <= qi)) ? sa0[r]*RSQD : NEGINF;
        const float s1 = (selr && (kb + 16 + c16 <= qi)) ? sa1[r]*RSQD : NEGINF;
        sm_step(s0, s1, row, c16, m[r], sum[r], out, r, Plh, Pll);
      }
      asm volatile("s_waitcnt lgkmcnt(0)" ::: "memory");
      const u16x8 pah = *(const u16x8*)&Plh[c16*40 + g16*8];
      const u16x8 pal = *(const u16x8*)&Pll[c16*40 + g16*8];
#pragma unroll
      for (int t = 0; t < 8; ++t){
        out[t] = MFMA(pah, bv[t], out[t]);
        out[t] = MFMA(pal, bv[t], out[t]);
      }
#pragma unroll
      for (int ks = 0; ks < 4; ++ks){ kc0[ks] = kn0[ks]; kc1[ks] = kn1[ks]; }
      b = bn;
    }
  }

  // ---- export per-wave m/sum ----
  if (c16 == 0){
#pragma unroll
    for (int r = 0; r < 4; ++r){ mS[wv][g16*4 + r] = m[r]; sumS[wv][g16*4 + r] = sum[r]; }
  }
  __syncthreads();

  // ---- per-row global max + this wave's factor; serialized fp32 accumulation ----
  float fw[4];
#pragma unroll
  for (int r = 0; r < 4; ++r){
    const int row = g16*4 + r;
    const float M = fmaxf(fmaxf(mS[0][row], mS[1][row]), fmaxf(mS[2][row], mS[3][row]));
    fw[r] = (m[r] == NEGINF) ? 0.f : __expf(m[r] - M);
  }
#pragma unroll
  for (int w = 0; w < 4; ++w){
    if (wv == w){
#pragma unroll
      for (int r = 0; r < 4; ++r){
        const int row = g16*4 + r;
#pragma unroll
        for (int t = 0; t < 8; ++t){
          const float v = fw[r] * out[t][r];
          if (w == 0) outS[row][t*16 + c16] = v;
          else        outS[row][t*16 + c16] += v;
        }
      }
    }
    __syncthreads();
  }

  // ---- final write: thread -> (row, 8 cols) ----
  {
    const int row = tid >> 4, cc0 = (tid & 15) * 8;
    bool doit = true;
    if (branch == 2) doit = (selvis[(size_t)h*128 + tile] >> row) & 1u;
    if (doit){
      const float m0 = mS[0][row], m1 = mS[1][row], m2 = mS[2][row], m3 = mS[3][row];
      const float M = fmaxf(fmaxf(m0, m1), fmaxf(m2, m3));
      const float f0 = (m0 == NEGINF) ? 0.f : __expf(m0 - M);
      const float f1 = (m1 == NEGINF) ? 0.f : __expf(m1 - M);
      const float f2 = (m2 == NEGINF) ? 0.f : __expf(m2 - M);
      const float f3 = (m3 == NEGINF) ? 0.f : __expf(m3 - M);
      const float S = f0*sumS[0][row] + f1*sumS[1][row] + f2*sumS[2][row] + f3*sumS[3][row];
      const float gate = gates[(q0+row)*3 + branch];
      const float inv = gate / S;
      float* dst = (branch == 0) ? comb : (branch == 1) ? combC : combS;
      const size_t ob = (size_t)(q0+row)*DIMN + h*HEADD + cc0;
#pragma unroll
      for (int j = 0; j < 8; ++j)
        dst[ob + j] = outS[row][cc0 + j] * inv;
    }
  }

  // ---- degenerate sel rows: exact scalar path (wave 0 only, after last barrier) ----
  if (branch == 2 && wv == 0){
    unsigned degbits = (~selvis[(size_t)h*128 + tile]) & 0xffffu;
    if (degbits){
      const bf16* Kbase = Ks + (size_t)kv*S_LEN*HEADD;
      const bf16* Vbase = Vs + (size_t)kv*S_LEN*HEADD;
      while (degbits){
        const int qq = __ffs(degbits) - 1; degbits &= degbits - 1;
        const int qi = q0 + qq;
        {
          const float* qr = Qs32 + (size_t)qi*DIMN + h*HEADD;
          qv[l] = qr[l]; qv[l+64] = qr[l+64];
        }
        asm volatile("s_waitcnt lgkmcnt(0)" ::: "memory");
        float md = NEGINF, sumd = 0.f, a0 = 0.f, a1 = 0.f;
        for (int k0 = 0; k0 <= qi; k0 += 64){
          const int key = k0 + l;
          const bool valid = key <= qi;
          const int keyc = min(key, S_LEN-1);
          float s = dot128_bf16(qv, Kbase + (size_t)keyc*HEADD) * RSQD;
          s = valid ? s : NEGINF;
          const float tmax = wave_max(s);
          const float mn = fmaxf(md, tmax);
          const float p = valid ? __expf(s - mn) : 0.f;
          const float scale = __expf(md - mn);
          sumd = sumd*scale + wave_sum(p);
          a0 *= scale; a1 *= scale;
          const unsigned* Vt = (const unsigned*)(Vbase + (size_t)k0*HEADD) + l;
#pragma unroll 8
          for (int j = 0; j < 64; ++j){
            const float pj = lane_bcast(p, j);
            const int kj = min(k0 + j, S_LEN-1) - k0;
            const unsigned u = Vt[(size_t)kj*64];
            a0 += pj * bfl(u & 0xffffu);
            a1 += pj * bfl(u >> 16);
          }
          md = mn;
        }
        const float mn = fmaxf(md, 0.f);
        const float scale = __expf(md - mn);
        sumd *= scale; a0 *= scale; a1 *= scale;
        const float ef = __expf(-mn);
        sumd += (float)(2047 - qi) * ef;
        const float2 s2 = ((const float2*)(suffV + ((size_t)kv*2049 + (qi+1))*HEADD))[l];
        a0 += ef * s2.x; a1 += ef * s2.y;
        const float g2 = gates[qi*3 + 2];
        const float inv = g2 / sumd;
        const size_t ob = (size_t)qi*DIMN + h*HEADD + 2*l;
        combS[ob]   = a0 * inv;
        combS[ob+1] = a1 * inv;
        asm volatile("s_waitcnt lgkmcnt(0)" ::: "memory");
      }
    }
  }
}

// sum three fp32 partials -> bf16
__global__ __launch_bounds__(256) void combine_kernel(const float* __restrict__ a, const float* __restrict__ b,
    const float* __restrict__ c, bf16* __restrict__ outb)
{
  const int i = blockIdx.x*blockDim.x + threadIdx.x;   // float4 index
  const float4 va = ((const float4*)a)[i];
  const float4 vb = ((const float4*)b)[i];
  const float4 vc = ((const float4*)c)[i];
  us4 r;
  r[0] = f2b(va.x + vb.x + vc.x);
  r[1] = f2b(va.y + vb.y + vc.y);
  r[2] = f2b(va.z + vb.z + vc.z);
  r[3] = f2b(va.w + vb.w + vc.w);
  ((us4*)outb)[i] = r;
}

// ---------------- host ----------------
extern "C" void kernel_launch(void* const* d_in, const int* in_sizes, int n_in,
                              void* d_out, int out_size, void* d_ws, size_t ws_size,
                              hipStream_t stream)
{
  (void)in_sizes; (void)n_in; (void)out_size;
  const float* x          = (const float*)d_in[0];
  const float* wq_win     = (const float*)d_in[1];
  const float* wk_win     = (const float*)d_in[2];
  const float* wv_win     = (const float*)d_in[3];
  const float* wq_sel     = (const float*)d_in[4];
  const float* wk_sel     = (const float*)d_in[5];
  const float* wv_sel     = (const float*)d_in[6];
  const float* wq_comp    = (const float*)d_in[7];
  const float* wk_comp    = (const float*)d_in[8];
  const float* wv_comp    = (const float*)d_in[9];
  const float* w_comp_mlp = (const float*)d_in[10];
  const float* w_gate     = (const float*)d_in[11];
  const float* w_o        = (const float*)d_in[12];
  float* outp = (float*)d_out;

  char* ws = (char*)d_ws;
  size_t o = 0;
  auto alloc = [&](size_t b)->char*{ char* p = ws + o; o += (b + 255) & ~(size_t)255; return p; };
  float* cosT = (float*)alloc((size_t)S_LEN*64*4);
  float* sinT = (float*)alloc((size_t)S_LEN*64*4);
  char*  xb_base = alloc((size_t)S_LEN*DIMN*2);
  bf16*  Xb   = (bf16*)xb_base;                       // dead after proj GEMM -> combb
  char*  wall_base = alloc((size_t)12288*DIMN*2);     // 50.33 MB
  bf16*  Wall = (bf16*)wall_base;
  char*  y_base = alloc((size_t)S_LEN*12288*2);       // 50.33 MB
  bf16*  Y    = (bf16*)y_base;
  bf16*  Qw = (bf16*)alloc((size_t)NHEAD*S_LEN*HEADD*2);
  bf16*  Qs = (bf16*)alloc((size_t)NHEAD*S_LEN*HEADD*2);
  bf16*  Qc = (bf16*)alloc((size_t)NHEAD*S_LEN*HEADD*2);
  bf16*  Kw = (bf16*)alloc((size_t)NKV*S_LEN*HEADD*2);
  bf16*  Ks = (bf16*)alloc((size_t)NKV*S_LEN*HEADD*2);
  bf16*  Kc = (bf16*)alloc((size_t)NKV*S_LEN*HEADD*2);
  bf16*  Vw = (bf16*)alloc((size_t)NKV*S_LEN*HEADD*2);
  bf16*  Vs = (bf16*)alloc((size_t)NKV*S_LEN*HEADD*2);
  bf16*  Vc = (bf16*)alloc((size_t)NKV*S_LEN*HEADD*2);
  // Qs bf16 is dead in the MFMA design (sel uses split Qs32) -> reuse for transposed V tensors
  bf16*  VwT = Qs;                                         // [NKV][HEADD][S_LEN], 4 MB
  bf16*  VsT = Qs + (size_t)NKV*S_LEN*HEADD;               // [NKV][HEADD][S_LEN], 4 MB
  // Wall dead after projection GEMM: three fp32 branch partials (exactly 50.33 MB)
  size_t e = 0;
  auto alloc2 = [&](size_t b)->char*{ char* p = wall_base + e; e += (b + 255) & ~(size_t)255; return p; };
  float* comb   = (float*)alloc2((size_t)S_LEN*DIMN*4);
  float* combC  = (float*)alloc2((size_t)S_LEN*DIMN*4);
  float* combS  = (float*)alloc2((size_t)S_LEN*DIMN*4);
  // Pre-split hi/lo bf16 buffers overlay comb/combC/combS (dead until win_mean/attn;
  // consumed by the gemm_bt3 launches which complete before step 6; stream-ordered)
  bf16* x_hi   = (bf16*)comb;                                   // 8 MB
  bf16* x_lo   = (bf16*)comb  + (size_t)S_LEN*DIMN;             // 8 MB
  bf16* wqs_hi = (bf16*)combC;                                  // 8 MB
  bf16* wqs_lo = (bf16*)combC + (size_t)S_LEN*DIMN;             // 8 MB
  bf16* wkc_hi = (bf16*)combS;                                  // 4 MB
  bf16* wkc_lo = (bf16*)combS + (size_t)1024*DIMN;              // 4 MB
  // Y dead after rope_scatter: fp32 selection chain + small late-phase buffers
  size_t y = 0;
  auto alloc3 = [&](size_t b)->char*{ char* p = y_base + y; y += (b + 255) & ~(size_t)255; return p; };
  float* Qs32   = (float*)alloc3((size_t)S_LEN*DIMN*4);
  float* Kc32   = (float*)alloc3((size_t)S_LEN*1024*4);
  char*  kc32hm_base = alloc3((size_t)NKV*S_LEN*HEADD*4);
  float* Kc32hm = (float*)kc32hm_base;                 // dead after ck32 GEMM -> wob
  float* ck32   = (float*)alloc3((size_t)512*128*4);
  bf16*  Wm     = (bf16*) alloc3((size_t)128*4096*2);
  float* cv     = (float*)alloc3((size_t)512*128*4);
  float* gates  = (float*)alloc3((size_t)S_LEN*3*4);
  float* meanvw = (float*)alloc3((size_t)NKV*HEADD*4);
  float* chunkS = (float*)alloc3((size_t)NKV*16*HEADD*4);
  float* suffV  = (float*)alloc3((size_t)NKV*2049*HEADD*4);
  bf16*  ckh    = (bf16*)alloc3((size_t)NKV*64*HEADD*2);   // split ck hi/lo (B-frag layout)
  bf16*  ckl    = (bf16*)alloc3((size_t)NKV*64*HEADD*2);
  bf16*  cvTh   = (bf16*)alloc3((size_t)NKV*HEADD*64*2);   // split cv^T hi/lo
  bf16*  cvTl   = (bf16*)alloc3((size_t)NKV*HEADD*64*2);
  unsigned long long* selm = (unsigned long long*)alloc3((size_t)NHEAD*128*16*8);  // 256 KB
  unsigned long long* selU = (unsigned long long*)alloc3((size_t)NHEAD*128*8);
  unsigned*           selvis = (unsigned*)alloc3((size_t)NHEAD*128*4);
  bf16*  wob    = (bf16*)kc32hm_base;                  // reuse: 8.4 MB bf16 in 8.4 MB fp32 region
  bf16*  combb  = (bf16*)xb_base;                      // reuse Xb
  if (o > ws_size) return;

  // 1) tables + FUSED vectorized bf16 conversions (x + 9 weights, one launch — R13)
  build_tables_kernel<<<dim3((S_LEN*64 + 255)/256), dim3(256), 0, stream>>>(cosT, sinT);
  cvt_fuse_kernel<<<dim3(2048), dim3(256), 0, stream>>>(x, wq_win, wk_win, wv_win,
                                                        wq_sel, wk_sel, wv_sel,
                                                        wq_comp, wk_comp, wv_comp,
                                                        Xb, Wall);
  // 2) fused QKV projection (bf16): Y[2048][12288] = Xb @ Wall^T
  gemm_bt<true><<<dim3(96, 16), dim3(256), 0, stream>>>(Xb, Wall, Y, 2048, 12288, 2048);
  // 3) RoPE + scatter into head-major bf16 q/k/v
  rope_scatter_kernel<<<dim3(S_LEN), dim3(256), 0, stream>>>(Y, cosT, sinT, Qw, Kw, Vw, Qs, Ks, Vs, Qc, Kc, Vc);
  // 3a) transposed V copies for MFMA B-fragments (overwrite dead Qs region)
  vtrans_kernel<<<dim3(32, 2, 8), dim3(256), 0, stream>>>(Vw, VwT);
  vtrans_kernel<<<dim3(32, 2, 8), dim3(256), 0, stream>>>(Vs, VsT);
  // 3b) fp32-accurate selection chain: FUSED pre-split (one launch — R13), then 3-pass GEMMs
  split3_kernel<<<dim3(1024), dim3(256), 0, stream>>>(x, wq_sel, wk_comp,
                                                      x_hi, x_lo, wqs_hi, wqs_lo, wkc_hi, wkc_lo);
  gemm_bt3<<<dim3(16, 16), dim3(256), 0, stream>>>(x_hi, x_lo, wqs_hi, wqs_lo, Qs32, 2048, 2048, 2048);
  gemm_bt3<<<dim3(8, 16),  dim3(256), 0, stream>>>(x_hi, x_lo, wkc_hi, wkc_lo, Kc32, 2048, 1024, 2048);
  rope32_kernel<<<dim3(S_LEN), dim3(256), 0, stream>>>(Qs32, cosT, sinT, 2048);
  rope32_kernel<<<dim3(S_LEN), dim3(256), 0, stream>>>(Kc32, cosT, sinT, 1024);
  khm_kernel<<<dim3(S_LEN*1024/256), dim3(256), 0, stream>>>(Kc32, Kc32hm);
  gemm_bt_split<<<dim3(1, 4), dim3(256), 0, stream>>>(Kc32hm, w_comp_mlp, ck32, 512, 128, 4096);
  // 3c) selection masks (exact scores, rank-based top-16)
  sel_select_kernel<<<dim3(128, 16), dim3(64), 0, stream>>>(Qs32, ck32, selm, selU, selvis);
  // 4) compress MLP value path (bf16 ok — smooth); wob into dead Kc32hm region
  cvt_f32_bf16<<<dim3(1024), dim3(256), 0, stream>>>(w_comp_mlp, Wm, 128*4096);
  gemm_bt<false><<<dim3(1, 4), dim3(256), 0, stream>>>(Vc, Wm, cv, 512, 128, 4096);
  cvt_f32_bf16<<<dim3(1024), dim3(256), 0, stream>>>(w_o, wob, DIMN*DIMN);
  // 4b) split-bf16 ck + transposed split-bf16 cv for the compressed MFMA branch
  comp_prep_kernel<<<dim3(256), dim3(256), 0, stream>>>(ck32, cv, ckh, ckl, cvTh, cvTl);
  // 5) gates, window mean, V suffix sums
  gates_kernel<<<dim3(S_LEN), dim3(64), 0, stream>>>(x, w_gate, gates);
  meanv_kernel<<<dim3(NKV), dim3(256), 0, stream>>>(Vw, meanvw);
  suffv_a_kernel<<<dim3(NKV, 16), dim3(256), 0, stream>>>(Vs, chunkS);
  suffv_b_kernel<<<dim3(NKV, 16), dim3(128), 0, stream>>>(Vs, chunkS, suffV);
  // 6) window-mean rows (q<1536) + fused 3-branch MFMA attention (R11 structure)
  win_mean_kernel<<<dim3(WSTART), dim3(256), 0, stream>>>(meanvw, gates, comb);
  attn_mfma_kernel<<<dim3(16, 288), dim3(256), 0, stream>>>(Qw, Kw, VwT, Qc, ckh, ckl, cvTh, cvTl,
                                                            Qs32, Ks, VsT, Vs, suffV, gates,
                                                            selm, selU, selvis,
                                                            comb, combC, combS);
  // 7) combine partials -> bf16, then output projection
  combine_kernel<<<dim3(S_LEN*DIMN/4/256), dim3(256), 0, stream>>>(comb, combC, combS, combb);
  gemm_bt<false><<<dim3(16, 16), dim3(256), 0, stream>>>(combb, wob, outp, 2048, 2048, 2048);
}

// Round 14
// 1071.977 us; speedup vs baseline: 1.1341x; 1.0868x over previous
//
#include <hip/hip_runtime.h>
#include <hip/hip_bf16.h>
#include <math.h>

// Problem constants (B=1)
#define S_LEN  2048
#define DIMN   2048
#define NHEAD  16
#define NKV    8
#define HEADD  128
#define WSTART 1536      // S - WIN
#define RSQD   0.08838834764831845f   // 1/sqrt(128)
#define NEGINF (-INFINITY)

typedef __hip_bfloat16 bf16;
typedef __attribute__((ext_vector_type(8))) __bf16 bf16x8;
typedef __attribute__((ext_vector_type(8))) unsigned short u16x8;
typedef __attribute__((ext_vector_type(4))) unsigned short us4;
typedef __attribute__((ext_vector_type(4))) float  f32x4;

__device__ __forceinline__ float bfl(unsigned u){ u <<= 16; float f; __builtin_memcpy(&f, &u, 4); return f; }
// fp32 -> bf16 bits, RTNE
__device__ __forceinline__ unsigned short f2b(float f){
  unsigned u; __builtin_memcpy(&u, &f, 4);
  u += 0x7fff + ((u >> 16) & 1);
  return (unsigned short)(u >> 16);
}
// broadcast lane j's float via v_readlane
__device__ __forceinline__ float lane_bcast(float v, int lane){
  int i; __builtin_memcpy(&i, &v, 4);
  i = __builtin_amdgcn_readlane(i, lane);
  float f; __builtin_memcpy(&f, &i, 4);
  return f;
}

__device__ __forceinline__ float wave_max(float v){
#pragma unroll
  for (int o = 32; o; o >>= 1) v = fmaxf(v, __shfl_xor(v, o));
  return v;
}
__device__ __forceinline__ float wave_sum(float v){
#pragma unroll
  for (int o = 32; o; o >>= 1) v += __shfl_xor(v, o);
  return v;
}

// ---- DPP 16-lane butterfly reduce (row = 16 lanes on CDNA) ----
template<int CTRL>
__device__ __forceinline__ float dpp_f(float v){
  int i; __builtin_memcpy(&i, &v, 4);
  i = __builtin_amdgcn_update_dpp(i, i, CTRL, 0xf, 0xf, false);
  float f; __builtin_memcpy(&f, &i, 4);
  return f;
}
__device__ __forceinline__ float gmax16(float v){
  v = fmaxf(v, dpp_f<0xB1>(v));    // quad_perm(1,0,3,2)  xor1
  v = fmaxf(v, dpp_f<0x4E>(v));    // quad_perm(2,3,0,1)  xor2
  v = fmaxf(v, dpp_f<0x141>(v));   // row_half_mirror     (quad exchange)
  v = fmaxf(v, dpp_f<0x140>(v));   // row_mirror          (half exchange)
  return v;
}
__device__ __forceinline__ float gsum16(float v){
  v += dpp_f<0xB1>(v);
  v += dpp_f<0x4E>(v);
  v += dpp_f<0x141>(v);
  v += dpp_f<0x140>(v);
  return v;
}

__device__ __forceinline__ float dot128_bf16(const float* __restrict__ qv, const bf16* __restrict__ krow){
  const uint4* kp = (const uint4*)krow;
  float s = 0.f;
#pragma unroll
  for (int t = 0; t < 16; ++t){
    uint4 u = kp[t];
    const float* q8 = qv + t*8;
    s += q8[0]*bfl(u.x & 0xffffu) + q8[1]*bfl(u.x >> 16)
       + q8[2]*bfl(u.y & 0xffffu) + q8[3]*bfl(u.y >> 16)
       + q8[4]*bfl(u.z & 0xffffu) + q8[5]*bfl(u.z >> 16)
       + q8[6]*bfl(u.w & 0xffffu) + q8[7]*bfl(u.w >> 16);
  }
  return s;
}

// exact summation order kept (selection top-k tie behavior must match the proven kernel)
__device__ __forceinline__ float dot128_f32(const float* __restrict__ qv, const float* __restrict__ row){
  const float4* rp = (const float4*)row;
  float s = 0.f;
#pragma unroll
  for (int t = 0; t < 32; ++t){
    float4 r = rp[t];
    const float* q4 = qv + t*4;
    s += q4[0]*r.x + q4[1]*r.y + q4[2]*r.z + q4[3]*r.w;
  }
  return s;
}

// u16x8 (bf16 bits) MFMA wrapper
__device__ __forceinline__ f32x4 MFMA(u16x8 a, u16x8 b, f32x4 c){
  bf16x8 ab, bb;
  __builtin_memcpy(&ab, &a, 16);
  __builtin_memcpy(&bb, &b, 16);
  return __builtin_amdgcn_mfma_f32_16x16x32_bf16(ab, bb, c, 0, 0, 0);
}

// L2-locality supertile remap (R10, bit-identical; kept — neutral)
__device__ __forceinline__ void remap_bc_br(int& bc, int& br){
  const int GN = gridDim.x, GM = gridDim.y;
  const int lin = blockIdx.y * GN + blockIdx.x;
  const int per = GM * 8;
  const int sc = lin / per, rem = lin % per;
  br = rem % GM;
  bc = sc * 8 + rem / GM;
}

// ---------------- GEMM: C[M][N] = A[M][K] * B[N][K]^T  (bf16 in, fp32 acc) ----------------
template<bool OUT_BF16>
__global__ __launch_bounds__(256) void gemm_bt(const bf16* __restrict__ A, const bf16* __restrict__ B,
                                               void* __restrict__ Cp, int M, int N, int K)
{
  __shared__ __align__(16) bf16 As[128*32];
  __shared__ __align__(16) bf16 Bs[128*32];
  const int t = threadIdx.x;
  const int w = t >> 6, l = t & 63;
  int bc, br; remap_bc_br(bc, br);
  const int wr = w >> 1, wc = w & 1;
  f32x4 acc[4][4];
  {
    f32x4 z = {0.f, 0.f, 0.f, 0.f};
#pragma unroll
    for (int m = 0; m < 4; ++m)
#pragma unroll
      for (int n = 0; n < 4; ++n) acc[m][n] = z;
  }
  const int srow = l >> 2, scol = (l & 3) * 8;
  const int lrow = l & 15, lko = (l >> 4) * 8;

  for (int kt = 0; kt < K; kt += 32){
#pragma unroll
    for (int cc = 0; cc < 2; ++cc){
      const int c = w + cc*4;
      const bf16* gA = A + (size_t)(br*128 + c*16 + srow)*K + kt + scol;
      const bf16* gB = B + (size_t)(bc*128 + c*16 + srow)*K + kt + scol;
      __builtin_amdgcn_global_load_lds((const __attribute__((address_space(1))) void*)gA,
                                       (__attribute__((address_space(3))) void*)&As[c*512], 16, 0, 0);
      __builtin_amdgcn_global_load_lds((const __attribute__((address_space(1))) void*)gB,
                                       (__attribute__((address_space(3))) void*)&Bs[c*512], 16, 0, 0);
    }
    __syncthreads();
    bf16x8 af[4], bfr[4];
#pragma unroll
    for (int m = 0; m < 4; ++m) af[m]  = *(const bf16x8*)&As[(wr*64 + m*16 + lrow)*32 + lko];
#pragma unroll
    for (int n = 0; n < 4; ++n) bfr[n] = *(const bf16x8*)&Bs[(wc*64 + n*16 + lrow)*32 + lko];
#pragma unroll
    for (int m = 0; m < 4; ++m)
#pragma unroll
      for (int n = 0; n < 4; ++n)
        acc[m][n] = __builtin_amdgcn_mfma_f32_16x16x32_bf16(af[m], bfr[n], acc[m][n], 0, 0, 0);
    __syncthreads();
  }
  const int crow0 = br*128 + wr*64 + (l >> 4)*4;
  const int ccol  = bc*128 + wc*64 + lrow;
#pragma unroll
  for (int m = 0; m < 4; ++m)
#pragma unroll
    for (int n = 0; n < 4; ++n)
#pragma unroll
      for (int r = 0; r < 4; ++r){
        const size_t idx = (size_t)(crow0 + m*16 + r)*N + (ccol + n*16);
        if constexpr (OUT_BF16) ((bf16*)Cp)[idx] = __float2bfloat16(acc[m][n][r]);
        else                    ((float*)Cp)[idx] = acc[m][n][r];
      }
}

// ---------------- pre-split 3-pass GEMM PAIR: two targets sharing A, one launch (R14) ------
// grid (24, 16): bx<16 -> C1 (N=2048, 16 col-blocks); bx>=16 -> C2 (N=1024, 8 col-blocks).
// Per-target supertile remap reproduces exactly the tile set of the two old launches ->
// per-tile computation (and acc order: hh, hl, lh) unchanged -> bit-identical outputs.
__global__ __launch_bounds__(256) void gemm_bt3_pair(
    const bf16* __restrict__ Ahg, const bf16* __restrict__ Alg,
    const bf16* __restrict__ B1h, const bf16* __restrict__ B1l, float* __restrict__ C1,
    const bf16* __restrict__ B2h, const bf16* __restrict__ B2l, float* __restrict__ C2,
    int K)
{
  __shared__ __align__(16) bf16 AhS[128*32], AlS[128*32], BhS[128*32], BlS[128*32];
  const int t = threadIdx.x;
  const int w = t >> 6, l = t & 63;
  const bf16* Bhg; const bf16* Blg; float* C; int N, GN, bcx;
  if (blockIdx.x < 16){ Bhg = B1h; Blg = B1l; C = C1; N = 2048; GN = 16; bcx = blockIdx.x; }
  else                { Bhg = B2h; Blg = B2l; C = C2; N = 1024; GN = 8;  bcx = blockIdx.x - 16; }
  // supertile remap within this target's (GN x 16) subgrid (same formula as remap_bc_br)
  int bc, br;
  {
    const int GM = 16;
    const int lin = blockIdx.y * GN + bcx;
    const int per = GM * 8;
    const int sc = lin / per, rem = lin % per;
    br = rem % GM;
    bc = sc * 8 + rem / GM;
  }
  const int wr = w >> 1, wc = w & 1;
  f32x4 acc[4][4];
  {
    f32x4 z = {0.f, 0.f, 0.f, 0.f};
#pragma unroll
    for (int m = 0; m < 4; ++m)
#pragma unroll
      for (int n = 0; n < 4; ++n) acc[m][n] = z;
  }
  const int srow = l >> 2, scol = (l & 3) * 8;
  const int lrow = l & 15, lko = (l >> 4) * 8;

  for (int kt = 0; kt < K; kt += 32){
#pragma unroll
    for (int cc = 0; cc < 2; ++cc){
      const int c = w + cc*4;
      const size_t aoff = (size_t)(br*128 + c*16 + srow)*K + kt + scol;
      const size_t boff = (size_t)(bc*128 + c*16 + srow)*K + kt + scol;
      __builtin_amdgcn_global_load_lds((const __attribute__((address_space(1))) void*)(Ahg + aoff),
                                       (__attribute__((address_space(3))) void*)&AhS[c*512], 16, 0, 0);
      __builtin_amdgcn_global_load_lds((const __attribute__((address_space(1))) void*)(Alg + aoff),
                                       (__attribute__((address_space(3))) void*)&AlS[c*512], 16, 0, 0);
      __builtin_amdgcn_global_load_lds((const __attribute__((address_space(1))) void*)(Bhg + boff),
                                       (__attribute__((address_space(3))) void*)&BhS[c*512], 16, 0, 0);
      __builtin_amdgcn_global_load_lds((const __attribute__((address_space(1))) void*)(Blg + boff),
                                       (__attribute__((address_space(3))) void*)&BlS[c*512], 16, 0, 0);
    }
    __syncthreads();
    bf16x8 ahf[4], alf[4], bhf[4], blf[4];
#pragma unroll
    for (int m = 0; m < 4; ++m){
      ahf[m] = *(const bf16x8*)&AhS[(wr*64 + m*16 + lrow)*32 + lko];
      alf[m] = *(const bf16x8*)&AlS[(wr*64 + m*16 + lrow)*32 + lko];
    }
#pragma unroll
    for (int n = 0; n < 4; ++n){
      bhf[n] = *(const bf16x8*)&BhS[(wc*64 + n*16 + lrow)*32 + lko];
      blf[n] = *(const bf16x8*)&BlS[(wc*64 + n*16 + lrow)*32 + lko];
    }
#pragma unroll
    for (int m = 0; m < 4; ++m)
#pragma unroll
      for (int n = 0; n < 4; ++n){
        acc[m][n] = __builtin_amdgcn_mfma_f32_16x16x32_bf16(ahf[m], bhf[n], acc[m][n], 0, 0, 0);
        acc[m][n] = __builtin_amdgcn_mfma_f32_16x16x32_bf16(ahf[m], blf[n], acc[m][n], 0, 0, 0);
        acc[m][n] = __builtin_amdgcn_mfma_f32_16x16x32_bf16(alf[m], bhf[n], acc[m][n], 0, 0, 0);
      }
    __syncthreads();
  }
  const int crow0 = br*128 + wr*64 + (l >> 4)*4;
  const int ccol  = bc*128 + wc*64 + lrow;
#pragma unroll
  for (int m = 0; m < 4; ++m)
#pragma unroll
    for (int n = 0; n < 4; ++n)
#pragma unroll
      for (int r = 0; r < 4; ++r)
        C[(size_t)(crow0 + m*16 + r)*N + (ccol + n*16)] = acc[m][n][r];
}

// ---------------- split-bf16 emulated-fp32 GEMM (kept for the small ck32 GEMM) ----------------
__global__ __launch_bounds__(256) void gemm_bt_split(const float* __restrict__ A, const float* __restrict__ B,
                                                     float* __restrict__ C, int M, int N, int K)
{
  __shared__ __align__(16) unsigned short Ah[128*32], Al[128*32], Bh[128*32], Bl[128*32];
  const int t = threadIdx.x;
  const int w = t >> 6, l = t & 63;
  const int bc = blockIdx.x, br = blockIdx.y;
  const int wr = w >> 1, wc = w & 1;
  f32x4 acc[4][4];
  {
    f32x4 z = {0.f, 0.f, 0.f, 0.f};
#pragma unroll
    for (int m = 0; m < 4; ++m)
#pragma unroll
      for (int n = 0; n < 4; ++n) acc[m][n] = z;
  }
  const int lrow = l & 15, lko = (l >> 4) * 8;

  for (int kt = 0; kt < K; kt += 32){
#pragma unroll
    for (int i = 0; i < 4; ++i){
      const int lin = t + i*256;
      const int row = lin >> 3;
      const int cq  = (lin & 7) * 4;
      const float4 va = *(const float4*)&A[(size_t)(br*128 + row)*K + kt + cq];
      const float4 vb = *(const float4*)&B[(size_t)(bc*128 + row)*K + kt + cq];
      const float fa[4] = {va.x, va.y, va.z, va.w};
      const float fb[4] = {vb.x, vb.y, vb.z, vb.w};
      us4 ah, al2, bh, bl2;
#pragma unroll
      for (int j = 0; j < 4; ++j){
        const unsigned short h = f2b(fa[j]); ah[j] = h; al2[j] = f2b(fa[j] - bfl(h));
        const unsigned short g = f2b(fb[j]); bh[j] = g; bl2[j] = f2b(fb[j] - bfl(g));
      }
      *(us4*)&Ah[row*32 + cq] = ah;  *(us4*)&Al[row*32 + cq] = al2;
      *(us4*)&Bh[row*32 + cq] = bh;  *(us4*)&Bl[row*32 + cq] = bl2;
    }
    __syncthreads();
    bf16x8 ahf[4], alf[4], bhf[4], blf[4];
#pragma unroll
    for (int m = 0; m < 4; ++m){
      ahf[m] = *(const bf16x8*)&Ah[(wr*64 + m*16 + lrow)*32 + lko];
      alf[m] = *(const bf16x8*)&Al[(wr*64 + m*16 + lrow)*32 + lko];
    }
#pragma unroll
    for (int n = 0; n < 4; ++n){
      bhf[n] = *(const bf16x8*)&Bh[(wc*64 + n*16 + lrow)*32 + lko];
      blf[n] = *(const bf16x8*)&Bl[(wc*64 + n*16 + lrow)*32 + lko];
    }
#pragma unroll
    for (int m = 0; m < 4; ++m)
#pragma unroll
      for (int n = 0; n < 4; ++n){
        acc[m][n] = __builtin_amdgcn_mfma_f32_16x16x32_bf16(ahf[m], bhf[n], acc[m][n], 0, 0, 0);
        acc[m][n] = __builtin_amdgcn_mfma_f32_16x16x32_bf16(ahf[m], blf[n], acc[m][n], 0, 0, 0);
        acc[m][n] = __builtin_amdgcn_mfma_f32_16x16x32_bf16(alf[m], bhf[n], acc[m][n], 0, 0, 0);
      }
    __syncthreads();
  }
  const int crow0 = br*128 + wr*64 + (l >> 4)*4;
  const int ccol  = bc*128 + wc*64 + lrow;
#pragma unroll
  for (int m = 0; m < 4; ++m)
#pragma unroll
    for (int n = 0; n < 4; ++n)
#pragma unroll
      for (int r = 0; r < 4; ++r)
        C[(size_t)(crow0 + m*16 + r)*N + (ccol + n*16)] = acc[m][n][r];
}

// ---------------- small utility kernels ----------------
__global__ void build_tables_kernel(float* __restrict__ cosT, float* __restrict__ sinT){
  const int idx = blockIdx.x*blockDim.x + threadIdx.x;
  if (idx >= S_LEN*64) return;
  const int s = idx >> 6, i = idx & 63;
  const float inv = powf(10000.f, -(float)(2*i) / 128.f);
  const float ang = (float)s * inv;
  cosT[idx] = cosf(ang);
  sinT[idx] = sinf(ang);
}

// R13: ONE launch, float4-vectorized, converts x + all 9 weights (10 compile-time ranges).
// Same __float2bfloat16 per element as the 10 scalar launches it replaces -> bit-identical.
__global__ __launch_bounds__(256) void cvt_fuse_kernel(
    const float* __restrict__ x,
    const float* __restrict__ w0, const float* __restrict__ w1, const float* __restrict__ w2,
    const float* __restrict__ w3, const float* __restrict__ w4, const float* __restrict__ w5,
    const float* __restrict__ w6, const float* __restrict__ w7, const float* __restrict__ w8,
    bf16* __restrict__ Xb, bf16* __restrict__ Wall)
{
  const int stride = gridDim.x * blockDim.x;
  for (int i = blockIdx.x*blockDim.x + threadIdx.x; i < 7340032; i += stride){
    const float* src; us4* dst; int li;
    if      (i < 1048576){ src = x;  dst = (us4*)Xb;                li = i; }
    else if (i < 2097152){ src = w0; dst = (us4*)Wall;              li = i - 1048576; }
    else if (i < 2621440){ src = w1; dst = (us4*)(Wall +  4194304); li = i - 2097152; }
    else if (i < 3145728){ src = w2; dst = (us4*)(Wall +  6291456); li = i - 2621440; }
    else if (i < 4194304){ src = w3; dst = (us4*)(Wall +  8388608); li = i - 3145728; }
    else if (i < 4718592){ src = w4; dst = (us4*)(Wall + 12582912); li = i - 4194304; }
    else if (i < 5242880){ src = w5; dst = (us4*)(Wall + 14680064); li = i - 4718592; }
    else if (i < 6291456){ src = w6; dst = (us4*)(Wall + 16777216); li = i - 5242880; }
    else if (i < 6815744){ src = w7; dst = (us4*)(Wall + 20971520); li = i - 6291456; }
    else                 { src = w8; dst = (us4*)(Wall + 23068672); li = i - 6815744; }
    const float4 v = ((const float4*)src)[li];
    us4 r;
    r[0] = __bfloat16_as_ushort(__float2bfloat16(v.x));
    r[1] = __bfloat16_as_ushort(__float2bfloat16(v.y));
    r[2] = __bfloat16_as_ushort(__float2bfloat16(v.z));
    r[3] = __bfloat16_as_ushort(__float2bfloat16(v.w));
    dst[li] = r;
  }
}

// R14: ONE launch, float4-vectorized, converts w_comp_mlp (Wm) + w_o (wob).
// Same __float2bfloat16 per element as the two scalar launches it replaces -> bit-identical.
__global__ __launch_bounds__(256) void cvt2_kernel(
    const float* __restrict__ wm_src, const float* __restrict__ wo_src,
    bf16* __restrict__ Wm, bf16* __restrict__ wob)
{
  const int stride = gridDim.x * blockDim.x;
  for (int i = blockIdx.x*blockDim.x + threadIdx.x; i < 1179648; i += stride){
    const float* src; us4* dst; int li;
    if (i < 131072){ src = wm_src; dst = (us4*)Wm;  li = i; }
    else           { src = wo_src; dst = (us4*)wob; li = i - 131072; }
    const float4 v = ((const float4*)src)[li];
    us4 r;
    r[0] = __bfloat16_as_ushort(__float2bfloat16(v.x));
    r[1] = __bfloat16_as_ushort(__float2bfloat16(v.y));
    r[2] = __bfloat16_as_ushort(__float2bfloat16(v.z));
    r[3] = __bfloat16_as_ushort(__float2bfloat16(v.w));
    dst[li] = r;
  }
}

// R13: ONE launch for all three hi/lo splits (x, wq_sel, wk_comp). Same f2b formulas
// as the split_f32_kernel launches it replaces -> bit-identical.
__global__ __launch_bounds__(256) void split3_kernel(
    const float* __restrict__ xx, const float* __restrict__ wqs, const float* __restrict__ wkc,
    bf16* __restrict__ x_hi, bf16* __restrict__ x_lo,
    bf16* __restrict__ wqs_hi, bf16* __restrict__ wqs_lo,
    bf16* __restrict__ wkc_hi, bf16* __restrict__ wkc_lo)
{
  const int stride = gridDim.x * blockDim.x;
  for (int i = blockIdx.x*blockDim.x + threadIdx.x; i < 2621440; i += stride){
    const float* src; us4* dh; us4* dl; int li;
    if      (i < 1048576){ src = xx;  dh = (us4*)x_hi;   dl = (us4*)x_lo;   li = i; }
    else if (i < 2097152){ src = wqs; dh = (us4*)wqs_hi; dl = (us4*)wqs_lo; li = i - 1048576; }
    else                 { src = wkc; dh = (us4*)wkc_hi; dl = (us4*)wkc_lo; li = i - 2097152; }
    const float4 v = ((const float4*)src)[li];
    const float f[4] = {v.x, v.y, v.z, v.w};
    us4 h, l2;
#pragma unroll
    for (int j = 0; j < 4; ++j){
      const unsigned short hh = f2b(f[j]);
      h[j] = hh;
      l2[j] = f2b(f[j] - bfl(hh));
    }
    dh[li] = h;
    dl[li] = l2;
  }
}

// R14: both fp32 RoPE passes (Qs32 C=2048, Kc32 C=1024) in one launch; same per-row
// arithmetic as the two rope32 launches it replaces -> bit-identical.
__global__ void rope32_pair_kernel(float* __restrict__ Q, float* __restrict__ Kc,
                                   const float* __restrict__ cosT, const float* __restrict__ sinT){
  const int s = blockIdx.x;
  float* row; int C;
  if (blockIdx.y == 0){ row = Q  + (size_t)s*2048; C = 2048; }
  else                { row = Kc + (size_t)s*1024; C = 1024; }
  for (int p = threadIdx.x; p < (C >> 1); p += blockDim.x){
    const int i = p & 63;
    const int col = (p >> 6)*128 + 2*i;
    const float a = row[col], b = row[col+1];
    const float c = cosT[s*64 + i], sn = sinT[s*64 + i];
    row[col]   = a*c - b*sn;
    row[col+1] = a*sn + b*c;
  }
}

// [s][kv*128+d] -> [kv][s][d] fp32
__global__ void khm_kernel(const float* __restrict__ src, float* __restrict__ dst){
  const int idx = blockIdx.x*blockDim.x + threadIdx.x;
  if (idx >= S_LEN*1024) return;
  const int s = idx >> 10, c = idx & 1023;
  const int kv = c >> 7, d = c & 127;
  dst[((size_t)kv*S_LEN + s)*HEADD + d] = src[idx];
}

// Y[s][12288] -> 9 head-major bf16 tensors with RoPE on q/k
__global__ void rope_scatter_kernel(const bf16* __restrict__ Y, const float* __restrict__ cosT,
    const float* __restrict__ sinT,
    bf16* __restrict__ Qw, bf16* __restrict__ Kw, bf16* __restrict__ Vw,
    bf16* __restrict__ Qs, bf16* __restrict__ Ks, bf16* __restrict__ Vs,
    bf16* __restrict__ Qc, bf16* __restrict__ Kc, bf16* __restrict__ Vc)
{
  const int s = blockIdx.x;
  const unsigned* Yrow = (const unsigned*)(Y + (size_t)s*12288);
  for (int p = threadIdx.x; p < 6144; p += blockDim.x){
    const int col = p*2;
    bf16* dst; int base; bool isv = false;
    if (col < 4096){
      if      (col < 2048){ dst = Qw; base = 0; }
      else if (col < 3072){ dst = Kw; base = 2048; }
      else                { dst = Vw; base = 3072; isv = true; }
    } else if (col < 8192){
      if      (col < 6144){ dst = Qs; base = 4096; }
      else if (col < 7168){ dst = Ks; base = 6144; }
      else                { dst = Vs; base = 7168; isv = true; }
    } else {
      if      (col < 10240){ dst = Qc; base = 8192; }
      else if (col < 11264){ dst = Kc; base = 10240; }
      else                 { dst = Vc; base = 11264; isv = true; }
    }
    const int lc = col - base;
    const int head = lc >> 7, d = lc & 127, i = d >> 1;
    const unsigned yy = Yrow[p];
    float a = bfl(yy & 0xffffu), b = bfl(yy >> 16);
    if (!isv){
      const float c = cosT[s*64 + i], sn = sinT[s*64 + i];
      const float na = a*c - b*sn;
      b = a*sn + b*c;
      a = na;
    }
    const size_t off = ((size_t)head*S_LEN + s)*HEADD + d;
    dst[off]   = __float2bfloat16(a);
    dst[off+1] = __float2bfloat16(b);
  }
}

// [NKV][S_LEN][HEADD] bf16 -> [NKV][HEADD][S_LEN] bf16 (64x64 LDS tiles)
__global__ __launch_bounds__(256) void vtrans_kernel(const bf16* __restrict__ src, bf16* __restrict__ dst){
  __shared__ unsigned short tile[64][72];   // 72: keeps 16B-aligned rows (144B)
  const int kv = blockIdx.z;
  const int r0 = blockIdx.x*64;   // S dim
  const int c0 = blockIdx.y*64;   // D dim
  const int t = threadIdx.x;
  const int lr = t >> 2, lc = (t & 3)*16;
  const unsigned short* sp = (const unsigned short*)src + ((size_t)kv*S_LEN + r0 + lr)*HEADD + c0 + lc;
  *(u16x8*)&tile[lr][lc]     = *(const u16x8*)sp;
  *(u16x8*)&tile[lr][lc + 8] = *(const u16x8*)(sp + 8);
  __syncthreads();
  unsigned short* dp = (unsigned short*)dst + ((size_t)kv*HEADD + c0 + lr)*S_LEN + r0 + lc;
  u16x8 v0, v1;
#pragma unroll
  for (int j = 0; j < 8; ++j){ v0[j] = tile[lc + j][lr]; v1[j] = tile[lc + 8 + j][lr]; }
  *(u16x8*)dp       = v0;
  *(u16x8*)(dp + 8) = v1;
}

// ck32/cv [NKV][64][HEADD] fp32 -> hi/lo bf16 (ck as-is, cv transposed to [NKV][HEADD][64])
__global__ void comp_prep_kernel(const float* __restrict__ ck32, const float* __restrict__ cv,
    bf16* __restrict__ ckh, bf16* __restrict__ ckl, bf16* __restrict__ cvTh, bf16* __restrict__ cvTl)
{
  const int i = blockIdx.x*256 + threadIdx.x;
  if (i >= NKV*64*HEADD) return;
  const int kv = i >> 13, rem = i & 8191, key = rem >> 7, d = rem & 127;
  const float a = ck32[i];
  const unsigned short ah = f2b(a);
  ((unsigned short*)ckh)[i] = ah;
  ((unsigned short*)ckl)[i] = f2b(a - bfl(ah));
  const float b = cv[i];
  const unsigned short bh = f2b(b);
  const size_t j = ((size_t)kv*HEADD + d)*64 + key;
  ((unsigned short*)cvTh)[j] = bh;
  ((unsigned short*)cvTl)[j] = f2b(b - bfl(bh));
}

__global__ __launch_bounds__(64) void gates_kernel(const float* __restrict__ x,
    const float* __restrict__ wg, float* __restrict__ gates)
{
  const int r = blockIdx.x, l = threadIdx.x;
  const float* xr = x + (size_t)r*DIMN;
  float p0 = 0.f, p1 = 0.f, p2 = 0.f;
  for (int i = l; i < DIMN; i += 64){
    const float xv = xr[i];
    p0 += xv * wg[i];
    p1 += xv * wg[DIMN + i];
    p2 += xv * wg[2*DIMN + i];
  }
  p0 = wave_sum(p0); p1 = wave_sum(p1); p2 = wave_sum(p2);
  if (l == 0){
    const float mx = fmaxf(p0, fmaxf(p1, p2));
    const float e0 = expf(p0-mx), e1 = expf(p1-mx), e2 = expf(p2-mx);
    const float inv = 1.f/(e0+e1+e2);
    gates[r*3+0] = e0*inv; gates[r*3+1] = e1*inv; gates[r*3+2] = e2*inv;
  }
}

// block per kv; thread (d, half) reduces 256 window rows each
__global__ __launch_bounds__(256) void meanv_kernel(const bf16* __restrict__ Vw, float* __restrict__ mean_vw){
  const int kv = blockIdx.x, t = threadIdx.x;
  const int d = t & 127, half = t >> 7;
  const bf16* base = Vw + ((size_t)kv*S_LEN + WSTART + half*256)*HEADD + d;
  float acc = 0.f;
  for (int r = 0; r < 256; ++r) acc += __bfloat162float(base[(size_t)r*HEADD]);
  __shared__ float red[256];
  red[t] = acc;
  __syncthreads();
  if (!half) mean_vw[kv*HEADD + d] = (red[d] + red[128 + d]) * (1.f/512.f);
}

// suffix-sum of Vs over s, two-phase
__global__ __launch_bounds__(256) void suffv_a_kernel(const bf16* __restrict__ Vs, float* __restrict__ chunkSums){
  const int kv = blockIdx.x, ch = blockIdx.y, t = threadIdx.x;
  const int d = t & 127, half = t >> 7;
  const bf16* base = Vs + ((size_t)kv*S_LEN + ch*128 + half*64)*HEADD + d;
  float acc = 0.f;
  for (int r = 0; r < 64; ++r) acc += __bfloat162float(base[(size_t)r*HEADD]);
  __shared__ float red[256];
  red[t] = acc;
  __syncthreads();
  if (!half) chunkSums[((size_t)kv*16 + ch)*HEADD + d] = red[d] + red[128 + d];
}
__global__ __launch_bounds__(128) void suffv_b_kernel(const bf16* __restrict__ Vs,
    const float* __restrict__ chunkSums, float* __restrict__ suffV){
  const int kv = blockIdx.x, ch = blockIdx.y, d = threadIdx.x;
  float acc = 0.f;
  for (int c = ch + 1; c < 16; ++c) acc += chunkSums[((size_t)kv*16 + c)*HEADD + d];
  const int s0 = ch*128;
  for (int r = 127; r >= 0; --r){
    acc += __bfloat162float(Vs[((size_t)kv*S_LEN + s0 + r)*HEADD + d]);
    suffV[((size_t)kv*2049 + s0 + r)*HEADD + d] = acc;
  }
  if (ch == 15) suffV[((size_t)kv*2049 + 2048)*HEADD + d] = 0.f;
}

__global__ void win_mean_kernel(const float* __restrict__ mean_vw, const float* __restrict__ gates,
                                float* __restrict__ comb)
{
  const int q = blockIdx.x;
  const float g0 = gates[q*3];
  for (int c = threadIdx.x; c < DIMN; c += blockDim.x){
    const int kv = c >> 8;
    const int d  = c & 127;
    comb[(size_t)q*DIMN + c] = g0 * mean_vw[kv*HEADD + d];
  }
}

// ---------------- selection kernel: exact dot order + rank-based top-16 ----------------
__global__ __launch_bounds__(64) void sel_select_kernel(
    const float* __restrict__ Qs32, const float* __restrict__ ck32,
    unsigned long long* __restrict__ selm, unsigned long long* __restrict__ selU,
    unsigned* __restrict__ selvis)
{
  const int tile = blockIdx.x, h = blockIdx.y, kv = h >> 1, l = threadIdx.x;
  const int q0 = tile*16, bq = tile >> 1;
  __shared__ float impS[16][64];
  __shared__ unsigned short pmaskS[16][4];
  __shared__ unsigned long long vmS[16];
  const float* ckrow = ck32 + (size_t)(kv*64 + l)*HEADD;
#pragma unroll
  for (int qq = 0; qq < 16; ++qq){
    const float* qr = Qs32 + (size_t)(q0+qq)*DIMN + h*HEADD;
    impS[qq][l] = dot128_f32(qr, ckrow);
  }
  __syncthreads();
  const int row = l >> 2, part = l & 3;
  float mine[16];
#pragma unroll
  for (int j = 0; j < 16; ++j) mine[j] = impS[row][part*16 + j];
  int rk[16];
#pragma unroll
  for (int j = 0; j < 16; ++j) rk[j] = 0;
  for (int b = 0; b < 64; ++b){
    const float vb = impS[row][b];
#pragma unroll
    for (int j = 0; j < 16; ++j){
      const int idxj = part*16 + j;
      rk[j] += ((vb > mine[j]) || (vb == mine[j] && b < idxj)) ? 1 : 0;
    }
  }
  unsigned pm = 0;
#pragma unroll
  for (int j = 0; j < 16; ++j) if (rk[j] < 16) pm |= (1u << j);
  pmaskS[row][part] = (unsigned short)pm;
  __syncthreads();
  if (l < 16){
    const unsigned long long sm =
        (unsigned long long)pmaskS[l][0]
      | ((unsigned long long)pmaskS[l][1] << 16)
      | ((unsigned long long)pmaskS[l][2] << 32)
      | ((unsigned long long)pmaskS[l][3] << 48);
    selm[((size_t)h*128 + tile)*16 + l] = sm;
    vmS[l] = (bq >= 63) ? sm : (sm & ((1ull << (bq+1)) - 1ull));
  }
  __syncthreads();
  if (l == 0){
    unsigned long long U = 0ull; unsigned vis = 0u;
#pragma unroll
    for (int i = 0; i < 16; ++i){ U |= vmS[i]; vis |= (vmS[i] ? 1u : 0u) << i; }
    selU[(size_t)h*128 + tile] = U;
    selvis[(size_t)h*128 + tile] = vis;
  }
}

// ---------------- MFMA fused attention, 4-way key-split flash (R11 state) ----------------
// R6: LPT grid. R7: V-prefetch. R8: __expf. R11: K-load software pipeline.
// R12 (64-key iterations) REGRESSED -> reverted to this proven R11 structure.

// online-softmax step; row-group reduces are DPP (no LDS shuffles)
__device__ __forceinline__ void sm_step(float s0, float s1, int row, int c16,
                                        float& m, float& sum, f32x4* out, int r,
                                        unsigned short* Plh, unsigned short* Pll)
{
  const float mx = gmax16(fmaxf(s0, s1));
  const float mn = fmaxf(m, mx);
  float p0, p1, scale;
  if (mn == NEGINF){ p0 = 0.f; p1 = 0.f; scale = 1.f; }        // fully-masked-so-far row
  else { scale = __expf(m - mn); p0 = __expf(s0 - mn); p1 = __expf(s1 - mn); }
  const bool needscale = (mn != m);
  m = mn;
  sum = sum*scale + gsum16(p0 + p1);
  if (needscale){
#pragma unroll
    for (int t = 0; t < 8; ++t) out[t][r] *= scale;
  }
  const unsigned short h0 = f2b(p0), h1 = f2b(p1);
  Plh[row*40 + c16]      = h0;
  Plh[row*40 + 16 + c16] = h1;
  Pll[row*40 + c16]      = f2b(p0 - bfl(h0));
  Pll[row*40 + 16 + c16] = f2b(p1 - bfl(h1));
}

__global__ __launch_bounds__(256) void attn_mfma_kernel(
    const bf16* __restrict__ Qw, const bf16* __restrict__ Kw, const bf16* __restrict__ VwT,
    const bf16* __restrict__ Qc, const bf16* __restrict__ ckh, const bf16* __restrict__ ckl,
    const bf16* __restrict__ cvTh, const bf16* __restrict__ cvTl,
    const float* __restrict__ Qs32, const bf16* __restrict__ Ks, const bf16* __restrict__ VsT,
    const bf16* __restrict__ Vs,
    const float* __restrict__ suffV, const float* __restrict__ gates,
    const unsigned long long* __restrict__ selm, const unsigned long long* __restrict__ selU,
    const unsigned* __restrict__ selvis,
    float* __restrict__ comb, float* __restrict__ combC, float* __restrict__ combS)
{
  const int h = blockIdx.x, kv = h >> 1;     // heads on X (dispatch-fastest axis)
  const int tid = threadIdx.x, wv = tid >> 6, l = tid & 63;
  const int g16 = l >> 4, c16 = l & 15;
  const int bx = blockIdx.y;                 // branch/tile on Y

  __shared__ unsigned short PlhS[4][640], PllS[4][640];
  __shared__ float outS[16][132];               // +4 pad: spreads rows across banks
  __shared__ float mS[4][16], sumS[4][16];
  __shared__ float qv[128];
  unsigned short* Plh = PlhS[wv];
  unsigned short* Pll = PllS[wv];

  f32x4 out[8];
  float m[4], sum[4];
#pragma unroll
  for (int t = 0; t < 8; ++t) out[t] = (f32x4){0.f,0.f,0.f,0.f};
#pragma unroll
  for (int r = 0; r < 4; ++r){ m[r] = NEGINF; sum[r] = 0.f; }

  int branch, tile, q0;                         // branch: 0=win 1=comp 2=sel (gate index)
  if (bx < 128)      { branch = 2; tile = 127 - bx;  q0 = tile*16; }
  else if (bx < 160) { branch = 0; tile = 159 - bx;  q0 = WSTART + tile*16; }
  else               { branch = 1; tile = bx - 160;  q0 = tile*16; }

  if (branch == 0){
    // ================= window: keys [1536, qi], chunks round-robin; K pipelined =========
    u16x8 qf[4];
    {
      const unsigned short* qrow = (const unsigned short*)Qw + ((size_t)h*S_LEN + q0 + c16)*HEADD + g16*8;
#pragma unroll
      for (int ks = 0; ks < 4; ++ks) qf[ks] = *(const u16x8*)(qrow + ks*32);
    }
    const unsigned short* Kb  = (const unsigned short*)Kw  + (size_t)kv*S_LEN*HEADD;
    const unsigned short* Vtb = (const unsigned short*)VwT + (size_t)kv*HEADD*S_LEN;
    const int cmax = tile >> 1;
    u16x8 kc0[4], kc1[4], kn0[4], kn1[4];
    int c = wv;
    if (c <= cmax){
      const int kb = WSTART + c*32;
#pragma unroll
      for (int ks = 0; ks < 4; ++ks){
        kc0[ks] = *(const u16x8*)(Kb + (size_t)(kb + c16)*HEADD      + g16*8 + ks*32);
        kc1[ks] = *(const u16x8*)(Kb + (size_t)(kb + 16 + c16)*HEADD + g16*8 + ks*32);
      }
    }
    for (; c <= cmax; c += 4){
      const int kb = WSTART + c*32;
      // V prefetch: issue early so HBM/L2 latency hides under the softmax chain
      u16x8 bv[8];
#pragma unroll
      for (int t = 0; t < 8; ++t)
        bv[t] = *(const u16x8*)(Vtb + (size_t)(t*16 + c16)*S_LEN + kb + g16*8);
      f32x4 sa0 = {0.f,0.f,0.f,0.f}, sa1 = {0.f,0.f,0.f,0.f};
#pragma unroll
      for (int ks = 0; ks < 4; ++ks){
        sa0 = MFMA(qf[ks], kc0[ks], sa0);
        sa1 = MFMA(qf[ks], kc1[ks], sa1);
      }
      // K pipeline: issue next chunk's K now — softmax+PV covers its latency
      const int cn = c + 4;
      const int kbn = WSTART + min(cn, cmax)*32;
      if (cn <= cmax){
#pragma unroll
        for (int ks = 0; ks < 4; ++ks){
          kn0[ks] = *(const u16x8*)(Kb + (size_t)(kbn + c16)*HEADD      + g16*8 + ks*32);
          kn1[ks] = *(const u16x8*)(Kb + (size_t)(kbn + 16 + c16)*HEADD + g16*8 + ks*32);
        }
      }
#pragma unroll
      for (int r = 0; r < 4; ++r){
        const int row = g16*4 + r;
        const int qi = q0 + row;
        const float s0 = (kb + c16      <= qi) ? sa0[r]*RSQD : NEGINF;
        const float s1 = (kb + 16 + c16 <= qi) ? sa1[r]*RSQD : NEGINF;
        sm_step(s0, s1, row, c16, m[r], sum[r], out, r, Plh, Pll);
      }
      asm volatile("s_waitcnt lgkmcnt(0)" ::: "memory");
      const u16x8 pah = *(const u16x8*)&Plh[c16*40 + g16*8];
      const u16x8 pal = *(const u16x8*)&Pll[c16*40 + g16*8];
#pragma unroll
      for (int t = 0; t < 8; ++t){
        out[t] = MFMA(pah, bv[t], out[t]);
        out[t] = MFMA(pal, bv[t], out[t]);
      }
#pragma unroll
      for (int ks = 0; ks < 4; ++ks){ kc0[ks] = kn0[ks]; kc1[ks] = kn1[ks]; }
    }
  } else if (branch == 1){
    // ================= compressed: 64 keys, non-causal, waves 0/1 take one chunk each ====
    // (cross-wave combine below is REQUIRED: each wave sees only half the keys — R5 bug)
    u16x8 qf[4];
    {
      const unsigned short* qrow = (const unsigned short*)Qc + ((size_t)h*S_LEN + q0 + c16)*HEADD + g16*8;
#pragma unroll
      for (int ks = 0; ks < 4; ++ks) qf[ks] = *(const u16x8*)(qrow + ks*32);
    }
    const unsigned short* ckhp = (const unsigned short*)ckh  + (size_t)kv*64*HEADD;
    const unsigned short* cklp = (const unsigned short*)ckl  + (size_t)kv*64*HEADD;
    const unsigned short* cvhp = (const unsigned short*)cvTh + (size_t)kv*HEADD*64;
    const unsigned short* cvlp = (const unsigned short*)cvTl + (size_t)kv*HEADD*64;
    for (int ch = wv; ch < 2; ch += 4){
      const int kb = ch*32;
      u16x8 bh0[4], bh1[4], bl0[4], bl1[4];
#pragma unroll
      for (int ks = 0; ks < 4; ++ks){
        bh0[ks] = *(const u16x8*)(ckhp + (size_t)(kb + c16)*HEADD      + g16*8 + ks*32);
        bh1[ks] = *(const u16x8*)(ckhp + (size_t)(kb + 16 + c16)*HEADD + g16*8 + ks*32);
        bl0[ks] = *(const u16x8*)(cklp + (size_t)(kb + c16)*HEADD      + g16*8 + ks*32);
        bl1[ks] = *(const u16x8*)(cklp + (size_t)(kb + 16 + c16)*HEADD + g16*8 + ks*32);
      }
      f32x4 sa0 = {0.f,0.f,0.f,0.f}, sa1 = {0.f,0.f,0.f,0.f};
#pragma unroll
      for (int ks = 0; ks < 4; ++ks){
        sa0 = MFMA(qf[ks], bh0[ks], sa0);
        sa0 = MFMA(qf[ks], bl0[ks], sa0);
        sa1 = MFMA(qf[ks], bh1[ks], sa1);
        sa1 = MFMA(qf[ks], bl1[ks], sa1);
      }
      // V prefetch (hi+lo) before the softmax chain
      u16x8 bvh[8], bvl[8];
#pragma unroll
      for (int t = 0; t < 8; ++t){
        bvh[t] = *(const u16x8*)(cvhp + (size_t)(t*16 + c16)*64 + kb + g16*8);
        bvl[t] = *(const u16x8*)(cvlp + (size_t)(t*16 + c16)*64 + kb + g16*8);
      }
#pragma unroll
      for (int r = 0; r < 4; ++r){
        const int row = g16*4 + r;
        sm_step(sa0[r]*RSQD, sa1[r]*RSQD, row, c16, m[r], sum[r], out, r, Plh, Pll);
      }
      asm volatile("s_waitcnt lgkmcnt(0)" ::: "memory");
      const u16x8 pah = *(const u16x8*)&Plh[c16*40 + g16*8];
      const u16x8 pal = *(const u16x8*)&Pll[c16*40 + g16*8];
#pragma unroll
      for (int t = 0; t < 8; ++t){
        out[t] = MFMA(pah, bvh[t], out[t]);
        out[t] = MFMA(pah, bvl[t], out[t]);
        out[t] = MFMA(pal, bvh[t], out[t]);
      }
    }
  } else {
    // ================= selected: precomputed masks, K pipelined over my-block list =======
    const size_t tb = (size_t)h*128 + tile;
    unsigned long long smr[4];
#pragma unroll
    for (int r = 0; r < 4; ++r) smr[r] = selm[tb*16 + g16*4 + r];
    const unsigned long long U = selU[tb];
    const int bq = tile >> 1;
    // split-fp32 Q fragments from Qs32 (hi/lo bf16 -> matches fp32-q scores)
    u16x8 qh[4], ql[4];
    {
      const float* qrow = Qs32 + (size_t)(q0 + c16)*DIMN + h*HEADD + g16*8;
#pragma unroll
      for (int ks = 0; ks < 4; ++ks){
        const float4 f0 = *(const float4*)(qrow + ks*32);
        const float4 f1 = *(const float4*)(qrow + ks*32 + 4);
        const float ff[8] = {f0.x,f0.y,f0.z,f0.w,f1.x,f1.y,f1.z,f1.w};
#pragma unroll
        for (int j = 0; j < 8; ++j){
          const unsigned short hh = f2b(ff[j]);
          qh[ks][j] = hh;
          ql[ks][j] = f2b(ff[j] - bfl(hh));
        }
      }
    }
    const unsigned short* Kb  = (const unsigned short*)Ks  + (size_t)kv*S_LEN*HEADD;
    const unsigned short* Vtb = (const unsigned short*)VsT + (size_t)kv*HEADD*S_LEN;
    // this wave's block subsequence (same ascending every-4th-selected order as before)
    unsigned long long myU = 0ull;
    {
      int cnt = 0;
      for (int b = 0; b <= bq; ++b){
        if ((U >> b) & 1ull){
          if ((cnt & 3) == wv) myU |= (1ull << b);
          ++cnt;
        }
      }
    }
    u16x8 kc0[4], kc1[4], kn0[4], kn1[4];
    int b = myU ? (__ffsll((long long)myU) - 1) : -1;
    myU &= myU - 1;
    if (b >= 0){
      const int kb = b*32;
#pragma unroll
      for (int ks = 0; ks < 4; ++ks){
        kc0[ks] = *(const u16x8*)(Kb + (size_t)(kb + c16)*HEADD      + g16*8 + ks*32);
        kc1[ks] = *(const u16x8*)(Kb + (size_t)(kb + 16 + c16)*HEADD + g16*8 + ks*32);
      }
    }
    while (b >= 0){
      const int kb = b*32;
      // V prefetch
      u16x8 bv[8];
#pragma unroll
      for (int t = 0; t < 8; ++t)
        bv[t] = *(const u16x8*)(Vtb + (size_t)(t*16 + c16)*S_LEN + kb + g16*8);
      f32x4 sa0 = {0.f,0.f,0.f,0.f}, sa1 = {0.f,0.f,0.f,0.f};
#pragma unroll
      for (int ks = 0; ks < 4; ++ks){
        sa0 = MFMA(qh[ks], kc0[ks], sa0);
        sa0 = MFMA(ql[ks], kc0[ks], sa0);
        sa1 = MFMA(qh[ks], kc1[ks], sa1);
        sa1 = MFMA(ql[ks], kc1[ks], sa1);
      }
      // K pipeline: issue next block's K now
      const int bn = myU ? (__ffsll((long long)myU) - 1) : -1;
      myU &= myU - 1;
      if (bn >= 0){
        const int kbn = bn*32;
#pragma unroll
        for (int ks = 0; ks < 4; ++ks){
          kn0[ks] = *(const u16x8*)(Kb + (size_t)(kbn + c16)*HEADD      + g16*8 + ks*32);
          kn1[ks] = *(const u16x8*)(Kb + (size_t)(kbn + 16 + c16)*HEADD + g16*8 + ks*32);
        }
      }
#pragma unroll
      for (int r = 0; r < 4; ++r){
        const int row = g16*4 + r;
        const int qi = q0 + row;
        const bool selr = (smr[r] >> b) & 1ull;
        const float s0 = (selr && (kb + c16      <= qi)) ? sa0[r]*RSQD : NEGINF;
        const float s1 = (selr && (kb + 16 + c16 <= qi)) ? sa1[r]*RSQD : NEGINF;
        sm_step(s0, s1, row, c16, m[r], sum[r], out, r, Plh, Pll);
      }
      asm volatile("s_waitcnt lgkmcnt(0)" ::: "memory");
      const u16x8 pah = *(const u16x8*)&Plh[c16*40 + g16*8];
      const u16x8 pal = *(const u16x8*)&Pll[c16*40 + g16*8];
#pragma unroll
      for (int t = 0; t < 8; ++t){
        out[t] = MFMA(pah, bv[t], out[t]);
        out[t] = MFMA(pal, bv[t], out[t]);
      }
#pragma unroll
      for (int ks = 0; ks < 4; ++ks){ kc0[ks] = kn0[ks]; kc1[ks] = kn1[ks]; }
      b = bn;
    }
  }

  // ---- export per-wave m/sum ----
  if (c16 == 0){
#pragma unroll
    for (int r = 0; r < 4; ++r){ mS[wv][g16*4 + r] = m[r]; sumS[wv][g16*4 + r] = sum[r]; }
  }
  __syncthreads();

  // ---- per-row global max + this wave's factor; serialized fp32 accumulation ----
  float fw[4];
#pragma unroll
  for (int r = 0; r < 4; ++r){
    const int row = g16*4 + r;
    const float M = fmaxf(fmaxf(mS[0][row], mS[1][row]), fmaxf(mS[2][row], mS[3][row]));
    fw[r] = (m[r] == NEGINF) ? 0.f : __expf(m[r] - M);
  }
#pragma unroll
  for (int w = 0; w < 4; ++w){
    if (wv == w){
#pragma unroll
      for (int r = 0; r < 4; ++r){
        const int row = g16*4 + r;
#pragma unroll
        for (int t = 0; t < 8; ++t){
          const float v = fw[r] * out[t][r];
          if (w == 0) outS[row][t*16 + c16] = v;
          else        outS[row][t*16 + c16] += v;
        }
      }
    }
    __syncthreads();
  }

  // ---- final write: thread -> (row, 8 cols) ----
  {
    const int row = tid >> 4, cc0 = (tid & 15) * 8;
    bool doit = true;
    if (branch == 2) doit = (selvis[(size_t)h*128 + tile] >> row) & 1u;
    if (doit){
      const float m0 = mS[0][row], m1 = mS[1][row], m2 = mS[2][row], m3 = mS[3][row];
      const float M = fmaxf(fmaxf(m0, m1), fmaxf(m2, m3));
      const float f0 = (m0 == NEGINF) ? 0.f : __expf(m0 - M);
      const float f1 = (m1 == NEGINF) ? 0.f : __expf(m1 - M);
      const float f2 = (m2 == NEGINF) ? 0.f : __expf(m2 - M);
      const float f3 = (m3 == NEGINF) ? 0.f : __expf(m3 - M);
      const float S = f0*sumS[0][row] + f1*sumS[1][row] + f2*sumS[2][row] + f3*sumS[3][row];
      const float gate = gates[(q0+row)*3 + branch];
      const float inv = gate / S;
      float* dst = (branch == 0) ? comb : (branch == 1) ? combC : combS;
      const size_t ob = (size_t)(q0+row)*DIMN + h*HEADD + cc0;
#pragma unroll
      for (int j = 0; j < 8; ++j)
        dst[ob + j] = outS[row][cc0 + j] * inv;
    }
  }

  // ---- degenerate sel rows: exact scalar path (wave 0 only, after last barrier) ----
  if (branch == 2 && wv == 0){
    unsigned degbits = (~selvis[(size_t)h*128 + tile]) & 0xffffu;
    if (degbits){
      const bf16* Kbase = Ks + (size_t)kv*S_LEN*HEADD;
      const bf16* Vbase = Vs + (size_t)kv*S_LEN*HEADD;
      while (degbits){
        const int qq = __ffs(degbits) - 1; degbits &= degbits - 1;
        const int qi = q0 + qq;
        {
          const float* qr = Qs32 + (size_t)qi*DIMN + h*HEADD;
          qv[l] = qr[l]; qv[l+64] = qr[l+64];
        }
        asm volatile("s_waitcnt lgkmcnt(0)" ::: "memory");
        float md = NEGINF, sumd = 0.f, a0 = 0.f, a1 = 0.f;
        for (int k0 = 0; k0 <= qi; k0 += 64){
          const int key = k0 + l;
          const bool valid = key <= qi;
          const int keyc = min(key, S_LEN-1);
          float s = dot128_bf16(qv, Kbase + (size_t)keyc*HEADD) * RSQD;
          s = valid ? s : NEGINF;
          const float tmax = wave_max(s);
          const float mn = fmaxf(md, tmax);
          const float p = valid ? __expf(s - mn) : 0.f;
          const float scale = __expf(md - mn);
          sumd = sumd*scale + wave_sum(p);
          a0 *= scale; a1 *= scale;
          const unsigned* Vt = (const unsigned*)(Vbase + (size_t)k0*HEADD) + l;
#pragma unroll 8
          for (int j = 0; j < 64; ++j){
            const float pj = lane_bcast(p, j);
            const int kj = min(k0 + j, S_LEN-1) - k0;
            const unsigned u = Vt[(size_t)kj*64];
            a0 += pj * bfl(u & 0xffffu);
            a1 += pj * bfl(u >> 16);
          }
          md = mn;
        }
        const float mn = fmaxf(md, 0.f);
        const float scale = __expf(md - mn);
        sumd *= scale; a0 *= scale; a1 *= scale;
        const float ef = __expf(-mn);
        sumd += (float)(2047 - qi) * ef;
        const float2 s2 = ((const float2*)(suffV + ((size_t)kv*2049 + (qi+1))*HEADD))[l];
        a0 += ef * s2.x; a1 += ef * s2.y;
        const float g2 = gates[qi*3 + 2];
        const float inv = g2 / sumd;
        const size_t ob = (size_t)qi*DIMN + h*HEADD + 2*l;
        combS[ob]   = a0 * inv;
        combS[ob+1] = a1 * inv;
        asm volatile("s_waitcnt lgkmcnt(0)" ::: "memory");
      }
    }
  }
}

// sum three fp32 partials -> bf16
__global__ __launch_bounds__(256) void combine_kernel(const float* __restrict__ a, const float* __restrict__ b,
    const float* __restrict__ c, bf16* __restrict__ outb)
{
  const int i = blockIdx.x*blockDim.x + threadIdx.x;   // float4 index
  const float4 va = ((const float4*)a)[i];
  const float4 vb = ((const float4*)b)[i];
  const float4 vc = ((const float4*)c)[i];
  us4 r;
  r[0] = f2b(va.x + vb.x + vc.x);
  r[1] = f2b(va.y + vb.y + vc.y);
  r[2] = f2b(va.z + vb.z + vc.z);
  r[3] = f2b(va.w + vb.w + vc.w);
  ((us4*)outb)[i] = r;
}

// ---------------- host ----------------
extern "C" void kernel_launch(void* const* d_in, const int* in_sizes, int n_in,
                              void* d_out, int out_size, void* d_ws, size_t ws_size,
                              hipStream_t stream)
{
  (void)in_sizes; (void)n_in; (void)out_size;
  const float* x          = (const float*)d_in[0];
  const float* wq_win     = (const float*)d_in[1];
  const float* wk_win     = (const float*)d_in[2];
  const float* wv_win     = (const float*)d_in[3];
  const float* wq_sel     = (const float*)d_in[4];
  const float* wk_sel     = (const float*)d_in[5];
  const float* wv_sel     = (const float*)d_in[6];
  const float* wq_comp    = (const float*)d_in[7];
  const float* wk_comp    = (const float*)d_in[8];
  const float* wv_comp    = (const float*)d_in[9];
  const float* w_comp_mlp = (const float*)d_in[10];
  const float* w_gate     = (const float*)d_in[11];
  const float* w_o        = (const float*)d_in[12];
  float* outp = (float*)d_out;

  char* ws = (char*)d_ws;
  size_t o = 0;
  auto alloc = [&](size_t b)->char*{ char* p = ws + o; o += (b + 255) & ~(size_t)255; return p; };
  float* cosT = (float*)alloc((size_t)S_LEN*64*4);
  float* sinT = (float*)alloc((size_t)S_LEN*64*4);
  char*  xb_base = alloc((size_t)S_LEN*DIMN*2);
  bf16*  Xb   = (bf16*)xb_base;                       // dead after proj GEMM -> combb
  char*  wall_base = alloc((size_t)12288*DIMN*2);     // 50.33 MB
  bf16*  Wall = (bf16*)wall_base;
  char*  y_base = alloc((size_t)S_LEN*12288*2);       // 50.33 MB
  bf16*  Y    = (bf16*)y_base;
  bf16*  Qw = (bf16*)alloc((size_t)NHEAD*S_LEN*HEADD*2);
  bf16*  Qs = (bf16*)alloc((size_t)NHEAD*S_LEN*HEADD*2);
  bf16*  Qc = (bf16*)alloc((size_t)NHEAD*S_LEN*HEADD*2);
  bf16*  Kw = (bf16*)alloc((size_t)NKV*S_LEN*HEADD*2);
  bf16*  Ks = (bf16*)alloc((size_t)NKV*S_LEN*HEADD*2);
  bf16*  Kc = (bf16*)alloc((size_t)NKV*S_LEN*HEADD*2);
  bf16*  Vw = (bf16*)alloc((size_t)NKV*S_LEN*HEADD*2);
  bf16*  Vs = (bf16*)alloc((size_t)NKV*S_LEN*HEADD*2);
  bf16*  Vc = (bf16*)alloc((size_t)NKV*S_LEN*HEADD*2);
  // Qs bf16 is dead in the MFMA design (sel uses split Qs32) -> reuse for transposed V tensors
  bf16*  VwT = Qs;                                         // [NKV][HEADD][S_LEN], 4 MB
  bf16*  VsT = Qs + (size_t)NKV*S_LEN*HEADD;               // [NKV][HEADD][S_LEN], 4 MB
  // Wall dead after projection GEMM: three fp32 branch partials (exactly 50.33 MB)
  size_t e = 0;
  auto alloc2 = [&](size_t b)->char*{ char* p = wall_base + e; e += (b + 255) & ~(size_t)255; return p; };
  float* comb   = (float*)alloc2((size_t)S_LEN*DIMN*4);
  float* combC  = (float*)alloc2((size_t)S_LEN*DIMN*4);
  float* combS  = (float*)alloc2((size_t)S_LEN*DIMN*4);
  // Pre-split hi/lo bf16 buffers overlay comb/combC/combS (dead until win_mean/attn;
  // consumed by the gemm_bt3_pair launch which completes before step 6; stream-ordered)
  bf16* x_hi   = (bf16*)comb;                                   // 8 MB
  bf16* x_lo   = (bf16*)comb  + (size_t)S_LEN*DIMN;             // 8 MB
  bf16* wqs_hi = (bf16*)combC;                                  // 8 MB
  bf16* wqs_lo = (bf16*)combC + (size_t)S_LEN*DIMN;             // 8 MB
  bf16* wkc_hi = (bf16*)combS;                                  // 4 MB
  bf16* wkc_lo = (bf16*)combS + (size_t)1024*DIMN;              // 4 MB
  // Y dead after rope_scatter: fp32 selection chain + small late-phase buffers
  size_t y = 0;
  auto alloc3 = [&](size_t b)->char*{ char* p = y_base + y; y += (b + 255) & ~(size_t)255; return p; };
  float* Qs32   = (float*)alloc3((size_t)S_LEN*DIMN*4);
  float* Kc32   = (float*)alloc3((size_t)S_LEN*1024*4);
  char*  kc32hm_base = alloc3((size_t)NKV*S_LEN*HEADD*4);
  float* Kc32hm = (float*)kc32hm_base;                 // dead after ck32 GEMM -> wob
  float* ck32   = (float*)alloc3((size_t)512*128*4);
  bf16*  Wm     = (bf16*) alloc3((size_t)128*4096*2);
  float* cv     = (float*)alloc3((size_t)512*128*4);
  float* gates  = (float*)alloc3((size_t)S_LEN*3*4);
  float* meanvw = (float*)alloc3((size_t)NKV*HEADD*4);
  float* chunkS = (float*)alloc3((size_t)NKV*16*HEADD*4);
  float* suffV  = (float*)alloc3((size_t)NKV*2049*HEADD*4);
  bf16*  ckh    = (bf16*)alloc3((size_t)NKV*64*HEADD*2);   // split ck hi/lo (B-frag layout)
  bf16*  ckl    = (bf16*)alloc3((size_t)NKV*64*HEADD*2);
  bf16*  cvTh   = (bf16*)alloc3((size_t)NKV*HEADD*64*2);   // split cv^T hi/lo
  bf16*  cvTl   = (bf16*)alloc3((size_t)NKV*HEADD*64*2);
  unsigned long long* selm = (unsigned long long*)alloc3((size_t)NHEAD*128*16*8);  // 256 KB
  unsigned long long* selU = (unsigned long long*)alloc3((size_t)NHEAD*128*8);
  unsigned*           selvis = (unsigned*)alloc3((size_t)NHEAD*128*4);
  bf16*  wob    = (bf16*)kc32hm_base;                  // reuse: 8.4 MB bf16 in 8.4 MB fp32 region
  bf16*  combb  = (bf16*)xb_base;                      // reuse Xb
  if (o > ws_size) return;

  // 1) tables + FUSED vectorized bf16 conversions (x + 9 weights, one launch — R13)
  build_tables_kernel<<<dim3((S_LEN*64 + 255)/256), dim3(256), 0, stream>>>(cosT, sinT);
  cvt_fuse_kernel<<<dim3(2048), dim3(256), 0, stream>>>(x, wq_win, wk_win, wv_win,
                                                        wq_sel, wk_sel, wv_sel,
                                                        wq_comp, wk_comp, wv_comp,
                                                        Xb, Wall);
  // 2) fused QKV projection (bf16): Y[2048][12288] = Xb @ Wall^T
  gemm_bt<true><<<dim3(96, 16), dim3(256), 0, stream>>>(Xb, Wall, Y, 2048, 12288, 2048);
  // 3) RoPE + scatter into head-major bf16 q/k/v
  rope_scatter_kernel<<<dim3(S_LEN), dim3(256), 0, stream>>>(Y, cosT, sinT, Qw, Kw, Vw, Qs, Ks, Vs, Qc, Kc, Vc);
  // 3a) transposed V copies for MFMA B-fragments (overwrite dead Qs region)
  vtrans_kernel<<<dim3(32, 2, 8), dim3(256), 0, stream>>>(Vw, VwT);
  vtrans_kernel<<<dim3(32, 2, 8), dim3(256), 0, stream>>>(Vs, VsT);
  // 3b) fp32-accurate selection chain: FUSED pre-split, then ONE paired 3-pass GEMM (R14)
  split3_kernel<<<dim3(1024), dim3(256), 0, stream>>>(x, wq_sel, wk_comp,
                                                      x_hi, x_lo, wqs_hi, wqs_lo, wkc_hi, wkc_lo);
  gemm_bt3_pair<<<dim3(24, 16), dim3(256), 0, stream>>>(x_hi, x_lo,
                                                        wqs_hi, wqs_lo, Qs32,
                                                        wkc_hi, wkc_lo, Kc32, 2048);
  rope32_pair_kernel<<<dim3(S_LEN, 2), dim3(256), 0, stream>>>(Qs32, Kc32, cosT, sinT);
  khm_kernel<<<dim3(S_LEN*1024/256), dim3(256), 0, stream>>>(Kc32, Kc32hm);
  gemm_bt_split<<<dim3(1, 4), dim3(256), 0, stream>>>(Kc32hm, w_comp_mlp, ck32, 512, 128, 4096);
  // 3c) selection masks (exact scores, rank-based top-16)
  sel_select_kernel<<<dim3(128, 16), dim3(64), 0, stream>>>(Qs32, ck32, selm, selU, selvis);
  // 4) compress MLP value path; FUSED vectorized Wm + wob conversion (R14; wob region is
  //    dead only after the ck32 GEMM above — ordering preserved)
  cvt2_kernel<<<dim3(1024), dim3(256), 0, stream>>>(w_comp_mlp, w_o, Wm, wob);
  gemm_bt<false><<<dim3(1, 4), dim3(256), 0, stream>>>(Vc, Wm, cv, 512, 128, 4096);
  // 4b) split-bf16 ck + transposed split-bf16 cv for the compressed MFMA branch
  comp_prep_kernel<<<dim3(256), dim3(256), 0, stream>>>(ck32, cv, ckh, ckl, cvTh, cvTl);
  // 5) gates, window mean, V suffix sums
  gates_kernel<<<dim3(S_LEN), dim3(64), 0, stream>>>(x, w_gate, gates);
  meanv_kernel<<<dim3(NKV), dim3(256), 0, stream>>>(Vw, meanvw);
  suffv_a_kernel<<<dim3(NKV, 16), dim3(256), 0, stream>>>(Vs, chunkS);
  suffv_b_kernel<<<dim3(NKV, 16), dim3(128), 0, stream>>>(Vs, chunkS, suffV);
  // 6) window-mean rows (q<1536) + fused 3-branch MFMA attention (R11 structure)
  win_mean_kernel<<<dim3(WSTART), dim3(256), 0, stream>>>(meanvw, gates, comb);
  attn_mfma_kernel<<<dim3(16, 288), dim3(256), 0, stream>>>(Qw, Kw, VwT, Qc, ckh, ckl, cvTh, cvTl,
                                                            Qs32, Ks, VsT, Vs, suffV, gates,
                                                            selm, selU, selvis,
                                                            comb, combC, combS);
  // 7) combine partials -> bf16, then output projection
  combine_kernel<<<dim3(S_LEN*DIMN/4/256), dim3(256), 0, stream>>>(comb, combC, combS, combb);
  gemm_bt<false><<<dim3(16, 16), dim3(256), 0, stream>>>(combb, wob, outp, 2048, 2048, 2048);
}

// Round 15
// 1062.947 us; speedup vs baseline: 1.1438x; 1.0085x over previous
//
#include <hip/hip_runtime.h>
#include <hip/hip_bf16.h>
#include <math.h>

// Problem constants (B=1)
#define S_LEN  2048
#define DIMN   2048
#define NHEAD  16
#define NKV    8
#define HEADD  128
#define WSTART 1536      // S - WIN
#define RSQD   0.08838834764831845f   // 1/sqrt(128)
#define NEGINF (-INFINITY)

typedef __hip_bfloat16 bf16;
typedef __attribute__((ext_vector_type(8))) __bf16 bf16x8;
typedef __attribute__((ext_vector_type(8))) unsigned short u16x8;
typedef __attribute__((ext_vector_type(4))) unsigned short us4;
typedef __attribute__((ext_vector_type(4))) float  f32x4;

__device__ __forceinline__ float bfl(unsigned u){ u <<= 16; float f; __builtin_memcpy(&f, &u, 4); return f; }
// fp32 -> bf16 bits, RTNE
__device__ __forceinline__ unsigned short f2b(float f){
  unsigned u; __builtin_memcpy(&u, &f, 4);
  u += 0x7fff + ((u >> 16) & 1);
  return (unsigned short)(u >> 16);
}
// broadcast lane j's float via v_readlane
__device__ __forceinline__ float lane_bcast(float v, int lane){
  int i; __builtin_memcpy(&i, &v, 4);
  i = __builtin_amdgcn_readlane(i, lane);
  float f; __builtin_memcpy(&f, &i, 4);
  return f;
}

__device__ __forceinline__ float wave_max(float v){
#pragma unroll
  for (int o = 32; o; o >>= 1) v = fmaxf(v, __shfl_xor(v, o));
  return v;
}
__device__ __forceinline__ float wave_sum(float v){
#pragma unroll
  for (int o = 32; o; o >>= 1) v += __shfl_xor(v, o);
  return v;
}

// ---- DPP 16-lane butterfly reduce (row = 16 lanes on CDNA) ----
template<int CTRL>
__device__ __forceinline__ float dpp_f(float v){
  int i; __builtin_memcpy(&i, &v, 4);
  i = __builtin_amdgcn_update_dpp(i, i, CTRL, 0xf, 0xf, false);
  float f; __builtin_memcpy(&f, &i, 4);
  return f;
}
__device__ __forceinline__ float gmax16(float v){
  v = fmaxf(v, dpp_f<0xB1>(v));    // quad_perm(1,0,3,2)  xor1
  v = fmaxf(v, dpp_f<0x4E>(v));    // quad_perm(2,3,0,1)  xor2
  v = fmaxf(v, dpp_f<0x141>(v));   // row_half_mirror     (quad exchange)
  v = fmaxf(v, dpp_f<0x140>(v));   // row_mirror          (half exchange)
  return v;
}
__device__ __forceinline__ float gsum16(float v){
  v += dpp_f<0xB1>(v);
  v += dpp_f<0x4E>(v);
  v += dpp_f<0x141>(v);
  v += dpp_f<0x140>(v);
  return v;
}

__device__ __forceinline__ float dot128_bf16(const float* __restrict__ qv, const bf16* __restrict__ krow){
  const uint4* kp = (const uint4*)krow;
  float s = 0.f;
#pragma unroll
  for (int t = 0; t < 16; ++t){
    uint4 u = kp[t];
    const float* q8 = qv + t*8;
    s += q8[0]*bfl(u.x & 0xffffu) + q8[1]*bfl(u.x >> 16)
       + q8[2]*bfl(u.y & 0xffffu) + q8[3]*bfl(u.y >> 16)
       + q8[4]*bfl(u.z & 0xffffu) + q8[5]*bfl(u.z >> 16)
       + q8[6]*bfl(u.w & 0xffffu) + q8[7]*bfl(u.w >> 16);
  }
  return s;
}

// exact summation order kept (selection top-k tie behavior must match the proven kernel)
__device__ __forceinline__ float dot128_f32(const float* __restrict__ qv, const float* __restrict__ row){
  const float4* rp = (const float4*)row;
  float s = 0.f;
#pragma unroll
  for (int t = 0; t < 32; ++t){
    float4 r = rp[t];
    const float* q4 = qv + t*4;
    s += q4[0]*r.x + q4[1]*r.y + q4[2]*r.z + q4[3]*r.w;
  }
  return s;
}

// u16x8 (bf16 bits) MFMA wrapper
__device__ __forceinline__ f32x4 MFMA(u16x8 a, u16x8 b, f32x4 c){
  bf16x8 ab, bb;
  __builtin_memcpy(&ab, &a, 16);
  __builtin_memcpy(&bb, &b, 16);
  return __builtin_amdgcn_mfma_f32_16x16x32_bf16(ab, bb, c, 0, 0, 0);
}

// L2-locality supertile remap (R10, bit-identical; kept — neutral)
__device__ __forceinline__ void remap_bc_br(int& bc, int& br){
  const int GN = gridDim.x, GM = gridDim.y;
  const int lin = blockIdx.y * GN + blockIdx.x;
  const int per = GM * 8;
  const int sc = lin / per, rem = lin % per;
  br = rem % GM;
  bc = sc * 8 + rem / GM;
}

// ---------------- GEMM: C[M][N] = A[M][K] * B[N][K]^T  (bf16 in, fp32 acc) ----------------
template<bool OUT_BF16>
__global__ __launch_bounds__(256) void gemm_bt(const bf16* __restrict__ A, const bf16* __restrict__ B,
                                               void* __restrict__ Cp, int M, int N, int K)
{
  __shared__ __align__(16) bf16 As[128*32];
  __shared__ __align__(16) bf16 Bs[128*32];
  const int t = threadIdx.x;
  const int w = t >> 6, l = t & 63;
  int bc, br; remap_bc_br(bc, br);
  const int wr = w >> 1, wc = w & 1;
  f32x4 acc[4][4];
  {
    f32x4 z = {0.f, 0.f, 0.f, 0.f};
#pragma unroll
    for (int m = 0; m < 4; ++m)
#pragma unroll
      for (int n = 0; n < 4; ++n) acc[m][n] = z;
  }
  const int srow = l >> 2, scol = (l & 3) * 8;
  const int lrow = l & 15, lko = (l >> 4) * 8;

  for (int kt = 0; kt < K; kt += 32){
#pragma unroll
    for (int cc = 0; cc < 2; ++cc){
      const int c = w + cc*4;
      const bf16* gA = A + (size_t)(br*128 + c*16 + srow)*K + kt + scol;
      const bf16* gB = B + (size_t)(bc*128 + c*16 + srow)*K + kt + scol;
      __builtin_amdgcn_global_load_lds((const __attribute__((address_space(1))) void*)gA,
                                       (__attribute__((address_space(3))) void*)&As[c*512], 16, 0, 0);
      __builtin_amdgcn_global_load_lds((const __attribute__((address_space(1))) void*)gB,
                                       (__attribute__((address_space(3))) void*)&Bs[c*512], 16, 0, 0);
    }
    __syncthreads();
    bf16x8 af[4], bfr[4];
#pragma unroll
    for (int m = 0; m < 4; ++m) af[m]  = *(const bf16x8*)&As[(wr*64 + m*16 + lrow)*32 + lko];
#pragma unroll
    for (int n = 0; n < 4; ++n) bfr[n] = *(const bf16x8*)&Bs[(wc*64 + n*16 + lrow)*32 + lko];
#pragma unroll
    for (int m = 0; m < 4; ++m)
#pragma unroll
      for (int n = 0; n < 4; ++n)
        acc[m][n] = __builtin_amdgcn_mfma_f32_16x16x32_bf16(af[m], bfr[n], acc[m][n], 0, 0, 0);
    __syncthreads();
  }
  const int crow0 = br*128 + wr*64 + (l >> 4)*4;
  const int ccol  = bc*128 + wc*64 + lrow;
#pragma unroll
  for (int m = 0; m < 4; ++m)
#pragma unroll
    for (int n = 0; n < 4; ++n)
#pragma unroll
      for (int r = 0; r < 4; ++r){
        const size_t idx = (size_t)(crow0 + m*16 + r)*N + (ccol + n*16);
        if constexpr (OUT_BF16) ((bf16*)Cp)[idx] = __float2bfloat16(acc[m][n][r]);
        else                    ((float*)Cp)[idx] = acc[m][n][r];
      }
}

// ---------------- pre-split 3-pass GEMM PAIR: two targets sharing A, one launch (R14) ------
__global__ __launch_bounds__(256) void gemm_bt3_pair(
    const bf16* __restrict__ Ahg, const bf16* __restrict__ Alg,
    const bf16* __restrict__ B1h, const bf16* __restrict__ B1l, float* __restrict__ C1,
    const bf16* __restrict__ B2h, const bf16* __restrict__ B2l, float* __restrict__ C2,
    int K)
{
  __shared__ __align__(16) bf16 AhS[128*32], AlS[128*32], BhS[128*32], BlS[128*32];
  const int t = threadIdx.x;
  const int w = t >> 6, l = t & 63;
  const bf16* Bhg; const bf16* Blg; float* C; int N, GN, bcx;
  if (blockIdx.x < 16){ Bhg = B1h; Blg = B1l; C = C1; N = 2048; GN = 16; bcx = blockIdx.x; }
  else                { Bhg = B2h; Blg = B2l; C = C2; N = 1024; GN = 8;  bcx = blockIdx.x - 16; }
  int bc, br;
  {
    const int GM = 16;
    const int lin = blockIdx.y * GN + bcx;
    const int per = GM * 8;
    const int sc = lin / per, rem = lin % per;
    br = rem % GM;
    bc = sc * 8 + rem / GM;
  }
  const int wr = w >> 1, wc = w & 1;
  f32x4 acc[4][4];
  {
    f32x4 z = {0.f, 0.f, 0.f, 0.f};
#pragma unroll
    for (int m = 0; m < 4; ++m)
#pragma unroll
      for (int n = 0; n < 4; ++n) acc[m][n] = z;
  }
  const int srow = l >> 2, scol = (l & 3) * 8;
  const int lrow = l & 15, lko = (l >> 4) * 8;

  for (int kt = 0; kt < K; kt += 32){
#pragma unroll
    for (int cc = 0; cc < 2; ++cc){
      const int c = w + cc*4;
      const size_t aoff = (size_t)(br*128 + c*16 + srow)*K + kt + scol;
      const size_t boff = (size_t)(bc*128 + c*16 + srow)*K + kt + scol;
      __builtin_amdgcn_global_load_lds((const __attribute__((address_space(1))) void*)(Ahg + aoff),
                                       (__attribute__((address_space(3))) void*)&AhS[c*512], 16, 0, 0);
      __builtin_amdgcn_global_load_lds((const __attribute__((address_space(1))) void*)(Alg + aoff),
                                       (__attribute__((address_space(3))) void*)&AlS[c*512], 16, 0, 0);
      __builtin_amdgcn_global_load_lds((const __attribute__((address_space(1))) void*)(Bhg + boff),
                                       (__attribute__((address_space(3))) void*)&BhS[c*512], 16, 0, 0);
      __builtin_amdgcn_global_load_lds((const __attribute__((address_space(1))) void*)(Blg + boff),
                                       (__attribute__((address_space(3))) void*)&BlS[c*512], 16, 0, 0);
    }
    __syncthreads();
    bf16x8 ahf[4], alf[4], bhf[4], blf[4];
#pragma unroll
    for (int m = 0; m < 4; ++m){
      ahf[m] = *(const bf16x8*)&AhS[(wr*64 + m*16 + lrow)*32 + lko];
      alf[m] = *(const bf16x8*)&AlS[(wr*64 + m*16 + lrow)*32 + lko];
    }
#pragma unroll
    for (int n = 0; n < 4; ++n){
      bhf[n] = *(const bf16x8*)&BhS[(wc*64 + n*16 + lrow)*32 + lko];
      blf[n] = *(const bf16x8*)&BlS[(wc*64 + n*16 + lrow)*32 + lko];
    }
#pragma unroll
    for (int m = 0; m < 4; ++m)
#pragma unroll
      for (int n = 0; n < 4; ++n){
        acc[m][n] = __builtin_amdgcn_mfma_f32_16x16x32_bf16(ahf[m], bhf[n], acc[m][n], 0, 0, 0);
        acc[m][n] = __builtin_amdgcn_mfma_f32_16x16x32_bf16(ahf[m], blf[n], acc[m][n], 0, 0, 0);
        acc[m][n] = __builtin_amdgcn_mfma_f32_16x16x32_bf16(alf[m], bhf[n], acc[m][n], 0, 0, 0);
      }
    __syncthreads();
  }
  const int crow0 = br*128 + wr*64 + (l >> 4)*4;
  const int ccol  = bc*128 + wc*64 + lrow;
#pragma unroll
  for (int m = 0; m < 4; ++m)
#pragma unroll
    for (int n = 0; n < 4; ++n)
#pragma unroll
      for (int r = 0; r < 4; ++r)
        C[(size_t)(crow0 + m*16 + r)*N + (ccol + n*16)] = acc[m][n][r];
}

// ---------------- split-bf16 emulated-fp32 GEMM (kept for the small ck32 GEMM) ----------------
__global__ __launch_bounds__(256) void gemm_bt_split(const float* __restrict__ A, const float* __restrict__ B,
                                                     float* __restrict__ C, int M, int N, int K)
{
  __shared__ __align__(16) unsigned short Ah[128*32], Al[128*32], Bh[128*32], Bl[128*32];
  const int t = threadIdx.x;
  const int w = t >> 6, l = t & 63;
  const int bc = blockIdx.x, br = blockIdx.y;
  const int wr = w >> 1, wc = w & 1;
  f32x4 acc[4][4];
  {
    f32x4 z = {0.f, 0.f, 0.f, 0.f};
#pragma unroll
    for (int m = 0; m < 4; ++m)
#pragma unroll
      for (int n = 0; n < 4; ++n) acc[m][n] = z;
  }
  const int lrow = l & 15, lko = (l >> 4) * 8;

  for (int kt = 0; kt < K; kt += 32){
#pragma unroll
    for (int i = 0; i < 4; ++i){
      const int lin = t + i*256;
      const int row = lin >> 3;
      const int cq  = (lin & 7) * 4;
      const float4 va = *(const float4*)&A[(size_t)(br*128 + row)*K + kt + cq];
      const float4 vb = *(const float4*)&B[(size_t)(bc*128 + row)*K + kt + cq];
      const float fa[4] = {va.x, va.y, va.z, va.w};
      const float fb[4] = {vb.x, vb.y, vb.z, vb.w};
      us4 ah, al2, bh, bl2;
#pragma unroll
      for (int j = 0; j < 4; ++j){
        const unsigned short h = f2b(fa[j]); ah[j] = h; al2[j] = f2b(fa[j] - bfl(h));
        const unsigned short g = f2b(fb[j]); bh[j] = g; bl2[j] = f2b(fb[j] - bfl(g));
      }
      *(us4*)&Ah[row*32 + cq] = ah;  *(us4*)&Al[row*32 + cq] = al2;
      *(us4*)&Bh[row*32 + cq] = bh;  *(us4*)&Bl[row*32 + cq] = bl2;
    }
    __syncthreads();
    bf16x8 ahf[4], alf[4], bhf[4], blf[4];
#pragma unroll
    for (int m = 0; m < 4; ++m){
      ahf[m] = *(const bf16x8*)&Ah[(wr*64 + m*16 + lrow)*32 + lko];
      alf[m] = *(const bf16x8*)&Al[(wr*64 + m*16 + lrow)*32 + lko];
    }
#pragma unroll
    for (int n = 0; n < 4; ++n){
      bhf[n] = *(const bf16x8*)&Bh[(wc*64 + n*16 + lrow)*32 + lko];
      blf[n] = *(const bf16x8*)&Bl[(wc*64 + n*16 + lrow)*32 + lko];
    }
#pragma unroll
    for (int m = 0; m < 4; ++m)
#pragma unroll
      for (int n = 0; n < 4; ++n){
        acc[m][n] = __builtin_amdgcn_mfma_f32_16x16x32_bf16(ahf[m], bhf[n], acc[m][n], 0, 0, 0);
        acc[m][n] = __builtin_amdgcn_mfma_f32_16x16x32_bf16(ahf[m], blf[n], acc[m][n], 0, 0, 0);
        acc[m][n] = __builtin_amdgcn_mfma_f32_16x16x32_bf16(alf[m], bhf[n], acc[m][n], 0, 0, 0);
      }
    __syncthreads();
  }
  const int crow0 = br*128 + wr*64 + (l >> 4)*4;
  const int ccol  = bc*128 + wc*64 + lrow;
#pragma unroll
  for (int m = 0; m < 4; ++m)
#pragma unroll
    for (int n = 0; n < 4; ++n)
#pragma unroll
      for (int r = 0; r < 4; ++r)
        C[(size_t)(crow0 + m*16 + r)*N + (ccol + n*16)] = acc[m][n][r];
}

// ---------------- small utility kernels ----------------
__global__ void build_tables_kernel(float* __restrict__ cosT, float* __restrict__ sinT){
  const int idx = blockIdx.x*blockDim.x + threadIdx.x;
  if (idx >= S_LEN*64) return;
  const int s = idx >> 6, i = idx & 63;
  const float inv = powf(10000.f, -(float)(2*i) / 128.f);
  const float ang = (float)s * inv;
  cosT[idx] = cosf(ang);
  sinT[idx] = sinf(ang);
}

// R13: ONE launch, float4-vectorized, converts x + all 9 weights (10 compile-time ranges).
__global__ __launch_bounds__(256) void cvt_fuse_kernel(
    const float* __restrict__ x,
    const float* __restrict__ w0, const float* __restrict__ w1, const float* __restrict__ w2,
    const float* __restrict__ w3, const float* __restrict__ w4, const float* __restrict__ w5,
    const float* __restrict__ w6, const float* __restrict__ w7, const float* __restrict__ w8,
    bf16* __restrict__ Xb, bf16* __restrict__ Wall)
{
  const int stride = gridDim.x * blockDim.x;
  for (int i = blockIdx.x*blockDim.x + threadIdx.x; i < 7340032; i += stride){
    const float* src; us4* dst; int li;
    if      (i < 1048576){ src = x;  dst = (us4*)Xb;                li = i; }
    else if (i < 2097152){ src = w0; dst = (us4*)Wall;              li = i - 1048576; }
    else if (i < 2621440){ src = w1; dst = (us4*)(Wall +  4194304); li = i - 2097152; }
    else if (i < 3145728){ src = w2; dst = (us4*)(Wall +  6291456); li = i - 2621440; }
    else if (i < 4194304){ src = w3; dst = (us4*)(Wall +  8388608); li = i - 3145728; }
    else if (i < 4718592){ src = w4; dst = (us4*)(Wall + 12582912); li = i - 4194304; }
    else if (i < 5242880){ src = w5; dst = (us4*)(Wall + 14680064); li = i - 4718592; }
    else if (i < 6291456){ src = w6; dst = (us4*)(Wall + 16777216); li = i - 5242880; }
    else if (i < 6815744){ src = w7; dst = (us4*)(Wall + 20971520); li = i - 6291456; }
    else                 { src = w8; dst = (us4*)(Wall + 23068672); li = i - 6815744; }
    const float4 v = ((const float4*)src)[li];
    us4 r;
    r[0] = __bfloat16_as_ushort(__float2bfloat16(v.x));
    r[1] = __bfloat16_as_ushort(__float2bfloat16(v.y));
    r[2] = __bfloat16_as_ushort(__float2bfloat16(v.z));
    r[3] = __bfloat16_as_ushort(__float2bfloat16(v.w));
    dst[li] = r;
  }
}

// R14: ONE launch, float4-vectorized, converts w_comp_mlp (Wm) + w_o (wob).
__global__ __launch_bounds__(256) void cvt2_kernel(
    const float* __restrict__ wm_src, const float* __restrict__ wo_src,
    bf16* __restrict__ Wm, bf16* __restrict__ wob)
{
  const int stride = gridDim.x * blockDim.x;
  for (int i = blockIdx.x*blockDim.x + threadIdx.x; i < 1179648; i += stride){
    const float* src; us4* dst; int li;
    if (i < 131072){ src = wm_src; dst = (us4*)Wm;  li = i; }
    else           { src = wo_src; dst = (us4*)wob; li = i - 131072; }
    const float4 v = ((const float4*)src)[li];
    us4 r;
    r[0] = __bfloat16_as_ushort(__float2bfloat16(v.x));
    r[1] = __bfloat16_as_ushort(__float2bfloat16(v.y));
    r[2] = __bfloat16_as_ushort(__float2bfloat16(v.z));
    r[3] = __bfloat16_as_ushort(__float2bfloat16(v.w));
    dst[li] = r;
  }
}

// R13: ONE launch for all three hi/lo splits (x, wq_sel, wk_comp).
__global__ __launch_bounds__(256) void split3_kernel(
    const float* __restrict__ xx, const float* __restrict__ wqs, const float* __restrict__ wkc,
    bf16* __restrict__ x_hi, bf16* __restrict__ x_lo,
    bf16* __restrict__ wqs_hi, bf16* __restrict__ wqs_lo,
    bf16* __restrict__ wkc_hi, bf16* __restrict__ wkc_lo)
{
  const int stride = gridDim.x * blockDim.x;
  for (int i = blockIdx.x*blockDim.x + threadIdx.x; i < 2621440; i += stride){
    const float* src; us4* dh; us4* dl; int li;
    if      (i < 1048576){ src = xx;  dh = (us4*)x_hi;   dl = (us4*)x_lo;   li = i; }
    else if (i < 2097152){ src = wqs; dh = (us4*)wqs_hi; dl = (us4*)wqs_lo; li = i - 1048576; }
    else                 { src = wkc; dh = (us4*)wkc_hi; dl = (us4*)wkc_lo; li = i - 2097152; }
    const float4 v = ((const float4*)src)[li];
    const float f[4] = {v.x, v.y, v.z, v.w};
    us4 h, l2;
#pragma unroll
    for (int j = 0; j < 4; ++j){
      const unsigned short hh = f2b(f[j]);
      h[j] = hh;
      l2[j] = f2b(f[j] - bfl(hh));
    }
    dh[li] = h;
    dl[li] = l2;
  }
}

// R14: both fp32 RoPE passes (Qs32 C=2048, Kc32 C=1024) in one launch; bit-identical.
__global__ void rope32_pair_kernel(float* __restrict__ Q, float* __restrict__ Kc,
                                   const float* __restrict__ cosT, const float* __restrict__ sinT){
  const int s = blockIdx.x;
  float* row; int C;
  if (blockIdx.y == 0){ row = Q  + (size_t)s*2048; C = 2048; }
  else                { row = Kc + (size_t)s*1024; C = 1024; }
  for (int p = threadIdx.x; p < (C >> 1); p += blockDim.x){
    const int i = p & 63;
    const int col = (p >> 6)*128 + 2*i;
    const float a = row[col], b = row[col+1];
    const float c = cosT[s*64 + i], sn = sinT[s*64 + i];
    row[col]   = a*c - b*sn;
    row[col+1] = a*sn + b*c;
  }
}

// [s][kv*128+d] -> [kv][s][d] fp32 — R15: float4 both sides (d%4 runs never cross kv rows);
// pure copy, bit-identical.
__global__ void khm_kernel(const float* __restrict__ src, float* __restrict__ dst){
  const int idx = blockIdx.x*blockDim.x + threadIdx.x;   // float4 index
  if (idx >= S_LEN*1024/4) return;
  const int lin = idx << 2;
  const int s = lin >> 10, c = lin & 1023;
  const int kv = c >> 7, d = c & 127;
  *(float4*)&dst[((size_t)kv*S_LEN + s)*HEADD + d] = ((const float4*)src)[idx];
}

// Y[s][12288] -> 9 head-major bf16 tensors with RoPE on q/k
// R15: uint4-vectorized (8 cols/iter; all region and head boundaries are %8==0, stores are
// 16B-aligned u16x8). Same per-element arithmetic as the scalar version -> bit-identical.
__global__ void rope_scatter_kernel(const bf16* __restrict__ Y, const float* __restrict__ cosT,
    const float* __restrict__ sinT,
    bf16* __restrict__ Qw, bf16* __restrict__ Kw, bf16* __restrict__ Vw,
    bf16* __restrict__ Qs, bf16* __restrict__ Ks, bf16* __restrict__ Vs,
    bf16* __restrict__ Qc, bf16* __restrict__ Kc, bf16* __restrict__ Vc)
{
  const int s = blockIdx.x;
  const uint4* Yrow = (const uint4*)(Y + (size_t)s*12288);   // 1536 uint4 per row
  for (int p4 = threadIdx.x; p4 < 1536; p4 += blockDim.x){
    const int col = p4*8;
    bf16* dst; int base; bool isv = false;
    if (col < 4096){
      if      (col < 2048){ dst = Qw; base = 0; }
      else if (col < 3072){ dst = Kw; base = 2048; }
      else                { dst = Vw; base = 3072; isv = true; }
    } else if (col < 8192){
      if      (col < 6144){ dst = Qs; base = 4096; }
      else if (col < 7168){ dst = Ks; base = 6144; }
      else                { dst = Vs; base = 7168; isv = true; }
    } else {
      if      (col < 10240){ dst = Qc; base = 8192; }
      else if (col < 11264){ dst = Kc; base = 10240; }
      else                 { dst = Vc; base = 11264; isv = true; }
    }
    const int lc = col - base;
    const int head = lc >> 7, d0 = lc & 127;
    const uint4 yy = Yrow[p4];
    const unsigned uu[4] = {yy.x, yy.y, yy.z, yy.w};
    u16x8 outv;
#pragma unroll
    for (int j = 0; j < 4; ++j){
      const int i = (d0 >> 1) + j;
      float a = bfl(uu[j] & 0xffffu), b = bfl(uu[j] >> 16);
      if (!isv){
        const float c = cosT[s*64 + i], sn = sinT[s*64 + i];
        const float na = a*c - b*sn;
        b = a*sn + b*c;
        a = na;
      }
      outv[2*j]   = __bfloat16_as_ushort(__float2bfloat16(a));
      outv[2*j+1] = __bfloat16_as_ushort(__float2bfloat16(b));
    }
    *(u16x8*)((unsigned short*)dst + ((size_t)head*S_LEN + s)*HEADD + d0) = outv;
  }
}

// R15: BOTH V transposes (Vw->VwT, Vs->VsT) in one launch (z<8: Vw, z>=8: Vs).
// Same 64x64 tiles as the two vtrans launches it replaces -> bit-identical.
__global__ __launch_bounds__(256) void vtrans2_kernel(const bf16* __restrict__ Vw, const bf16* __restrict__ Vs,
                                                      bf16* __restrict__ VwT, bf16* __restrict__ VsT){
  __shared__ unsigned short tile[64][72];   // 72: keeps 16B-aligned rows (144B)
  const int z = blockIdx.z;
  const bf16* src = (z < 8) ? Vw : Vs;
  bf16* dst = (z < 8) ? VwT : VsT;
  const int kv = z & 7;
  const int r0 = blockIdx.x*64;   // S dim
  const int c0 = blockIdx.y*64;   // D dim
  const int t = threadIdx.x;
  const int lr = t >> 2, lc = (t & 3)*16;
  const unsigned short* sp = (const unsigned short*)src + ((size_t)kv*S_LEN + r0 + lr)*HEADD + c0 + lc;
  *(u16x8*)&tile[lr][lc]     = *(const u16x8*)sp;
  *(u16x8*)&tile[lr][lc + 8] = *(const u16x8*)(sp + 8);
  __syncthreads();
  unsigned short* dp = (unsigned short*)dst + ((size_t)kv*HEADD + c0 + lr)*S_LEN + r0 + lc;
  u16x8 v0, v1;
#pragma unroll
  for (int j = 0; j < 8; ++j){ v0[j] = tile[lc + j][lr]; v1[j] = tile[lc + 8 + j][lr]; }
  *(u16x8*)dp       = v0;
  *(u16x8*)(dp + 8) = v1;
}

// ck32/cv [NKV][64][HEADD] fp32 -> hi/lo bf16 (ck as-is, cv transposed to [NKV][HEADD][64])
__global__ void comp_prep_kernel(const float* __restrict__ ck32, const float* __restrict__ cv,
    bf16* __restrict__ ckh, bf16* __restrict__ ckl, bf16* __restrict__ cvTh, bf16* __restrict__ cvTl)
{
  const int i = blockIdx.x*256 + threadIdx.x;
  if (i >= NKV*64*HEADD) return;
  const int kv = i >> 13, rem = i & 8191, key = rem >> 7, d = rem & 127;
  const float a = ck32[i];
  const unsigned short ah = f2b(a);
  ((unsigned short*)ckh)[i] = ah;
  ((unsigned short*)ckl)[i] = f2b(a - bfl(ah));
  const float b = cv[i];
  const unsigned short bh = f2b(b);
  const size_t j = ((size_t)kv*HEADD + d)*64 + key;
  ((unsigned short*)cvTh)[j] = bh;
  ((unsigned short*)cvTl)[j] = f2b(b - bfl(bh));
}

__global__ __launch_bounds__(64) void gates_kernel(const float* __restrict__ x,
    const float* __restrict__ wg, float* __restrict__ gates)
{
  const int r = blockIdx.x, l = threadIdx.x;
  const float* xr = x + (size_t)r*DIMN;
  float p0 = 0.f, p1 = 0.f, p2 = 0.f;
  for (int i = l; i < DIMN; i += 64){
    const float xv = xr[i];
    p0 += xv * wg[i];
    p1 += xv * wg[DIMN + i];
    p2 += xv * wg[2*DIMN + i];
  }
  p0 = wave_sum(p0); p1 = wave_sum(p1); p2 = wave_sum(p2);
  if (l == 0){
    const float mx = fmaxf(p0, fmaxf(p1, p2));
    const float e0 = expf(p0-mx), e1 = expf(p1-mx), e2 = expf(p2-mx);
    const float inv = 1.f/(e0+e1+e2);
    gates[r*3+0] = e0*inv; gates[r*3+1] = e1*inv; gates[r*3+2] = e2*inv;
  }
}

// R15: meanv (y==16) + suffv_a (y<16) fused into one launch; same reductions -> bit-identical.
__global__ __launch_bounds__(256) void meansuff_kernel(const bf16* __restrict__ Vw,
    const bf16* __restrict__ Vs, float* __restrict__ mean_vw, float* __restrict__ chunkSums)
{
  const int kv = blockIdx.x, t = threadIdx.x;
  const int d = t & 127, half = t >> 7;
  __shared__ float red[256];
  if (blockIdx.y == 16){
    const bf16* base = Vw + ((size_t)kv*S_LEN + WSTART + half*256)*HEADD + d;
    float acc = 0.f;
    for (int r = 0; r < 256; ++r) acc += __bfloat162float(base[(size_t)r*HEADD]);
    red[t] = acc;
    __syncthreads();
    if (!half) mean_vw[kv*HEADD + d] = (red[d] + red[128 + d]) * (1.f/512.f);
  } else {
    const int ch = blockIdx.y;
    const bf16* base = Vs + ((size_t)kv*S_LEN + ch*128 + half*64)*HEADD + d;
    float acc = 0.f;
    for (int r = 0; r < 64; ++r) acc += __bfloat162float(base[(size_t)r*HEADD]);
    red[t] = acc;
    __syncthreads();
    if (!half) chunkSums[((size_t)kv*16 + ch)*HEADD + d] = red[d] + red[128 + d];
  }
}

__global__ __launch_bounds__(128) void suffv_b_kernel(const bf16* __restrict__ Vs,
    const float* __restrict__ chunkSums, float* __restrict__ suffV){
  const int kv = blockIdx.x, ch = blockIdx.y, d = threadIdx.x;
  float acc = 0.f;
  for (int c = ch + 1; c < 16; ++c) acc += chunkSums[((size_t)kv*16 + c)*HEADD + d];
  const int s0 = ch*128;
  for (int r = 127; r >= 0; --r){
    acc += __bfloat162float(Vs[((size_t)kv*S_LEN + s0 + r)*HEADD + d]);
    suffV[((size_t)kv*2049 + s0 + r)*HEADD + d] = acc;
  }
  if (ch == 15) suffV[((size_t)kv*2049 + 2048)*HEADD + d] = 0.f;
}

// ---------------- selection kernel: exact dot order + rank-based top-16 ----------------
__global__ __launch_bounds__(64) void sel_select_kernel(
    const float* __restrict__ Qs32, const float* __restrict__ ck32,
    unsigned long long* __restrict__ selm, unsigned long long* __restrict__ selU,
    unsigned* __restrict__ selvis)
{
  const int tile = blockIdx.x, h = blockIdx.y, kv = h >> 1, l = threadIdx.x;
  const int q0 = tile*16, bq = tile >> 1;
  __shared__ float impS[16][64];
  __shared__ unsigned short pmaskS[16][4];
  __shared__ unsigned long long vmS[16];
  const float* ckrow = ck32 + (size_t)(kv*64 + l)*HEADD;
#pragma unroll
  for (int qq = 0; qq < 16; ++qq){
    const float* qr = Qs32 + (size_t)(q0+qq)*DIMN + h*HEADD;
    impS[qq][l] = dot128_f32(qr, ckrow);
  }
  __syncthreads();
  const int row = l >> 2, part = l & 3;
  float mine[16];
#pragma unroll
  for (int j = 0; j < 16; ++j) mine[j] = impS[row][part*16 + j];
  int rk[16];
#pragma unroll
  for (int j = 0; j < 16; ++j) rk[j] = 0;
  for (int b = 0; b < 64; ++b){
    const float vb = impS[row][b];
#pragma unroll
    for (int j = 0; j < 16; ++j){
      const int idxj = part*16 + j;
      rk[j] += ((vb > mine[j]) || (vb == mine[j] && b < idxj)) ? 1 : 0;
    }
  }
  unsigned pm = 0;
#pragma unroll
  for (int j = 0; j < 16; ++j) if (rk[j] < 16) pm |= (1u << j);
  pmaskS[row][part] = (unsigned short)pm;
  __syncthreads();
  if (l < 16){
    const unsigned long long sm =
        (unsigned long long)pmaskS[l][0]
      | ((unsigned long long)pmaskS[l][1] << 16)
      | ((unsigned long long)pmaskS[l][2] << 32)
      | ((unsigned long long)pmaskS[l][3] << 48);
    selm[((size_t)h*128 + tile)*16 + l] = sm;
    vmS[l] = (bq >= 63) ? sm : (sm & ((1ull << (bq+1)) - 1ull));
  }
  __syncthreads();
  if (l == 0){
    unsigned long long U = 0ull; unsigned vis = 0u;
#pragma unroll
    for (int i = 0; i < 16; ++i){ U |= vmS[i]; vis |= (vmS[i] ? 1u : 0u) << i; }
    selU[(size_t)h*128 + tile] = U;
    selvis[(size_t)h*128 + tile] = vis;
  }
}

// ---------------- MFMA fused attention, 4-way key-split flash (R11 structure) ----------------
// R6: LPT grid. R7: V-prefetch. R8: __expf. R11: K-load software pipeline.
// R15: win_mean folded in as by in [288,384) (trivial per-row write, early return).

// online-softmax step; row-group reduces are DPP (no LDS shuffles)
__device__ __forceinline__ void sm_step(float s0, float s1, int row, int c16,
                                        float& m, float& sum, f32x4* out, int r,
                                        unsigned short* Plh, unsigned short* Pll)
{
  const float mx = gmax16(fmaxf(s0, s1));
  const float mn = fmaxf(m, mx);
  float p0, p1, scale;
  if (mn == NEGINF){ p0 = 0.f; p1 = 0.f; scale = 1.f; }        // fully-masked-so-far row
  else { scale = __expf(m - mn); p0 = __expf(s0 - mn); p1 = __expf(s1 - mn); }
  const bool needscale = (mn != m);
  m = mn;
  sum = sum*scale + gsum16(p0 + p1);
  if (needscale){
#pragma unroll
    for (int t = 0; t < 8; ++t) out[t][r] *= scale;
  }
  const unsigned short h0 = f2b(p0), h1 = f2b(p1);
  Plh[row*40 + c16]      = h0;
  Plh[row*40 + 16 + c16] = h1;
  Pll[row*40 + c16]      = f2b(p0 - bfl(h0));
  Pll[row*40 + 16 + c16] = f2b(p1 - bfl(h1));
}

__global__ __launch_bounds__(256) void attn_mfma_kernel(
    const bf16* __restrict__ Qw, const bf16* __restrict__ Kw, const bf16* __restrict__ VwT,
    const bf16* __restrict__ Qc, const bf16* __restrict__ ckh, const bf16* __restrict__ ckl,
    const bf16* __restrict__ cvTh, const bf16* __restrict__ cvTl,
    const float* __restrict__ Qs32, const bf16* __restrict__ Ks, const bf16* __restrict__ VsT,
    const bf16* __restrict__ Vs,
    const float* __restrict__ suffV, const float* __restrict__ gates,
    const float* __restrict__ mean_vw,
    const unsigned long long* __restrict__ selm, const unsigned long long* __restrict__ selU,
    const unsigned* __restrict__ selvis,
    float* __restrict__ comb, float* __restrict__ combC, float* __restrict__ combS)
{
  const int h = blockIdx.x, kv = h >> 1;     // heads on X (dispatch-fastest axis)
  const int tid = threadIdx.x, wv = tid >> 6, l = tid & 63;
  const int g16 = l >> 4, c16 = l & 15;
  const int bx = blockIdx.y;                 // branch/tile on Y

  // R15: win-mean rows (q<1536), one block per row; same formula as old win_mean_kernel
  if (bx >= 288){
    const int q = (bx - 288)*16 + h;
    const float g0 = gates[q*3];
    for (int cc = tid; cc < DIMN; cc += 256)
      comb[(size_t)q*DIMN + cc] = g0 * mean_vw[(cc >> 8)*HEADD + (cc & 127)];
    return;
  }

  __shared__ unsigned short PlhS[4][640], PllS[4][640];
  __shared__ float outS[16][132];               // +4 pad: spreads rows across banks
  __shared__ float mS[4][16], sumS[4][16];
  __shared__ float qv[128];
  unsigned short* Plh = PlhS[wv];
  unsigned short* Pll = PllS[wv];

  f32x4 out[8];
  float m[4], sum[4];
#pragma unroll
  for (int t = 0; t < 8; ++t) out[t] = (f32x4){0.f,0.f,0.f,0.f};
#pragma unroll
  for (int r = 0; r < 4; ++r){ m[r] = NEGINF; sum[r] = 0.f; }

  int branch, tile, q0;                         // branch: 0=win 1=comp 2=sel (gate index)
  if (bx < 128)      { branch = 2; tile = 127 - bx;  q0 = tile*16; }
  else if (bx < 160) { branch = 0; tile = 159 - bx;  q0 = WSTART + tile*16; }
  else               { branch = 1; tile = bx - 160;  q0 = tile*16; }

  if (branch == 0){
    // ================= window: keys [1536, qi], chunks round-robin; K pipelined =========
    u16x8 qf[4];
    {
      const unsigned short* qrow = (const unsigned short*)Qw + ((size_t)h*S_LEN + q0 + c16)*HEADD + g16*8;
#pragma unroll
      for (int ks = 0; ks < 4; ++ks) qf[ks] = *(const u16x8*)(qrow + ks*32);
    }
    const unsigned short* Kb  = (const unsigned short*)Kw  + (size_t)kv*S_LEN*HEADD;
    const unsigned short* Vtb = (const unsigned short*)VwT + (size_t)kv*HEADD*S_LEN;
    const int cmax = tile >> 1;
    u16x8 kc0[4], kc1[4], kn0[4], kn1[4];
    int c = wv;
    if (c <= cmax){
      const int kb = WSTART + c*32;
#pragma unroll
      for (int ks = 0; ks < 4; ++ks){
        kc0[ks] = *(const u16x8*)(Kb + (size_t)(kb + c16)*HEADD      + g16*8 + ks*32);
        kc1[ks] = *(const u16x8*)(Kb + (size_t)(kb + 16 + c16)*HEADD + g16*8 + ks*32);
      }
    }
    for (; c <= cmax; c += 4){
      const int kb = WSTART + c*32;
      // V prefetch: issue early so HBM/L2 latency hides under the softmax chain
      u16x8 bv[8];
#pragma unroll
      for (int t = 0; t < 8; ++t)
        bv[t] = *(const u16x8*)(Vtb + (size_t)(t*16 + c16)*S_LEN + kb + g16*8);
      f32x4 sa0 = {0.f,0.f,0.f,0.f}, sa1 = {0.f,0.f,0.f,0.f};
#pragma unroll
      for (int ks = 0; ks < 4; ++ks){
        sa0 = MFMA(qf[ks], kc0[ks], sa0);
        sa1 = MFMA(qf[ks], kc1[ks], sa1);
      }
      // K pipeline: issue next chunk's K now — softmax+PV covers its latency
      const int cn = c + 4;
      const int kbn = WSTART + min(cn, cmax)*32;
      if (cn <= cmax){
#pragma unroll
        for (int ks = 0; ks < 4; ++ks){
          kn0[ks] = *(const u16x8*)(Kb + (size_t)(kbn + c16)*HEADD      + g16*8 + ks*32);
          kn1[ks] = *(const u16x8*)(Kb + (size_t)(kbn + 16 + c16)*HEADD + g16*8 + ks*32);
        }
      }
#pragma unroll
      for (int r = 0; r < 4; ++r){
        const int row = g16*4 + r;
        const int qi = q0 + row;
        const float s0 = (kb + c16      <= qi) ? sa0[r]*RSQD : NEGINF;
        const float s1 = (kb + 16 + c16 <= qi) ? sa1[r]*RSQD : NEGINF;
        sm_step(s0, s1, row, c16, m[r], sum[r], out, r, Plh, Pll);
      }
      asm volatile("s_waitcnt lgkmcnt(0)" ::: "memory");
      const u16x8 pah = *(const u16x8*)&Plh[c16*40 + g16*8];
      const u16x8 pal = *(const u16x8*)&Pll[c16*40 + g16*8];
#pragma unroll
      for (int t = 0; t < 8; ++t){
        out[t] = MFMA(pah, bv[t], out[t]);
        out[t] = MFMA(pal, bv[t], out[t]);
      }
#pragma unroll
      for (int ks = 0; ks < 4; ++ks){ kc0[ks] = kn0[ks]; kc1[ks] = kn1[ks]; }
    }
  } else if (branch == 1){
    // ================= compressed: 64 keys, non-causal, waves 0/1 take one chunk each ====
    // (cross-wave combine below is REQUIRED: each wave sees only half the keys — R5 bug)
    u16x8 qf[4];
    {
      const unsigned short* qrow = (const unsigned short*)Qc + ((size_t)h*S_LEN + q0 + c16)*HEADD + g16*8;
#pragma unroll
      for (int ks = 0; ks < 4; ++ks) qf[ks] = *(const u16x8*)(qrow + ks*32);
    }
    const unsigned short* ckhp = (const unsigned short*)ckh  + (size_t)kv*64*HEADD;
    const unsigned short* cklp = (const unsigned short*)ckl  + (size_t)kv*64*HEADD;
    const unsigned short* cvhp = (const unsigned short*)cvTh + (size_t)kv*HEADD*64;
    const unsigned short* cvlp = (const unsigned short*)cvTl + (size_t)kv*HEADD*64;
    for (int ch = wv; ch < 2; ch += 4){
      const int kb = ch*32;
      u16x8 bh0[4], bh1[4], bl0[4], bl1[4];
#pragma unroll
      for (int ks = 0; ks < 4; ++ks){
        bh0[ks] = *(const u16x8*)(ckhp + (size_t)(kb + c16)*HEADD      + g16*8 + ks*32);
        bh1[ks] = *(const u16x8*)(ckhp + (size_t)(kb + 16 + c16)*HEADD + g16*8 + ks*32);
        bl0[ks] = *(const u16x8*)(cklp + (size_t)(kb + c16)*HEADD      + g16*8 + ks*32);
        bl1[ks] = *(const u16x8*)(cklp + (size_t)(kb + 16 + c16)*HEADD + g16*8 + ks*32);
      }
      f32x4 sa0 = {0.f,0.f,0.f,0.f}, sa1 = {0.f,0.f,0.f,0.f};
#pragma unroll
      for (int ks = 0; ks < 4; ++ks){
        sa0 = MFMA(qf[ks], bh0[ks], sa0);
        sa0 = MFMA(qf[ks], bl0[ks], sa0);
        sa1 = MFMA(qf[ks], bh1[ks], sa1);
        sa1 = MFMA(qf[ks], bl1[ks], sa1);
      }
      // V prefetch (hi+lo) before the softmax chain
      u16x8 bvh[8], bvl[8];
#pragma unroll
      for (int t = 0; t < 8; ++t){
        bvh[t] = *(const u16x8*)(cvhp + (size_t)(t*16 + c16)*64 + kb + g16*8);
        bvl[t] = *(const u16x8*)(cvlp + (size_t)(t*16 + c16)*64 + kb + g16*8);
      }
#pragma unroll
      for (int r = 0; r < 4; ++r){
        const int row = g16*4 + r;
        sm_step(sa0[r]*RSQD, sa1[r]*RSQD, row, c16, m[r], sum[r], out, r, Plh, Pll);
      }
      asm volatile("s_waitcnt lgkmcnt(0)" ::: "memory");
      const u16x8 pah = *(const u16x8*)&Plh[c16*40 + g16*8];
      const u16x8 pal = *(const u16x8*)&Pll[c16*40 + g16*8];
#pragma unroll
      for (int t = 0; t < 8; ++t){
        out[t] = MFMA(pah, bvh[t], out[t]);
        out[t] = MFMA(pah, bvl[t], out[t]);
        out[t] = MFMA(pal, bvh[t], out[t]);
      }
    }
  } else {
    // ================= selected: precomputed masks, K pipelined over my-block list =======
    const size_t tb = (size_t)h*128 + tile;
    unsigned long long smr[4];
#pragma unroll
    for (int r = 0; r < 4; ++r) smr[r] = selm[tb*16 + g16*4 + r];
    const unsigned long long U = selU[tb];
    const int bq = tile >> 1;
    // split-fp32 Q fragments from Qs32 (hi/lo bf16 -> matches fp32-q scores)
    u16x8 qh[4], ql[4];
    {
      const float* qrow = Qs32 + (size_t)(q0 + c16)*DIMN + h*HEADD + g16*8;
#pragma unroll
      for (int ks = 0; ks < 4; ++ks){
        const float4 f0 = *(const float4*)(qrow + ks*32);
        const float4 f1 = *(const float4*)(qrow + ks*32 + 4);
        const float ff[8] = {f0.x,f0.y,f0.z,f0.w,f1.x,f1.y,f1.z,f1.w};
#pragma unroll
        for (int j = 0; j < 8; ++j){
          const unsigned short hh = f2b(ff[j]);
          qh[ks][j] = hh;
          ql[ks][j] = f2b(ff[j] - bfl(hh));
        }
      }
    }
    const unsigned short* Kb  = (const unsigned short*)Ks  + (size_t)kv*S_LEN*HEADD;
    const unsigned short* Vtb = (const unsigned short*)VsT + (size_t)kv*HEADD*S_LEN;
    // this wave's block subsequence (same ascending every-4th-selected order as before)
    unsigned long long myU = 0ull;
    {
      int cnt = 0;
      for (int b = 0; b <= bq; ++b){
        if ((U >> b) & 1ull){
          if ((cnt & 3) == wv) myU |= (1ull << b);
          ++cnt;
        }
      }
    }
    u16x8 kc0[4], kc1[4], kn0[4], kn1[4];
    int b = myU ? (__ffsll((long long)myU) - 1) : -1;
    myU &= myU - 1;
    if (b >= 0){
      const int kb = b*32;
#pragma unroll
      for (int ks = 0; ks < 4; ++ks){
        kc0[ks] = *(const u16x8*)(Kb + (size_t)(kb + c16)*HEADD      + g16*8 + ks*32);
        kc1[ks] = *(const u16x8*)(Kb + (size_t)(kb + 16 + c16)*HEADD + g16*8 + ks*32);
      }
    }
    while (b >= 0){
      const int kb = b*32;
      // V prefetch
      u16x8 bv[8];
#pragma unroll
      for (int t = 0; t < 8; ++t)
        bv[t] = *(const u16x8*)(Vtb + (size_t)(t*16 + c16)*S_LEN + kb + g16*8);
      f32x4 sa0 = {0.f,0.f,0.f,0.f}, sa1 = {0.f,0.f,0.f,0.f};
#pragma unroll
      for (int ks = 0; ks < 4; ++ks){
        sa0 = MFMA(qh[ks], kc0[ks], sa0);
        sa0 = MFMA(ql[ks], kc0[ks], sa0);
        sa1 = MFMA(qh[ks], kc1[ks], sa1);
        sa1 = MFMA(ql[ks], kc1[ks], sa1);
      }
      // K pipeline: issue next block's K now
      const int bn = myU ? (__ffsll((long long)myU) - 1) : -1;
      myU &= myU - 1;
      if (bn >= 0){
        const int kbn = bn*32;
#pragma unroll
        for (int ks = 0; ks < 4; ++ks){
          kn0[ks] = *(const u16x8*)(Kb + (size_t)(kbn + c16)*HEADD      + g16*8 + ks*32);
          kn1[ks] = *(const u16x8*)(Kb + (size_t)(kbn + 16 + c16)*HEADD + g16*8 + ks*32);
        }
      }
#pragma unroll
      for (int r = 0; r < 4; ++r){
        const int row = g16*4 + r;
        const int qi = q0 + row;
        const bool selr = (smr[r] >> b) & 1ull;
        const float s0 = (selr && (kb + c16      <= qi)) ? sa0[r]*RSQD : NEGINF;
        const float s1 = (selr && (kb + 16 + c16 <= qi)) ? sa1[r]*RSQD : NEGINF;
        sm_step(s0, s1, row, c16, m[r], sum[r], out, r, Plh, Pll);
      }
      asm volatile("s_waitcnt lgkmcnt(0)" ::: "memory");
      const u16x8 pah = *(const u16x8*)&Plh[c16*40 + g16*8];
      const u16x8 pal = *(const u16x8*)&Pll[c16*40 + g16*8];
#pragma unroll
      for (int t = 0; t < 8; ++t){
        out[t] = MFMA(pah, bv[t], out[t]);
        out[t] = MFMA(pal, bv[t], out[t]);
      }
#pragma unroll
      for (int ks = 0; ks < 4; ++ks){ kc0[ks] = kn0[ks]; kc1[ks] = kn1[ks]; }
      b = bn;
    }
  }

  // ---- export per-wave m/sum ----
  if (c16 == 0){
#pragma unroll
    for (int r = 0; r < 4; ++r){ mS[wv][g16*4 + r] = m[r]; sumS[wv][g16*4 + r] = sum[r]; }
  }
  __syncthreads();

  // ---- per-row global max + this wave's factor; serialized fp32 accumulation ----
  float fw[4];
#pragma unroll
  for (int r = 0; r < 4; ++r){
    const int row = g16*4 + r;
    const float M = fmaxf(fmaxf(mS[0][row], mS[1][row]), fmaxf(mS[2][row], mS[3][row]));
    fw[r] = (m[r] == NEGINF) ? 0.f : __expf(m[r] - M);
  }
#pragma unroll
  for (int w = 0; w < 4; ++w){
    if (wv == w){
#pragma unroll
      for (int r = 0; r < 4; ++r){
        const int row = g16*4 + r;
#pragma unroll
        for (int t = 0; t < 8; ++t){
          const float v = fw[r] * out[t][r];
          if (w == 0) outS[row][t*16 + c16] = v;
          else        outS[row][t*16 + c16] += v;
        }
      }
    }
    __syncthreads();
  }

  // ---- final write: thread -> (row, 8 cols) ----
  {
    const int row = tid >> 4, cc0 = (tid & 15) * 8;
    bool doit = true;
    if (branch == 2) doit = (selvis[(size_t)h*128 + tile] >> row) & 1u;
    if (doit){
      const float m0 = mS[0][row], m1 = mS[1][row], m2 = mS[2][row], m3 = mS[3][row];
      const float M = fmaxf(fmaxf(m0, m1), fmaxf(m2, m3));
      const float f0 = (m0 == NEGINF) ? 0.f : __expf(m0 - M);
      const float f1 = (m1 == NEGINF) ? 0.f : __expf(m1 - M);
      const float f2 = (m2 == NEGINF) ? 0.f : __expf(m2 - M);
      const float f3 = (m3 == NEGINF) ? 0.f : __expf(m3 - M);
      const float S = f0*sumS[0][row] + f1*sumS[1][row] + f2*sumS[2][row] + f3*sumS[3][row];
      const float gate = gates[(q0+row)*3 + branch];
      const float inv = gate / S;
      float* dst = (branch == 0) ? comb : (branch == 1) ? combC : combS;
      const size_t ob = (size_t)(q0+row)*DIMN + h*HEADD + cc0;
#pragma unroll
      for (int j = 0; j < 8; ++j)
        dst[ob + j] = outS[row][cc0 + j] * inv;
    }
  }

  // ---- degenerate sel rows: exact scalar path (wave 0 only, after last barrier) ----
  if (branch == 2 && wv == 0){
    unsigned degbits = (~selvis[(size_t)h*128 + tile]) & 0xffffu;
    if (degbits){
      const bf16* Kbase = Ks + (size_t)kv*S_LEN*HEADD;
      const bf16* Vbase = Vs + (size_t)kv*S_LEN*HEADD;
      while (degbits){
        const int qq = __ffs(degbits) - 1; degbits &= degbits - 1;
        const int qi = q0 + qq;
        {
          const float* qr = Qs32 + (size_t)qi*DIMN + h*HEADD;
          qv[l] = qr[l]; qv[l+64] = qr[l+64];
        }
        asm volatile("s_waitcnt lgkmcnt(0)" ::: "memory");
        float md = NEGINF, sumd = 0.f, a0 = 0.f, a1 = 0.f;
        for (int k0 = 0; k0 <= qi; k0 += 64){
          const int key = k0 + l;
          const bool valid = key <= qi;
          const int keyc = min(key, S_LEN-1);
          float s = dot128_bf16(qv, Kbase + (size_t)keyc*HEADD) * RSQD;
          s = valid ? s : NEGINF;
          const float tmax = wave_max(s);
          const float mn = fmaxf(md, tmax);
          const float p = valid ? __expf(s - mn) : 0.f;
          const float scale = __expf(md - mn);
          sumd = sumd*scale + wave_sum(p);
          a0 *= scale; a1 *= scale;
          const unsigned* Vt = (const unsigned*)(Vbase + (size_t)k0*HEADD) + l;
#pragma unroll 8
          for (int j = 0; j < 64; ++j){
            const float pj = lane_bcast(p, j);
            const int kj = min(k0 + j, S_LEN-1) - k0;
            const unsigned u = Vt[(size_t)kj*64];
            a0 += pj * bfl(u & 0xffffu);
            a1 += pj * bfl(u >> 16);
          }
          md = mn;
        }
        const float mn = fmaxf(md, 0.f);
        const float scale = __expf(md - mn);
        sumd *= scale; a0 *= scale; a1 *= scale;
        const float ef = __expf(-mn);
        sumd += (float)(2047 - qi) * ef;
        const float2 s2 = ((const float2*)(suffV + ((size_t)kv*2049 + (qi+1))*HEADD))[l];
        a0 += ef * s2.x; a1 += ef * s2.y;
        const float g2 = gates[qi*3 + 2];
        const float inv = g2 / sumd;
        const size_t ob = (size_t)qi*DIMN + h*HEADD + 2*l;
        combS[ob]   = a0 * inv;
        combS[ob+1] = a1 * inv;
        asm volatile("s_waitcnt lgkmcnt(0)" ::: "memory");
      }
    }
  }
}

// sum three fp32 partials -> bf16
__global__ __launch_bounds__(256) void combine_kernel(const float* __restrict__ a, const float* __restrict__ b,
    const float* __restrict__ c, bf16* __restrict__ outb)
{
  const int i = blockIdx.x*blockDim.x + threadIdx.x;   // float4 index
  const float4 va = ((const float4*)a)[i];
  const float4 vb = ((const float4*)b)[i];
  const float4 vc = ((const float4*)c)[i];
  us4 r;
  r[0] = f2b(va.x + vb.x + vc.x);
  r[1] = f2b(va.y + vb.y + vc.y);
  r[2] = f2b(va.z + vb.z + vc.z);
  r[3] = f2b(va.w + vb.w + vc.w);
  ((us4*)outb)[i] = r;
}

// ---------------- host ----------------
extern "C" void kernel_launch(void* const* d_in, const int* in_sizes, int n_in,
                              void* d_out, int out_size, void* d_ws, size_t ws_size,
                              hipStream_t stream)
{
  (void)in_sizes; (void)n_in; (void)out_size;
  const float* x          = (const float*)d_in[0];
  const float* wq_win     = (const float*)d_in[1];
  const float* wk_win     = (const float*)d_in[2];
  const float* wv_win     = (const float*)d_in[3];
  const float* wq_sel     = (const float*)d_in[4];
  const float* wk_sel     = (const float*)d_in[5];
  const float* wv_sel     = (const float*)d_in[6];
  const float* wq_comp    = (const float*)d_in[7];
  const float* wk_comp    = (const float*)d_in[8];
  const float* wv_comp    = (const float*)d_in[9];
  const float* w_comp_mlp = (const float*)d_in[10];
  const float* w_gate     = (const float*)d_in[11];
  const float* w_o        = (const float*)d_in[12];
  float* outp = (float*)d_out;

  char* ws = (char*)d_ws;
  size_t o = 0;
  auto alloc = [&](size_t b)->char*{ char* p = ws + o; o += (b + 255) & ~(size_t)255; return p; };
  float* cosT = (float*)alloc((size_t)S_LEN*64*4);
  float* sinT = (float*)alloc((size_t)S_LEN*64*4);
  char*  xb_base = alloc((size_t)S_LEN*DIMN*2);
  bf16*  Xb   = (bf16*)xb_base;                       // dead after proj GEMM -> combb
  char*  wall_base = alloc((size_t)12288*DIMN*2);     // 50.33 MB
  bf16*  Wall = (bf16*)wall_base;
  char*  y_base = alloc((size_t)S_LEN*12288*2);       // 50.33 MB
  bf16*  Y    = (bf16*)y_base;
  bf16*  Qw = (bf16*)alloc((size_t)NHEAD*S_LEN*HEADD*2);
  bf16*  Qs = (bf16*)alloc((size_t)NHEAD*S_LEN*HEADD*2);
  bf16*  Qc = (bf16*)alloc((size_t)NHEAD*S_LEN*HEADD*2);
  bf16*  Kw = (bf16*)alloc((size_t)NKV*S_LEN*HEADD*2);
  bf16*  Ks = (bf16*)alloc((size_t)NKV*S_LEN*HEADD*2);
  bf16*  Kc = (bf16*)alloc((size_t)NKV*S_LEN*HEADD*2);
  bf16*  Vw = (bf16*)alloc((size_t)NKV*S_LEN*HEADD*2);
  bf16*  Vs = (bf16*)alloc((size_t)NKV*S_LEN*HEADD*2);
  bf16*  Vc = (bf16*)alloc((size_t)NKV*S_LEN*HEADD*2);
  // Qs bf16 is dead in the MFMA design (sel uses split Qs32) -> reuse for transposed V tensors
  bf16*  VwT = Qs;                                         // [NKV][HEADD][S_LEN], 4 MB
  bf16*  VsT = Qs + (size_t)NKV*S_LEN*HEADD;               // [NKV][HEADD][S_LEN], 4 MB
  // Wall dead after projection GEMM: three fp32 branch partials (exactly 50.33 MB)
  size_t e = 0;
  auto alloc2 = [&](size_t b)->char*{ char* p = wall_base + e; e += (b + 255) & ~(size_t)255; return p; };
  float* comb   = (float*)alloc2((size_t)S_LEN*DIMN*4);
  float* combC  = (float*)alloc2((size_t)S_LEN*DIMN*4);
  float* combS  = (float*)alloc2((size_t)S_LEN*DIMN*4);
  // Pre-split hi/lo bf16 buffers overlay comb/combC/combS (dead until win_mean/attn;
  // consumed by the gemm_bt3_pair launch which completes before step 6; stream-ordered)
  bf16* x_hi   = (bf16*)comb;                                   // 8 MB
  bf16* x_lo   = (bf16*)comb  + (size_t)S_LEN*DIMN;             // 8 MB
  bf16* wqs_hi = (bf16*)combC;                                  // 8 MB
  bf16* wqs_lo = (bf16*)combC + (size_t)S_LEN*DIMN;             // 8 MB
  bf16* wkc_hi = (bf16*)combS;                                  // 4 MB
  bf16* wkc_lo = (bf16*)combS + (size_t)1024*DIMN;              // 4 MB
  // Y dead after rope_scatter: fp32 selection chain + small late-phase buffers
  size_t y = 0;
  auto alloc3 = [&](size_t b)->char*{ char* p = y_base + y; y += (b + 255) & ~(size_t)255; return p; };
  float* Qs32   = (float*)alloc3((size_t)S_LEN*DIMN*4);
  float* Kc32   = (float*)alloc3((size_t)S_LEN*1024*4);
  char*  kc32hm_base = alloc3((size_t)NKV*S_LEN*HEADD*4);
  float* Kc32hm = (float*)kc32hm_base;                 // dead after ck32 GEMM -> wob
  float* ck32   = (float*)alloc3((size_t)512*128*4);
  bf16*  Wm     = (bf16*) alloc3((size_t)128*4096*2);
  float* cv     = (float*)alloc3((size_t)512*128*4);
  float* gates  = (float*)alloc3((size_t)S_LEN*3*4);
  float* meanvw = (float*)alloc3((size_t)NKV*HEADD*4);
  float* chunkS = (float*)alloc3((size_t)NKV*16*HEADD*4);
  float* suffV  = (float*)alloc3((size_t)NKV*2049*HEADD*4);
  bf16*  ckh    = (bf16*)alloc3((size_t)NKV*64*HEADD*2);   // split ck hi/lo (B-frag layout)
  bf16*  ckl    = (bf16*)alloc3((size_t)NKV*64*HEADD*2);
  bf16*  cvTh   = (bf16*)alloc3((size_t)NKV*HEADD*64*2);   // split cv^T hi/lo
  bf16*  cvTl   = (bf16*)alloc3((size_t)NKV*HEADD*64*2);
  unsigned long long* selm = (unsigned long long*)alloc3((size_t)NHEAD*128*16*8);  // 256 KB
  unsigned long long* selU = (unsigned long long*)alloc3((size_t)NHEAD*128*8);
  unsigned*           selvis = (unsigned*)alloc3((size_t)NHEAD*128*4);
  bf16*  wob    = (bf16*)kc32hm_base;                  // reuse: 8.4 MB bf16 in 8.4 MB fp32 region
  bf16*  combb  = (bf16*)xb_base;                      // reuse Xb
  if (o > ws_size) return;

  // 1) tables + FUSED vectorized bf16 conversions (x + 9 weights, one launch — R13)
  build_tables_kernel<<<dim3((S_LEN*64 + 255)/256), dim3(256), 0, stream>>>(cosT, sinT);
  cvt_fuse_kernel<<<dim3(2048), dim3(256), 0, stream>>>(x, wq_win, wk_win, wv_win,
                                                        wq_sel, wk_sel, wv_sel,
                                                        wq_comp, wk_comp, wv_comp,
                                                        Xb, Wall);
  // 2) fused QKV projection (bf16): Y[2048][12288] = Xb @ Wall^T
  gemm_bt<true><<<dim3(96, 16), dim3(256), 0, stream>>>(Xb, Wall, Y, 2048, 12288, 2048);
  // 3) RoPE + scatter into head-major bf16 q/k/v (R15: uint4-vectorized)
  rope_scatter_kernel<<<dim3(S_LEN), dim3(256), 0, stream>>>(Y, cosT, sinT, Qw, Kw, Vw, Qs, Ks, Vs, Qc, Kc, Vc);
  // 3a) BOTH transposed V copies in one launch (R15)
  vtrans2_kernel<<<dim3(32, 2, 16), dim3(256), 0, stream>>>(Vw, Vs, VwT, VsT);
  // 3b) fp32-accurate selection chain: FUSED pre-split, then ONE paired 3-pass GEMM (R14)
  split3_kernel<<<dim3(1024), dim3(256), 0, stream>>>(x, wq_sel, wk_comp,
                                                      x_hi, x_lo, wqs_hi, wqs_lo, wkc_hi, wkc_lo);
  gemm_bt3_pair<<<dim3(24, 16), dim3(256), 0, stream>>>(x_hi, x_lo,
                                                        wqs_hi, wqs_lo, Qs32,
                                                        wkc_hi, wkc_lo, Kc32, 2048);
  rope32_pair_kernel<<<dim3(S_LEN, 2), dim3(256), 0, stream>>>(Qs32, Kc32, cosT, sinT);
  khm_kernel<<<dim3(S_LEN*1024/4/256), dim3(256), 0, stream>>>(Kc32, Kc32hm);
  gemm_bt_split<<<dim3(1, 4), dim3(256), 0, stream>>>(Kc32hm, w_comp_mlp, ck32, 512, 128, 4096);
  // 3c) selection masks (exact scores, rank-based top-16)
  sel_select_kernel<<<dim3(128, 16), dim3(64), 0, stream>>>(Qs32, ck32, selm, selU, selvis);
  // 4) compress MLP value path; FUSED vectorized Wm + wob conversion (R14)
  cvt2_kernel<<<dim3(1024), dim3(256), 0, stream>>>(w_comp_mlp, w_o, Wm, wob);
  gemm_bt<false><<<dim3(1, 4), dim3(256), 0, stream>>>(Vc, Wm, cv, 512, 128, 4096);
  // 4b) split-bf16 ck + transposed split-bf16 cv for the compressed MFMA branch
  comp_prep_kernel<<<dim3(256), dim3(256), 0, stream>>>(ck32, cv, ckh, ckl, cvTh, cvTl);
  // 5) gates; FUSED window-mean + V suffix chunk sums (R15); suffix pass b
  gates_kernel<<<dim3(S_LEN), dim3(64), 0, stream>>>(x, w_gate, gates);
  meansuff_kernel<<<dim3(NKV, 17), dim3(256), 0, stream>>>(Vw, Vs, meanvw, chunkS);
  suffv_b_kernel<<<dim3(NKV, 16), dim3(128), 0, stream>>>(Vs, chunkS, suffV);
  // 6) fused 3-branch MFMA attention + win-mean rows (R15: by in [288,384))
  attn_mfma_kernel<<<dim3(16, 384), dim3(256), 0, stream>>>(Qw, Kw, VwT, Qc, ckh, ckl, cvTh, cvTl,
                                                            Qs32, Ks, VsT, Vs, suffV, gates, meanvw,
                                                            selm, selU, selvis,
                                                            comb, combC, combS);
  // 7) combine partials -> bf16, then output projection
  combine_kernel<<<dim3(S_LEN*DIMN/4/256), dim3(256), 0, stream>>>(comb, combC, combS, combb);
  gemm_bt<false><<<dim3(16, 16), dim3(256), 0, stream>>>(combb, wob, outp, 2048, 2048, 2048);
}